// Round 1
// baseline (1502.791 us; speedup 1.0000x reference)
//
#include <hip/hip_runtime.h>
#include <math.h>

#define BB_ 2
#define C0 6
#define S0 48
#define V0 (S0*S0*S0)      // 110592
#define C1 192
#define S1 24
#define V1 (S1*S1*S1)      // 13824
#define C2 768
#define S2 12
#define LL (S2*S2*S2)      // 1728
#define NH 12
#define HD 64
#define KDIM (C1*8)        // 1536
#define MDIM (BB_*LL)      // 3456

static __device__ __forceinline__ float gelu_exact(float x){
  return 0.5f*x*(1.0f+erff(x*0.70710678118654752440f));
}

// ---------------- LN over 6 channels (channels_first), per voxel ----------------
__global__ __launch_bounds__(256) void ln6_kernel(const float* __restrict__ in,
    const float* __restrict__ w, const float* __restrict__ bia, float* __restrict__ out){
  int idx = blockIdx.x*256 + threadIdx.x;          // b*V0 + vox, exact grid
  int b = idx / V0, vox = idx - b*V0;
  const float* p = in + (size_t)b*(C0*V0) + vox;
  float v[C0]; float s=0.f;
#pragma unroll
  for (int c=0;c<C0;c++){ v[c]=p[(size_t)c*V0]; s+=v[c]; }
  float u = s*(1.f/C0);
  float ss=0.f;
#pragma unroll
  for (int c=0;c<C0;c++){ float d=v[c]-u; ss+=d*d; }
  float inv = rsqrtf(ss*(1.f/C0)+1e-6f);
  float* o = out + (size_t)b*(C0*V0) + vox;
#pragma unroll
  for (int c=0;c<C0;c++) o[(size_t)c*V0] = (v[c]-u)*inv*w[c]+bia[c];
}

// ------------- conv1 (6->192, k2s2) + LN(192) + GELU, writes im2col layout -------------
// h1p[(b*LL+tok)*1536 + p8*192 + oc]
__global__ __launch_bounds__(192) void conv1_kernel(const float* __restrict__ in,
    const float* __restrict__ w1, const float* __restrict__ g1, const float* __restrict__ b1,
    float* __restrict__ h1p){
  __shared__ float ws[C1*48];
  __shared__ float patch[48];
  __shared__ float red[8];
  __shared__ float stats[2];
  int t = threadIdx.x;
  for (int i=t;i<C1*48;i+=192) ws[i]=w1[i];
  const int nvox = BB_*V1;
  for (int v = blockIdx.x; v < nvox; v += gridDim.x){
    int b = v / V1, v24 = v - b*V1;
    int y = v24/(S1*S1), x=(v24/S1)%S1, z=v24%S1;
    __syncthreads();
    if (t < 48){
      int ic=t>>3, p=t&7;
      int vox48 = (2*y+((p>>2)&1))*(S0*S0) + (2*x+((p>>1)&1))*S0 + (2*z+(p&1));
      patch[t] = in[(size_t)(b*C0+ic)*V0 + vox48];
    }
    __syncthreads();
    float acc=0.f;
    const float* wr = &ws[t*48];
#pragma unroll
    for (int j=0;j<48;j++) acc = fmaf(patch[j], wr[j], acc);
    float s1=acc, s2=acc*acc;
#pragma unroll
    for (int off=32;off>0;off>>=1){ s1+=__shfl_xor(s1,off); s2+=__shfl_xor(s2,off); }
    int wid=t>>6;
    if ((t&63)==0){ red[wid]=s1; red[4+wid]=s2; }
    __syncthreads();
    if (t==0){
      float a=red[0]+red[1]+red[2], qq=red[4]+red[5]+red[6];
      float u=a*(1.f/C1);
      stats[0]=u; stats[1]=rsqrtf(qq*(1.f/C1)-u*u+1e-6f);
    }
    __syncthreads();
    float xn=(acc-stats[0])*stats[1]*g1[t]+b1[t];
    int tok=(y>>1)*(S2*S2)+(x>>1)*S2+(z>>1);
    int p8=(y&1)*4+(x&1)*2+(z&1);
    h1p[(size_t)(b*LL+tok)*KDIM + p8*C1 + t] = gelu_exact(xn);
  }
}

// -------- transpose w2 (oc,ic,kpq) -> w2t[(p*192+ic)*768 + oc] --------
__global__ __launch_bounds__(256) void transw2_kernel(const float* __restrict__ w2,
    float* __restrict__ w2t){
  int idx = blockIdx.x*256 + threadIdx.x;     // exact grid: KDIM*C2
  int oc = idx % C2;
  int kidx = idx / C2;
  int p = kidx / C1, ic = kidx - p*C1;
  w2t[idx] = w2[(size_t)oc*KDIM + ic*8 + p];
}

// ---------------- fp32 tiled GEMM 64x64, BK=16, 256 thr, 4x4 micro-tile ----------------
// EPI=0: plain C[m*N+n]. EPI=1: scatter for convT1 -> dh[(b*V1+v24)*192 + o]
template<int EPI>
__global__ __launch_bounds__(256) void gemm_kernel(const float* __restrict__ A,
    const float* __restrict__ Bm, float* __restrict__ Cm, int Md, int Nd, int Kd){
  __shared__ float As[16][68];
  __shared__ float Bs[16][64];
  int t = threadIdx.x;
  int tr = t>>4, tc = t&15;
  int m0 = blockIdx.y*64, n0 = blockIdx.x*64;
  int arow = t>>2, akq = t&3;
  int bkk = t>>4, bc4 = t&15;
  float acc[4][4]={};
  for (int kb=0; kb<Kd; kb+=16){
    __syncthreads();
    float4 a4 = *(const float4*)(A + (size_t)(m0+arow)*Kd + kb + akq*4);
    float4 b4 = *(const float4*)(Bm + (size_t)(kb+bkk)*Nd + n0 + bc4*4);
    As[akq*4+0][arow]=a4.x; As[akq*4+1][arow]=a4.y; As[akq*4+2][arow]=a4.z; As[akq*4+3][arow]=a4.w;
    *(float4*)&Bs[bkk][bc4*4]=b4;
    __syncthreads();
#pragma unroll
    for (int kk=0;kk<16;kk++){
      float4 av=*(const float4*)&As[kk][tr*4];
      float4 bv=*(const float4*)&Bs[kk][tc*4];
      float ax[4]={av.x,av.y,av.z,av.w};
      float bx[4]={bv.x,bv.y,bv.z,bv.w};
#pragma unroll
      for (int i=0;i<4;i++)
#pragma unroll
        for (int j=0;j<4;j++) acc[i][j] = fmaf(ax[i],bx[j],acc[i][j]);
    }
  }
  if (EPI==0){
#pragma unroll
    for (int i=0;i<4;i++){
      float4 o4 = make_float4(acc[i][0],acc[i][1],acc[i][2],acc[i][3]);
      *(float4*)(Cm + (size_t)(m0+tr*4+i)*Nd + n0+tc*4) = o4;
    }
  } else {
#pragma unroll
    for (int i=0;i<4;i++){
      int m=m0+tr*4+i; int b=m/LL; int tok=m-b*LL;
      int h=tok/(S2*S2), w=(tok/S2)%S2, d=tok%S2;
#pragma unroll
      for (int j=0;j<4;j++){
        int n=n0+tc*4+j; int o=n>>3, kpq=n&7;
        int v24=(2*h+((kpq>>2)&1))*(S1*S1)+(2*w+((kpq>>1)&1))*S1+(2*d+(kpq&1));
        Cm[(size_t)(b*V1+v24)*C1 + o]=acc[i][j];
      }
    }
  }
}

// ---------------- LN over 768 per token (+ optional RoPE), in-place, 1 wave/token ----------------
__global__ __launch_bounds__(64) void ln768_kernel(float* __restrict__ x,
    const float* __restrict__ g, const float* __restrict__ bia, int do_rope){
  int tok = blockIdx.x;
  int lane = threadIdx.x;
  float* row = x + (size_t)tok*C2;
  float v[12]; float s1=0.f,s2=0.f;
#pragma unroll
  for (int i=0;i<12;i++){ float t=row[i*64+lane]; v[i]=t; s1+=t; s2+=t*t; }
#pragma unroll
  for (int off=32;off>0;off>>=1){ s1+=__shfl_xor(s1,off); s2+=__shfl_xor(s2,off); }
  float u=s1*(1.f/C2);
  float inv=rsqrtf(s2*(1.f/C2)-u*u+1e-6f);
  if (!do_rope){
#pragma unroll
    for (int i=0;i<12;i++){ int j=i*64+lane; row[j]=(v[i]-u)*inv*g[j]+bia[j]; }
  } else {
    int pos = tok % LL;
#pragma unroll
    for (int i=0;i<6;i++){
      int j=i*64+lane;
      float xn1=(v[i]-u)*inv*g[j]+bia[j];
      float xn2=(v[i+6]-u)*inv*g[j+384]+bia[j+384];
      float fr=(float)pos*__expf(-0.02398526139f*(float)j);  // 10000^{-j/384}
      float cs=cosf(fr), sn=sinf(fr);
      row[j]     = xn1*cs - xn2*sn;
      row[j+384] = xn2*cs + xn1*sn;
    }
  }
}

// ---------------- flash attention fp32: BQ=64, BK=32, 256 thr ----------------
// out layout: ao[(b*LL+l)*768 + d*12 + h]   (matches 'b nh l c -> b (c nh) ...')
__global__ __launch_bounds__(256) void attn_kernel(const float* __restrict__ q,
    const float* __restrict__ k, const float* __restrict__ v, float* __restrict__ o){
  __shared__ float Qs[64][68];
  __shared__ float Ks[32][68];
  __shared__ float Vs[32][68];
  __shared__ float Ps[64][36];
  __shared__ float mS[64], lS[64];
  int qt=blockIdx.x, hh=blockIdx.y, b=blockIdx.z;
  int t=threadIdx.x;
  int g=t>>4, u=t&15;
  const float* qb = q + (size_t)(b*LL+qt*64)*C2 + hh*HD;
#pragma unroll
  for (int i=0;i<4;i++){
    int idx=t+i*256; int r=idx>>4, c4=idx&15;
    float4 a=*(const float4*)(qb + (size_t)r*C2 + c4*4);
    a.x*=0.125f;a.y*=0.125f;a.z*=0.125f;a.w*=0.125f;
    *(float4*)&Qs[r][c4*4]=a;
  }
  if (t<64){ mS[t]=-1e30f; lS[t]=0.f; }
  float O[4][4]={};
  for (int kt=0;kt<LL/32;kt++){
    __syncthreads();
    const float* kb = k + (size_t)(b*LL+kt*32)*C2 + hh*HD;
    const float* vb = v + (size_t)(b*LL+kt*32)*C2 + hh*HD;
#pragma unroll
    for (int i=0;i<2;i++){
      int idx=t+i*256; int r=idx>>4, c4=idx&15;
      *(float4*)&Ks[r][c4*4]=*(const float4*)(kb+(size_t)r*C2+c4*4);
      *(float4*)&Vs[r][c4*4]=*(const float4*)(vb+(size_t)r*C2+c4*4);
    }
    __syncthreads();
    float sc[4][2]={};
#pragma unroll
    for (int d=0;d<64;d+=4){
      float4 kv0=*(const float4*)&Ks[u*2][d];
      float4 kv1=*(const float4*)&Ks[u*2+1][d];
#pragma unroll
      for (int i=0;i<4;i++){
        float4 qv=*(const float4*)&Qs[g*4+i][d];
        sc[i][0]+=qv.x*kv0.x+qv.y*kv0.y+qv.z*kv0.z+qv.w*kv0.w;
        sc[i][1]+=qv.x*kv1.x+qv.y*kv1.y+qv.z*kv1.z+qv.w*kv1.w;
      }
    }
    float mloc[4], ps[4], alpha[4];
#pragma unroll
    for (int i=0;i<4;i++) mloc[i]=fmaxf(sc[i][0],sc[i][1]);
#pragma unroll
    for (int off=1;off<16;off<<=1)
#pragma unroll
      for (int i=0;i<4;i++) mloc[i]=fmaxf(mloc[i],__shfl_xor(mloc[i],off));
#pragma unroll
    for (int i=0;i<4;i++){
      float mo=mS[g*4+i];
      float mn=fmaxf(mo,mloc[i]);
      sc[i][0]=__expf(sc[i][0]-mn);
      sc[i][1]=__expf(sc[i][1]-mn);
      ps[i]=sc[i][0]+sc[i][1];
      alpha[i]=__expf(mo-mn);
      mloc[i]=mn;
    }
#pragma unroll
    for (int off=1;off<16;off<<=1)
#pragma unroll
      for (int i=0;i<4;i++) ps[i]+=__shfl_xor(ps[i],off);
#pragma unroll
    for (int i=0;i<4;i++){
      *(float2*)&Ps[g*4+i][u*2]=make_float2(sc[i][0],sc[i][1]);
#pragma unroll
      for (int j=0;j<4;j++) O[i][j]*=alpha[i];
    }
    if (u==0){
#pragma unroll
      for (int i=0;i<4;i++){ mS[g*4+i]=mloc[i]; lS[g*4+i]=lS[g*4+i]*alpha[i]+ps[i]; }
    }
    __syncthreads();
#pragma unroll
    for (int kc=0;kc<32;kc+=4){
      float4 vv0=*(const float4*)&Vs[kc][u*4];
      float4 vv1=*(const float4*)&Vs[kc+1][u*4];
      float4 vv2=*(const float4*)&Vs[kc+2][u*4];
      float4 vv3=*(const float4*)&Vs[kc+3][u*4];
#pragma unroll
      for (int i=0;i<4;i++){
        float4 pv=*(const float4*)&Ps[g*4+i][kc];
        O[i][0]+=pv.x*vv0.x+pv.y*vv1.x+pv.z*vv2.x+pv.w*vv3.x;
        O[i][1]+=pv.x*vv0.y+pv.y*vv1.y+pv.z*vv2.y+pv.w*vv3.y;
        O[i][2]+=pv.x*vv0.z+pv.y*vv1.z+pv.z*vv2.z+pv.w*vv3.z;
        O[i][3]+=pv.x*vv0.w+pv.y*vv1.w+pv.z*vv2.w+pv.w*vv3.w;
      }
    }
  }
  __syncthreads();
#pragma unroll
  for (int i=0;i<4;i++){
    float li=1.f/lS[g*4+i];
    int rowg = b*LL + qt*64 + g*4 + i;
#pragma unroll
    for (int j=0;j<4;j++){
      int c=(u*4+j)*NH + hh;
      o[(size_t)rowg*C2 + c]=O[i][j]*li;
    }
  }
}

// ---------------- LN over 192 + GELU, in-place, 1 wave/voxel24 ----------------
__global__ __launch_bounds__(64) void ln192_gelu_kernel(float* __restrict__ x,
    const float* __restrict__ g, const float* __restrict__ bia){
  int vi=blockIdx.x; int lane=threadIdx.x;
  float* row = x + (size_t)vi*C1;
  float v[3]; float s1=0.f,s2=0.f;
#pragma unroll
  for (int i=0;i<3;i++){ float t=row[i*64+lane]; v[i]=t; s1+=t; s2+=t*t; }
#pragma unroll
  for (int off=32;off>0;off>>=1){ s1+=__shfl_xor(s1,off); s2+=__shfl_xor(s2,off); }
  float u=s1*(1.f/C1), inv=rsqrtf(s2*(1.f/C1)-u*u+1e-6f);
#pragma unroll
  for (int i=0;i<3;i++){ int j=i*64+lane; float xn=(v[i]-u)*inv*g[j]+bia[j]; row[j]=gelu_exact(xn); }
}

// ---------------- convT2 (192->6, k2s2) + bias + residual ----------------
__global__ __launch_bounds__(256) void convt2_kernel(const float* __restrict__ dh,
    const float* __restrict__ tw2, const float* __restrict__ tb2,
    const float* __restrict__ skip, float* __restrict__ out){
  __shared__ float ws[C1*48];
  int t=threadIdx.x;
  for (int i=t;i<C1*48;i+=256) ws[i]=tw2[i];
  __syncthreads();
  int idx=blockIdx.x*256+t;          // exact grid 864*256 = 2*110592
  int b=idx/V0, vox=idx-b*V0;
  int y=vox/(S0*S0), x=(vox/S0)%S0, z=vox%S0;
  int v24=(y>>1)*(S1*S1)+(x>>1)*S1+(z>>1);
  int kpq=(y&1)*4+(x&1)*2+(z&1);
  const float* row = dh + (size_t)(b*V1+v24)*C1;
  float acc[C0];
#pragma unroll
  for (int c=0;c<C0;c++) acc[c]=tb2[c];
  for (int i=0;i<C1;i+=4){
    float4 r=*(const float4*)&row[i];
#pragma unroll
    for (int c=0;c<C0;c++){
      const float* wp=&ws[i*48 + c*8 + kpq];
      acc[c]+=r.x*wp[0]+r.y*wp[48]+r.z*wp[96]+r.w*wp[144];
    }
  }
#pragma unroll
  for (int c=0;c<C0;c++){
    size_t oi=(size_t)(b*C0+c)*V0+vox;
    out[oi]=acc[c]+skip[oi];
  }
}

extern "C" void kernel_launch(void* const* d_in, const int* in_sizes, int n_in,
                              void* d_out, int out_size, void* d_ws, size_t ws_size,
                              hipStream_t stream){
  (void)in_sizes; (void)n_in; (void)out_size; (void)ws_size;
  const float* x    =(const float*)d_in[0];
  const float* skip =(const float*)d_in[1];
  const float* q_w1 =(const float*)d_in[2];
  const float* q_g1 =(const float*)d_in[3];
  const float* q_b1 =(const float*)d_in[4];
  const float* q_w2 =(const float*)d_in[5];
  const float* q_g2 =(const float*)d_in[6];
  const float* q_b2 =(const float*)d_in[7];
  const float* k_w1 =(const float*)d_in[8];
  const float* k_g1 =(const float*)d_in[9];
  const float* k_b1 =(const float*)d_in[10];
  const float* k_w2 =(const float*)d_in[11];
  const float* k_g2 =(const float*)d_in[12];
  const float* k_b2 =(const float*)d_in[13];
  const float* v_w1 =(const float*)d_in[14];
  const float* v_g1 =(const float*)d_in[15];
  const float* v_b1 =(const float*)d_in[16];
  const float* v_w2 =(const float*)d_in[17];
  const float* v_g2 =(const float*)d_in[18];
  const float* v_b2 =(const float*)d_in[19];
  const float* o_tw1=(const float*)d_in[20];
  const float* o_g  =(const float*)d_in[21];
  const float* o_b  =(const float*)d_in[22];
  const float* o_tw2=(const float*)d_in[23];
  const float* o_tb2=(const float*)d_in[24];
  const float* ns_w =(const float*)d_in[25];
  const float* ns_b =(const float*)d_in[26];
  const float* nx_w =(const float*)d_in[27];
  const float* nx_b =(const float*)d_in[28];
  const float* no_w =(const float*)d_in[29];
  const float* no_b =(const float*)d_in[30];
  float* out=(float*)d_out;

  float* ws  =(float*)d_ws;
  float* lnS = ws;                    // 1,327,104
  float* lnX = lnS + 1327104;         // 1,327,104
  float* h1p = lnX + 1327104;         // 5,308,416 (also reused as dh)
  float* w2t = h1p + 5308416;         // 1,179,648
  float* qbuf= w2t + 1179648;         // 2,654,208
  float* kbuf= qbuf+ 2654208;         // 2,654,208
  float* vbuf= kbuf+ 2654208;         // 2,654,208
  float* ao  = vbuf+ 2654208;         // 2,654,208   total ~79 MB

  ln6_kernel<<<864,256,0,stream>>>(skip, ns_w, ns_b, lnS);
  ln6_kernel<<<864,256,0,stream>>>(x,    nx_w, nx_b, lnX);

  // q stem (input: ln'd skip)
  conv1_kernel<<<864,192,0,stream>>>(lnS,q_w1,q_g1,q_b1,h1p);
  transw2_kernel<<<4608,256,0,stream>>>(q_w2,w2t);
  gemm_kernel<0><<<dim3(12,54),256,0,stream>>>(h1p,w2t,qbuf,MDIM,C2,KDIM);
  ln768_kernel<<<MDIM,64,0,stream>>>(qbuf,q_g2,q_b2,1);

  // k stem (input: ln'd x)
  conv1_kernel<<<864,192,0,stream>>>(lnX,k_w1,k_g1,k_b1,h1p);
  transw2_kernel<<<4608,256,0,stream>>>(k_w2,w2t);
  gemm_kernel<0><<<dim3(12,54),256,0,stream>>>(h1p,w2t,kbuf,MDIM,C2,KDIM);
  ln768_kernel<<<MDIM,64,0,stream>>>(kbuf,k_g2,k_b2,1);

  // v stem
  conv1_kernel<<<864,192,0,stream>>>(lnX,v_w1,v_g1,v_b1,h1p);
  transw2_kernel<<<4608,256,0,stream>>>(v_w2,w2t);
  gemm_kernel<0><<<dim3(12,54),256,0,stream>>>(h1p,w2t,vbuf,MDIM,C2,KDIM);
  ln768_kernel<<<MDIM,64,0,stream>>>(vbuf,v_g2,v_b2,0);

  // attention
  attn_kernel<<<dim3(27,12,2),256,0,stream>>>(qbuf,kbuf,vbuf,ao);
  ln768_kernel<<<MDIM,64,0,stream>>>(ao,no_w,no_b,0);

  // debed: convT1 as GEMM with scatter epilogue into dh (=h1p buffer)
  gemm_kernel<1><<<dim3(24,54),256,0,stream>>>(ao,o_tw1,h1p,MDIM,KDIM,C2);
  ln192_gelu_kernel<<<BB_*V1,64,0,stream>>>(h1p,o_g,o_b);
  convt2_kernel<<<864,256,0,stream>>>(h1p,o_tw2,o_tb2,skip,out);
}

// Round 2
// 566.140 us; speedup vs baseline: 2.6544x; 2.6544x over previous
//
#include <hip/hip_runtime.h>
#include <math.h>

#define BB_ 2
#define C0 6
#define S0 48
#define V0 (S0*S0*S0)      // 110592
#define C1 192
#define S1 24
#define V1 (S1*S1*S1)      // 13824
#define C2 768
#define S2 12
#define LL (S2*S2*S2)      // 1728
#define NH 12
#define HD 64
#define KDIM (C1*8)        // 1536
#define MDIM (BB_*LL)      // 3456

typedef __attribute__((ext_vector_type(8))) short short8;
typedef __attribute__((ext_vector_type(4))) float float4v;

static __device__ __forceinline__ float gelu_exact(float x){
  return 0.5f*x*(1.0f+erff(x*0.70710678118654752440f));
}
static __device__ __forceinline__ unsigned short f2bf(float f){
  unsigned int u = __float_as_uint(f);
  unsigned int r = (u + 0x7fffu + ((u>>16)&1u)) >> 16;
  return (unsigned short)r;
}
static __device__ __forceinline__ void load_lds16(const void* g, void* l){
  __builtin_amdgcn_global_load_lds((const __attribute__((address_space(1))) unsigned int*)g,
      (__attribute__((address_space(3))) unsigned int*)l, 16, 0, 0);
}

// ---------------- LN over 6 channels (channels_first), per voxel ----------------
__global__ __launch_bounds__(256) void ln6_kernel(const float* __restrict__ in,
    const float* __restrict__ w, const float* __restrict__ bia, float* __restrict__ out){
  int idx = blockIdx.x*256 + threadIdx.x;
  int b = idx / V0, vox = idx - b*V0;
  const float* p = in + (size_t)b*(C0*V0) + vox;
  float v[C0]; float s=0.f;
#pragma unroll
  for (int c=0;c<C0;c++){ v[c]=p[(size_t)c*V0]; s+=v[c]; }
  float u = s*(1.f/C0);
  float ss=0.f;
#pragma unroll
  for (int c=0;c<C0;c++){ float d=v[c]-u; ss+=d*d; }
  float inv = rsqrtf(ss*(1.f/C0)+1e-6f);
  float* o = out + (size_t)b*(C0*V0) + vox;
#pragma unroll
  for (int c=0;c<C0;c++) o[(size_t)c*V0] = (v[c]-u)*inv*w[c]+bia[c];
}

// ------------- conv1 (6->192, k2s2) + LN(192) + GELU, wave-per-voxel -------------
// writes bf16 im2col: h1p[(b*LL+tok)*1536 + p8*192 + oc]
__global__ __launch_bounds__(256) void conv1_kernel(const float* __restrict__ in,
    const float* __restrict__ w1, const float* __restrict__ g1, const float* __restrict__ b1,
    unsigned short* __restrict__ h1p){
  __shared__ float ws[C1*50];
  __shared__ float ppat[4*64];
  int t = threadIdx.x, w = t>>6, lane = t&63;
  for (int i=t;i<C1*48;i+=256){ int oc=i/48, j=i-oc*48; ws[oc*50+j]=w1[i]; }
  __syncthreads();
  for (int v = blockIdx.x*4 + w; v < BB_*V1; v += 3456){
    int b = v / V1, v24 = v - b*V1;
    int y = v24/(S1*S1), x=(v24/S1)%S1, z=v24%S1;
    if (lane < 48){
      int ic=lane>>3, p=lane&7;
      int vox48 = (2*y+((p>>2)&1))*(S0*S0) + (2*x+((p>>1)&1))*S0 + (2*z+(p&1));
      ppat[w*64+lane] = in[(size_t)(b*C0+ic)*V0 + vox48];
    }
    float a0=0.f,a1=0.f,a2=0.f;
    const float* w0 = &ws[lane*50];
    const float* w1p = &ws[(lane+64)*50];
    const float* w2p = &ws[(lane+128)*50];
#pragma unroll
    for (int j=0;j<48;j+=2){
      float2 pv = *(const float2*)&ppat[w*64+j];
      float2 q0 = *(const float2*)&w0[j];
      float2 q1 = *(const float2*)&w1p[j];
      float2 q2 = *(const float2*)&w2p[j];
      a0 += pv.x*q0.x + pv.y*q0.y;
      a1 += pv.x*q1.x + pv.y*q1.y;
      a2 += pv.x*q2.x + pv.y*q2.y;
    }
    float s1 = a0+a1+a2, s2 = a0*a0+a1*a1+a2*a2;
#pragma unroll
    for (int off=32;off>0;off>>=1){ s1+=__shfl_xor(s1,off); s2+=__shfl_xor(s2,off); }
    float u = s1*(1.f/C1);
    float inv = rsqrtf(s2*(1.f/C1)-u*u+1e-6f);
    int tok=(y>>1)*(S2*S2)+(x>>1)*S2+(z>>1);
    int p8=(y&1)*4+(x&1)*2+(z&1);
    unsigned short* hb = h1p + (size_t)(b*LL+tok)*KDIM + p8*C1;
    hb[lane]     = f2bf(gelu_exact((a0-u)*inv*g1[lane]     + b1[lane]));
    hb[lane+64]  = f2bf(gelu_exact((a1-u)*inv*g1[lane+64]  + b1[lane+64]));
    hb[lane+128] = f2bf(gelu_exact((a2-u)*inv*g1[lane+128] + b1[lane+128]));
  }
}

// -------- repack w2 (oc,ic,kpq) fp32 -> Bt bf16 [oc][p*192+ic] --------
__global__ __launch_bounds__(256) void repack_w2_kernel(const float* __restrict__ w2,
    unsigned short* __restrict__ out){
  int idx = blockIdx.x*256 + threadIdx.x;       // 4608*256 = 1179648 exact
  int oc = idx/KDIM; int r = idx-oc*KDIM; int p = r/C1; int ic = r-p*C1;
  out[idx] = f2bf(w2[(size_t)oc*KDIM + ic*8 + p]);
}

// -------- repack o_tw1 (i,o,kpq) fp32 -> Btd bf16 [kpq*192+o][i] --------
__global__ __launch_bounds__(256) void repack_tw1_kernel(const float* __restrict__ tw,
    unsigned short* __restrict__ out){
  int idx = blockIdx.x*256 + threadIdx.x;       // 1536*768 = 1179648 exact
  int n = idx/C2; int i = idx-n*C2; int kpq = n/C1; int o = n-kpq*C1;
  out[idx] = f2bf(tw[(size_t)i*KDIM + o*8 + kpq]);
}

// ---------------- bf16 MFMA GEMM, tiles 128(M)x64(N), BK=32, 256 thr ----------------
// C[m][n] = sum_k A[m][k]*Bt[n][k].  EPI=0: C fp32 row-major [M][Nd]
// EPI=1: debed scatter -> dh[(b*V1+v24)*192 + o], n = kpq*192+o
template<int EPI>
__global__ __launch_bounds__(256) void gemm_bf16(const unsigned short* __restrict__ A,
    const unsigned short* __restrict__ Bt, float* __restrict__ C, int Nd, int Kd){
  __shared__ __align__(16) unsigned short Al[128*32];
  __shared__ __align__(16) unsigned short Bl[64*32];
  int t=threadIdx.x, w=t>>6, lane=t&63;
  int g=lane>>4, l16=lane&15, r16=lane>>2, c16=lane&3;
  int m0=blockIdx.y*128, n0=blockIdx.x*64;
  int wm=w>>1, wn=w&1;
  float4v acc[4][2] = {};
  for (int kb=0;kb<Kd;kb+=32){
    __syncthreads();
#pragma unroll
    for (int cc=0;cc<3;cc++){
      int ch = w*3+cc;
      if (ch<8){
        const unsigned short* gp = A + (size_t)(m0+ch*16+r16)*Kd + kb + c16*8;
        load_lds16(gp, &Al[ch*512]);
      } else {
        const unsigned short* gp = Bt + (size_t)(n0+(ch-8)*16+r16)*Kd + kb + c16*8;
        load_lds16(gp, &Bl[(ch-8)*512]);
      }
    }
    __syncthreads();
    short8 af[4], bf[2];
#pragma unroll
    for (int mt=0;mt<4;mt++) af[mt] = *(const short8*)&Al[(wm*64+mt*16+l16)*32 + g*8];
#pragma unroll
    for (int nt=0;nt<2;nt++) bf[nt] = *(const short8*)&Bl[(wn*32+nt*16+l16)*32 + g*8];
#pragma unroll
    for (int mt=0;mt<4;mt++)
#pragma unroll
      for (int nt=0;nt<2;nt++)
        acc[mt][nt] = __builtin_amdgcn_mfma_f32_16x16x32_bf16(af[mt], bf[nt], acc[mt][nt], 0,0,0);
  }
  if (EPI==0){
#pragma unroll
    for (int mt=0;mt<4;mt++){
      int mb = m0 + wm*64 + mt*16 + g*4;
#pragma unroll
      for (int nt=0;nt<2;nt++){
        int col = n0 + wn*32 + nt*16 + l16;
#pragma unroll
        for (int reg=0;reg<4;reg++)
          C[(size_t)(mb+reg)*Nd + col] = acc[mt][nt][reg];
      }
    }
  } else {
    int kpq = (n0 + wn*32)/C1;        // 64-blocks never straddle 192 boundaries
#pragma unroll
    for (int nt=0;nt<2;nt++){
      int n = n0 + wn*32 + nt*16 + l16;
      int o = n - kpq*C1;
#pragma unroll
      for (int mt=0;mt<4;mt++){
        int mb = m0 + wm*64 + mt*16 + g*4;
#pragma unroll
        for (int reg=0;reg<4;reg++){
          int m = mb + reg;
          int b = m / LL; int tok = m - b*LL;
          int h = tok/(S2*S2), ww=(tok/S2)%S2, d=tok%S2;
          int v24 = (2*h+((kpq>>2)&1))*(S1*S1) + (2*ww+((kpq>>1)&1))*S1 + (2*d+(kpq&1));
          C[(size_t)(b*V1+v24)*C1 + o] = acc[mt][nt][reg];
        }
      }
    }
  }
}

// ------------- LN over 768 per token (+rope,+scale), fp32 in -> bf16 out -------------
__global__ __launch_bounds__(64) void ln768_bf_kernel(const float* __restrict__ in,
    const float* __restrict__ g, const float* __restrict__ bia,
    unsigned short* __restrict__ out, int do_rope, float scale){
  int tok = blockIdx.x, lane = threadIdx.x;
  const float* row = in + (size_t)tok*C2;
  unsigned short* orow = out + (size_t)tok*C2;
  float v[12]; float s1=0.f,s2=0.f;
#pragma unroll
  for (int i=0;i<12;i++){ float t=row[i*64+lane]; v[i]=t; s1+=t; s2+=t*t; }
#pragma unroll
  for (int off=32;off>0;off>>=1){ s1+=__shfl_xor(s1,off); s2+=__shfl_xor(s2,off); }
  float u=s1*(1.f/C2);
  float inv=rsqrtf(s2*(1.f/C2)-u*u+1e-6f);
  if (!do_rope){
#pragma unroll
    for (int i=0;i<12;i++){ int j=i*64+lane; orow[j]=f2bf(((v[i]-u)*inv*g[j]+bia[j])*scale); }
  } else {
    int pos = tok % LL;
#pragma unroll
    for (int i=0;i<6;i++){
      int j=i*64+lane;
      float xn1=(v[i]-u)*inv*g[j]+bia[j];
      float xn2=(v[i+6]-u)*inv*g[j+384]+bia[j+384];
      float fr=(float)pos*__expf(-0.02398526139f*(float)j);  // 10000^{-j/384}
      float cs=cosf(fr), sn=sinf(fr);
      orow[j]     = f2bf((xn1*cs - xn2*sn)*scale);
      orow[j+384] = f2bf((xn2*cs + xn1*sn)*scale);
    }
  }
}

// ------------- V transpose: vbf [m][768] bf16 -> vT [(b*12+h)*64+d][1728] bf16 -------------
__global__ __launch_bounds__(256) void vtrans_kernel(const unsigned short* __restrict__ vbf,
    unsigned short* __restrict__ vT){
  int idx = blockIdx.x*256 + threadIdx.x;   // 1296*256 = 331776 = 2*12*8*1728 exact
  int token = idx % LL;
  int rest = idx / LL;
  int dc = rest & 7;
  int hb = rest >> 3;
  int h = hb % NH, b = hb / NH;
  const unsigned short* src = vbf + (size_t)(b*LL+token)*C2 + h*64 + dc*8;
  uint4 d4 = *(const uint4*)src;
  const unsigned short* s = (const unsigned short*)&d4;
#pragma unroll
  for (int i=0;i<8;i++)
    vT[(size_t)((b*NH+h)*HD + dc*8 + i)*LL + token] = s[i];
}

// ---------------- MFMA flash attention: BQ=64 (16/wave), BK=64 keys/iter ----------------
// out: ao[(b*LL+l)*768 + d*12 + h]  fp32
__global__ __launch_bounds__(256) void attn_kernel(const unsigned short* __restrict__ q,
    const unsigned short* __restrict__ k, const unsigned short* __restrict__ vt,
    float* __restrict__ o){
  __shared__ __align__(16) unsigned short QsA[64*32], QsB[64*32];
  __shared__ __align__(16) unsigned short KsA[64*32], KsB[64*32];
  __shared__ __align__(16) unsigned short VtA[64*32], VtB[64*32];
  __shared__ __align__(16) unsigned short Ps[4][2][16*32];
  int qt=blockIdx.x, h=blockIdx.y, b=blockIdx.z;
  int t=threadIdx.x, w=t>>6, lane=t&63;
  int g=lane>>4, l16=lane&15, r16=lane>>2, c16=lane&3;
  // stage Q (each wave its own 16 rows, both d-halves); Q pre-scaled by 1/8 in ln768_bf
  {
    const unsigned short* qg = q + (size_t)(b*LL + qt*64 + w*16 + r16)*C2 + h*64 + c16*8;
    load_lds16(qg,      &QsA[w*512]);
    load_lds16(qg + 32, &QsB[w*512]);
  }
  float mrow[4] = {-1e30f,-1e30f,-1e30f,-1e30f};
  float lrow[4] = {0.f,0.f,0.f,0.f};
  float4v O4[4] = {};
  const float LOG2E = 1.44269504089f;
  for (int kt=0; kt<LL/64; kt++){
    __syncthreads();
#pragma unroll
    for (int cc=0;cc<4;cc++){
      int ch = w*4+cc;
      if (ch<4){
        const unsigned short* gp = k + (size_t)(b*LL + kt*64 + ch*16 + r16)*C2 + h*64 + c16*8;
        load_lds16(gp, &KsA[ch*512]);
      } else if (ch<8){
        int cr = ch-4;
        const unsigned short* gp = k + (size_t)(b*LL + kt*64 + cr*16 + r16)*C2 + h*64 + 32 + c16*8;
        load_lds16(gp, &KsB[cr*512]);
      } else if (ch<12){
        int cr = ch-8;
        const unsigned short* gp = vt + (size_t)((b*NH+h)*HD + cr*16 + r16)*LL + kt*64 + c16*8;
        load_lds16(gp, &VtA[cr*512]);
      } else {
        int cr = ch-12;
        const unsigned short* gp = vt + (size_t)((b*NH+h)*HD + cr*16 + r16)*LL + kt*64 + 32 + c16*8;
        load_lds16(gp, &VtB[cr*512]);
      }
    }
    __syncthreads();
    // S = Q K^T  (rows = this wave's 16 q, cols = 64 keys)
    float4v sc[4] = {};
    short8 aA = *(const short8*)&QsA[(w*16+l16)*32 + g*8];
    short8 aB = *(const short8*)&QsB[(w*16+l16)*32 + g*8];
#pragma unroll
    for (int nt=0;nt<4;nt++){
      short8 bA = *(const short8*)&KsA[(nt*16+l16)*32 + g*8];
      short8 bB = *(const short8*)&KsB[(nt*16+l16)*32 + g*8];
      sc[nt] = __builtin_amdgcn_mfma_f32_16x16x32_bf16(aA, bA, sc[nt], 0,0,0);
      sc[nt] = __builtin_amdgcn_mfma_f32_16x16x32_bf16(aB, bB, sc[nt], 0,0,0);
    }
    // online softmax (rows g*4+reg)
    float mnew[4], al[4], psum[4];
#pragma unroll
    for (int reg=0;reg<4;reg++){
      float mx = fmaxf(fmaxf(sc[0][reg],sc[1][reg]), fmaxf(sc[2][reg],sc[3][reg]));
#pragma unroll
      for (int off=1;off<16;off<<=1) mx = fmaxf(mx, __shfl_xor(mx,off));
      mnew[reg] = fmaxf(mrow[reg], mx);
    }
#pragma unroll
    for (int nt=0;nt<4;nt++)
#pragma unroll
      for (int reg=0;reg<4;reg++)
        sc[nt][reg] = exp2f((sc[nt][reg]-mnew[reg])*LOG2E);
#pragma unroll
    for (int reg=0;reg<4;reg++){
      float ps = sc[0][reg]+sc[1][reg]+sc[2][reg]+sc[3][reg];
#pragma unroll
      for (int off=1;off<16;off<<=1) ps += __shfl_xor(ps,off);
      psum[reg]=ps;
      al[reg] = exp2f((mrow[reg]-mnew[reg])*LOG2E);
      lrow[reg] = lrow[reg]*al[reg] + psum[reg];
      mrow[reg] = mnew[reg];
    }
    // write P to wave-private LDS (bf16, paired into dword writes)
#pragma unroll
    for (int nt=0;nt<4;nt++){
#pragma unroll
      for (int reg=0;reg<4;reg++){
        unsigned int u0 = f2bf(sc[nt][reg]);
        unsigned int u1 = (unsigned int)__shfl_xor((int)u0, 1);
        if (!(lane&1)){
          int half = nt>>1, kl = (nt&1)*16 + l16;
          *(unsigned int*)&Ps[w][half][(g*4+reg)*32 + kl] = u0 | (u1<<16);
        }
      }
    }
    // rescale O
#pragma unroll
    for (int dt=0;dt<4;dt++)
#pragma unroll
      for (int reg=0;reg<4;reg++) O4[dt][reg] *= al[reg];
    // O += P V   (P: A-layout rows l16, V^T tiles: n=d, k=key)
    short8 pA = *(const short8*)&Ps[w][0][l16*32 + g*8];
    short8 pB = *(const short8*)&Ps[w][1][l16*32 + g*8];
#pragma unroll
    for (int dt=0;dt<4;dt++){
      short8 vA = *(const short8*)&VtA[(dt*16+l16)*32 + g*8];
      short8 vB = *(const short8*)&VtB[(dt*16+l16)*32 + g*8];
      O4[dt] = __builtin_amdgcn_mfma_f32_16x16x32_bf16(pA, vA, O4[dt], 0,0,0);
      O4[dt] = __builtin_amdgcn_mfma_f32_16x16x32_bf16(pB, vB, O4[dt], 0,0,0);
    }
  }
  float invl[4];
#pragma unroll
  for (int reg=0;reg<4;reg++) invl[reg] = 1.f/lrow[reg];
#pragma unroll
  for (int dt=0;dt<4;dt++){
#pragma unroll
    for (int reg=0;reg<4;reg++){
      int mg = b*LL + qt*64 + w*16 + g*4 + reg;
      int c = (dt*16+l16)*NH + h;
      o[(size_t)mg*C2 + c] = O4[dt][reg]*invl[reg];
    }
  }
}

// ---------------- LN over 192 + GELU, in-place (dh fp32) ----------------
__global__ __launch_bounds__(64) void ln192_gelu_kernel(float* __restrict__ x,
    const float* __restrict__ g, const float* __restrict__ bia){
  int vi=blockIdx.x; int lane=threadIdx.x;
  float* row = x + (size_t)vi*C1;
  float v[3]; float s1=0.f,s2=0.f;
#pragma unroll
  for (int i=0;i<3;i++){ float t=row[i*64+lane]; v[i]=t; s1+=t; s2+=t*t; }
#pragma unroll
  for (int off=32;off>0;off>>=1){ s1+=__shfl_xor(s1,off); s2+=__shfl_xor(s2,off); }
  float u=s1*(1.f/C1), inv=rsqrtf(s2*(1.f/C1)-u*u+1e-6f);
#pragma unroll
  for (int i=0;i<3;i++){ int j=i*64+lane; float xn=(v[i]-u)*inv*g[j]+bia[j]; row[j]=gelu_exact(xn); }
}

// ---------------- convT2 (192->6, k2s2) + bias + residual ----------------
__global__ __launch_bounds__(256) void convt2_kernel(const float* __restrict__ dh,
    const float* __restrict__ tw2, const float* __restrict__ tb2,
    const float* __restrict__ skip, float* __restrict__ out){
  __shared__ float ws[C1*48];
  int t=threadIdx.x;
  for (int i=t;i<C1*48;i+=256) ws[i]=tw2[i];
  __syncthreads();
  int idx=blockIdx.x*256+t;
  int b=idx/V0, vox=idx-b*V0;
  int y=vox/(S0*S0), x=(vox/S0)%S0, z=vox%S0;
  int v24=(y>>1)*(S1*S1)+(x>>1)*S1+(z>>1);
  int kpq=(y&1)*4+(x&1)*2+(z&1);
  const float* row = dh + (size_t)(b*V1+v24)*C1;
  float acc[C0];
#pragma unroll
  for (int c=0;c<C0;c++) acc[c]=tb2[c];
  for (int i=0;i<C1;i+=4){
    float4 r=*(const float4*)&row[i];
#pragma unroll
    for (int c=0;c<C0;c++){
      const float* wp=&ws[i*48 + c*8 + kpq];
      acc[c]+=r.x*wp[0]+r.y*wp[48]+r.z*wp[96]+r.w*wp[144];
    }
  }
#pragma unroll
  for (int c=0;c<C0;c++){
    size_t oi=(size_t)(b*C0+c)*V0+vox;
    out[oi]=acc[c]+skip[oi];
  }
}

extern "C" void kernel_launch(void* const* d_in, const int* in_sizes, int n_in,
                              void* d_out, int out_size, void* d_ws, size_t ws_size,
                              hipStream_t stream){
  (void)in_sizes; (void)n_in; (void)out_size; (void)ws_size;
  const float* x    =(const float*)d_in[0];
  const float* skip =(const float*)d_in[1];
  const float* q_w1 =(const float*)d_in[2];
  const float* q_g1 =(const float*)d_in[3];
  const float* q_b1 =(const float*)d_in[4];
  const float* q_w2 =(const float*)d_in[5];
  const float* q_g2 =(const float*)d_in[6];
  const float* q_b2 =(const float*)d_in[7];
  const float* k_w1 =(const float*)d_in[8];
  const float* k_g1 =(const float*)d_in[9];
  const float* k_b1 =(const float*)d_in[10];
  const float* k_w2 =(const float*)d_in[11];
  const float* k_g2 =(const float*)d_in[12];
  const float* k_b2 =(const float*)d_in[13];
  const float* v_w1 =(const float*)d_in[14];
  const float* v_g1 =(const float*)d_in[15];
  const float* v_b1 =(const float*)d_in[16];
  const float* v_w2 =(const float*)d_in[17];
  const float* v_g2 =(const float*)d_in[18];
  const float* v_b2 =(const float*)d_in[19];
  const float* o_tw1=(const float*)d_in[20];
  const float* o_g  =(const float*)d_in[21];
  const float* o_b  =(const float*)d_in[22];
  const float* o_tw2=(const float*)d_in[23];
  const float* o_tb2=(const float*)d_in[24];
  const float* ns_w =(const float*)d_in[25];
  const float* ns_b =(const float*)d_in[26];
  const float* nx_w =(const float*)d_in[27];
  const float* nx_b =(const float*)d_in[28];
  const float* no_w =(const float*)d_in[29];
  const float* no_b =(const float*)d_in[30];
  float* out=(float*)d_out;

  char* W = (char*)d_ws;
  float*          lnS = (float*)(W + 0);                  //  5,308,416 B
  float*          lnX = (float*)(W + 5308416);            //  5,308,416 B
  unsigned short* h1p = (unsigned short*)(W + 10616832);  // 10,616,832 B
  unsigned short* w2t = (unsigned short*)(W + 21233664);  //  2,359,296 B
  float*          cf32= (float*)(W + 23592960);           // 10,616,832 B
  unsigned short* qbf = (unsigned short*)(W + 34209792);  //  5,308,416 B
  unsigned short* kbf = (unsigned short*)(W + 39518208);  //  5,308,416 B
  unsigned short* vbf = (unsigned short*)(W + 44826624);  //  5,308,416 B
  unsigned short* vT  = (unsigned short*)(W + 50135040);  //  5,308,416 B
  float*          ao  = (float*)(W + 55443456);           // 10,616,832 B
  unsigned short* aob = (unsigned short*)(W + 66060288);  //  5,308,416 B
  unsigned short* Btd = (unsigned short*)(W + 71368704);  //  2,359,296 B -> 73,728,000 total
  float*          dh  = (float*)(W + 0);                  // overlay on lnS+lnX+h1p (21,233,664 B)

  ln6_kernel<<<864,256,0,stream>>>(skip, ns_w, ns_b, lnS);
  ln6_kernel<<<864,256,0,stream>>>(x,    nx_w, nx_b, lnX);

  // q stem
  conv1_kernel<<<864,256,0,stream>>>(lnS, q_w1, q_g1, q_b1, h1p);
  repack_w2_kernel<<<4608,256,0,stream>>>(q_w2, w2t);
  gemm_bf16<0><<<dim3(12,27),256,0,stream>>>(h1p, w2t, cf32, C2, KDIM);
  ln768_bf_kernel<<<MDIM,64,0,stream>>>(cf32, q_g2, q_b2, qbf, 1, 0.125f);

  // k stem
  conv1_kernel<<<864,256,0,stream>>>(lnX, k_w1, k_g1, k_b1, h1p);
  repack_w2_kernel<<<4608,256,0,stream>>>(k_w2, w2t);
  gemm_bf16<0><<<dim3(12,27),256,0,stream>>>(h1p, w2t, cf32, C2, KDIM);
  ln768_bf_kernel<<<MDIM,64,0,stream>>>(cf32, k_g2, k_b2, kbf, 1, 1.0f);

  // v stem
  conv1_kernel<<<864,256,0,stream>>>(lnX, v_w1, v_g1, v_b1, h1p);
  repack_w2_kernel<<<4608,256,0,stream>>>(v_w2, w2t);
  gemm_bf16<0><<<dim3(12,27),256,0,stream>>>(h1p, w2t, cf32, C2, KDIM);
  ln768_bf_kernel<<<MDIM,64,0,stream>>>(cf32, v_g2, v_b2, vbf, 0, 1.0f);
  vtrans_kernel<<<1296,256,0,stream>>>(vbf, vT);

  // attention
  attn_kernel<<<dim3(27,12,2),256,0,stream>>>(qbf, kbf, vT, ao);
  ln768_bf_kernel<<<MDIM,64,0,stream>>>(ao, no_w, no_b, aob, 0, 1.0f);

  // debed
  repack_tw1_kernel<<<4608,256,0,stream>>>(o_tw1, Btd);
  gemm_bf16<1><<<dim3(24,27),256,0,stream>>>(aob, Btd, dh, KDIM, C2);
  ln192_gelu_kernel<<<BB_*V1,64,0,stream>>>(dh, o_g, o_b);
  convt2_kernel<<<864,256,0,stream>>>(dh, o_tw2, o_tb2, skip, out);
}

// Round 3
// 511.611 us; speedup vs baseline: 2.9374x; 1.1066x over previous
//
#include <hip/hip_runtime.h>
#include <math.h>

#define BB_ 2
#define C0 6
#define S0 48
#define V0 (S0*S0*S0)      // 110592
#define C1 192
#define S1 24
#define V1 (S1*S1*S1)      // 13824
#define C2 768
#define S2 12
#define LL (S2*S2*S2)      // 1728
#define NH 12
#define HD 64
#define KDIM (C1*8)        // 1536
#define MDIM (BB_*LL)      // 3456

typedef __attribute__((ext_vector_type(8))) short short8;
typedef __attribute__((ext_vector_type(4))) short short4v;
typedef __attribute__((ext_vector_type(4))) float float4v;

static __device__ __forceinline__ float gelu_exact(float x){
  return 0.5f*x*(1.0f+erff(x*0.70710678118654752440f));
}
static __device__ __forceinline__ unsigned short f2bf(float f){
  unsigned int u = __float_as_uint(f);
  unsigned int r = (u + 0x7fffu + ((u>>16)&1u)) >> 16;
  return (unsigned short)r;
}
static __device__ __forceinline__ void load_lds16(const void* g, void* l){
  __builtin_amdgcn_global_load_lds((const __attribute__((address_space(1))) unsigned int*)g,
      (__attribute__((address_space(3))) unsigned int*)l, 16, 0, 0);
}
static __device__ __forceinline__ float4v mfma32(short8 a, short8 b, float4v c){
  return __builtin_amdgcn_mfma_f32_16x16x32_bf16(a,b,c,0,0,0);
}
static __device__ __forceinline__ float4v mfma16(short4v a, short4v b, float4v c){
#if __has_builtin(__builtin_amdgcn_mfma_f32_16x16x16bf16_1k)
  return __builtin_amdgcn_mfma_f32_16x16x16bf16_1k(a,b,c,0,0,0);
#else
  asm volatile("v_mfma_f32_16x16x16_bf16 %0, %1, %2, %0" : "+v"(c) : "v"(a), "v"(b));
  return c;
#endif
}

// ---------------- LN over 6 channels (channels_first), per voxel ----------------
__global__ __launch_bounds__(256) void ln6_kernel(const float* __restrict__ in,
    const float* __restrict__ w, const float* __restrict__ bia, float* __restrict__ out){
  int idx = blockIdx.x*256 + threadIdx.x;
  int b = idx / V0, vox = idx - b*V0;
  const float* p = in + (size_t)b*(C0*V0) + vox;
  float v[C0]; float s=0.f;
#pragma unroll
  for (int c=0;c<C0;c++){ v[c]=p[(size_t)c*V0]; s+=v[c]; }
  float u = s*(1.f/C0);
  float ss=0.f;
#pragma unroll
  for (int c=0;c<C0;c++){ float d=v[c]-u; ss+=d*d; }
  float inv = rsqrtf(ss*(1.f/C0)+1e-6f);
  float* o = out + (size_t)b*(C0*V0) + vox;
#pragma unroll
  for (int c=0;c<C0;c++) o[(size_t)c*V0] = (v[c]-u)*inv*w[c]+bia[c];
}

// ------------- conv1 (6->192, k2s2) + LN(192) + GELU, wave-per-voxel -------------
__global__ __launch_bounds__(256) void conv1_kernel(const float* __restrict__ in,
    const float* __restrict__ w1, const float* __restrict__ g1, const float* __restrict__ b1,
    unsigned short* __restrict__ h1p){
  __shared__ float ws[C1*50];
  __shared__ float ppat[4*64];
  int t = threadIdx.x, w = t>>6, lane = t&63;
  for (int i=t;i<C1*48;i+=256){ int oc=i/48, j=i-oc*48; ws[oc*50+j]=w1[i]; }
  __syncthreads();
  for (int v = blockIdx.x*4 + w; v < BB_*V1; v += 3456){
    int b = v / V1, v24 = v - b*V1;
    int y = v24/(S1*S1), x=(v24/S1)%S1, z=v24%S1;
    if (lane < 48){
      int ic=lane>>3, p=lane&7;
      int vox48 = (2*y+((p>>2)&1))*(S0*S0) + (2*x+((p>>1)&1))*S0 + (2*z+(p&1));
      ppat[w*64+lane] = in[(size_t)(b*C0+ic)*V0 + vox48];
    }
    float a0=0.f,a1=0.f,a2=0.f;
    const float* w0 = &ws[lane*50];
    const float* w1p = &ws[(lane+64)*50];
    const float* w2p = &ws[(lane+128)*50];
#pragma unroll
    for (int j=0;j<48;j+=2){
      float2 pv = *(const float2*)&ppat[w*64+j];
      float2 q0 = *(const float2*)&w0[j];
      float2 q1 = *(const float2*)&w1p[j];
      float2 q2 = *(const float2*)&w2p[j];
      a0 += pv.x*q0.x + pv.y*q0.y;
      a1 += pv.x*q1.x + pv.y*q1.y;
      a2 += pv.x*q2.x + pv.y*q2.y;
    }
    float s1 = a0+a1+a2, s2 = a0*a0+a1*a1+a2*a2;
#pragma unroll
    for (int off=32;off>0;off>>=1){ s1+=__shfl_xor(s1,off); s2+=__shfl_xor(s2,off); }
    float u = s1*(1.f/C1);
    float inv = rsqrtf(s2*(1.f/C1)-u*u+1e-6f);
    int tok=(y>>1)*(S2*S2)+(x>>1)*S2+(z>>1);
    int p8=(y&1)*4+(x&1)*2+(z&1);
    unsigned short* hb = h1p + (size_t)(b*LL+tok)*KDIM + p8*C1;
    hb[lane]     = f2bf(gelu_exact((a0-u)*inv*g1[lane]     + b1[lane]));
    hb[lane+64]  = f2bf(gelu_exact((a1-u)*inv*g1[lane+64]  + b1[lane+64]));
    hb[lane+128] = f2bf(gelu_exact((a2-u)*inv*g1[lane+128] + b1[lane+128]));
  }
}

// -------- repack w2 (oc,ic,kpq) fp32 -> Bt bf16 [oc][p*192+ic] --------
__global__ __launch_bounds__(256) void repack_w2_kernel(const float* __restrict__ w2,
    unsigned short* __restrict__ out){
  int idx = blockIdx.x*256 + threadIdx.x;
  int oc = idx/KDIM; int r = idx-oc*KDIM; int p = r/C1; int ic = r-p*C1;
  out[idx] = f2bf(w2[(size_t)oc*KDIM + ic*8 + p]);
}

// -------- repack o_tw1 (i,o,kpq) fp32 -> Btd bf16 [kpq*192+o][p], p head-major --------
__global__ __launch_bounds__(256) void repack_tw1_kernel(const float* __restrict__ tw,
    unsigned short* __restrict__ out){
  int idx = blockIdx.x*256 + threadIdx.x;       // 1536*768
  int n = idx/C2; int p = idx-n*C2;
  int i = ((p&63)*NH) + (p>>6);                 // permuted channel: p = h*64+d -> c = d*12+h
  int kpq = n/C1, o = n-kpq*C1;
  out[idx] = f2bf(tw[(size_t)i*KDIM + o*8 + kpq]);
}

// -------- repack o_tw2 (i,c,kpq) fp32 -> Bt48 bf16 [n=c*8+kpq (pad 64)][i=192] --------
__global__ __launch_bounds__(256) void repack_tw2_kernel(const float* __restrict__ tw2,
    unsigned short* __restrict__ out){
  int idx = blockIdx.x*256 + threadIdx.x;       // 48 blocks: 64*192
  int n = idx/C1; int i = idx-n*C1;
  out[idx] = (n<48) ? f2bf(tw2[(size_t)i*48 + n]) : (unsigned short)0;
}

// ---------------- bf16 MFMA GEMM, tiles 128(M)x64(N), BK=32, 256 thr ----------------
// C[m][n] = sum_k A[m][k]*Bt[n][k].
// EPI=0: C fp32 row-major [M][Nd]
// EPI=1: debed scatter -> dh[(b*V1+v24)*192 + o], n = kpq*192+o
// EPI=2: convT2: n=c*8+kpq (n<48), out[(b*6+c)*V0+vox] = acc + tb2[c] + skip
template<int EPI>
__global__ __launch_bounds__(256) void gemm_bf16(const unsigned short* __restrict__ A,
    const unsigned short* __restrict__ Bt, float* __restrict__ C, int Nd, int Kd,
    const float* __restrict__ skipp, const float* __restrict__ tb2s){
  __shared__ __align__(16) unsigned short Al[128*32];
  __shared__ __align__(16) unsigned short Bl[64*32];
  int t=threadIdx.x, w=t>>6, lane=t&63;
  int g=lane>>4, l16=lane&15, r16=lane>>2, c16=lane&3;
  int m0=blockIdx.y*128, n0=blockIdx.x*64;
  int wm=w>>1, wn=w&1;
  float4v acc[4][2] = {};
  for (int kb=0;kb<Kd;kb+=32){
    __syncthreads();
#pragma unroll
    for (int cc=0;cc<3;cc++){
      int ch = w*3+cc;
      if (ch<8){
        const unsigned short* gp = A + (size_t)(m0+ch*16+r16)*Kd + kb + c16*8;
        load_lds16(gp, &Al[ch*512]);
      } else {
        const unsigned short* gp = Bt + (size_t)(n0+(ch-8)*16+r16)*Kd + kb + c16*8;
        load_lds16(gp, &Bl[(ch-8)*512]);
      }
    }
    __syncthreads();
    short8 af[4], bf[2];
#pragma unroll
    for (int mt=0;mt<4;mt++) af[mt] = *(const short8*)&Al[(wm*64+mt*16+l16)*32 + g*8];
#pragma unroll
    for (int nt=0;nt<2;nt++) bf[nt] = *(const short8*)&Bl[(wn*32+nt*16+l16)*32 + g*8];
#pragma unroll
    for (int mt=0;mt<4;mt++)
#pragma unroll
      for (int nt=0;nt<2;nt++)
        acc[mt][nt] = mfma32(af[mt], bf[nt], acc[mt][nt]);
  }
  if (EPI==0){
#pragma unroll
    for (int mt=0;mt<4;mt++){
      int mb = m0 + wm*64 + mt*16 + g*4;
#pragma unroll
      for (int nt=0;nt<2;nt++){
        int col = n0 + wn*32 + nt*16 + l16;
#pragma unroll
        for (int reg=0;reg<4;reg++)
          C[(size_t)(mb+reg)*Nd + col] = acc[mt][nt][reg];
      }
    }
  } else if (EPI==1){
    int kpq = (n0 + wn*32)/C1;
#pragma unroll
    for (int nt=0;nt<2;nt++){
      int n = n0 + wn*32 + nt*16 + l16;
      int o = n - kpq*C1;
#pragma unroll
      for (int mt=0;mt<4;mt++){
        int mb = m0 + wm*64 + mt*16 + g*4;
#pragma unroll
        for (int reg=0;reg<4;reg++){
          int m = mb + reg;
          int b = m / LL; int tok = m - b*LL;
          int h = tok/(S2*S2), ww=(tok/S2)%S2, d=tok%S2;
          int v24 = (2*h+((kpq>>2)&1))*(S1*S1) + (2*ww+((kpq>>1)&1))*S1 + (2*d+(kpq&1));
          C[(size_t)(b*V1+v24)*C1 + o] = acc[mt][nt][reg];
        }
      }
    }
  } else {
#pragma unroll
    for (int nt=0;nt<2;nt++){
      int n = n0 + wn*32 + nt*16 + l16;
      if (n < 48){
        int c = n>>3, kpq = n&7;
        float bias = tb2s[c];
#pragma unroll
        for (int mt=0;mt<4;mt++){
          int mb = m0 + wm*64 + mt*16 + g*4;
#pragma unroll
          for (int reg=0;reg<4;reg++){
            int m = mb + reg;
            int b = m / V1; int v24 = m - b*V1;
            int y24 = v24/(S1*S1), x24=(v24/S1)%S1, z24=v24%S1;
            int vox = (2*y24+((kpq>>2)&1))*(S0*S0) + (2*x24+((kpq>>1)&1))*S0 + 2*z24+(kpq&1);
            size_t oi = (size_t)(b*C0+c)*V0 + vox;
            C[oi] = acc[mt][nt][reg] + bias + skipp[oi];
          }
        }
      }
    }
  }
}

// ------------- LN over 768 per token, fp32 in -> bf16 out -------------
// mode 0: plain.  mode 1: rope + scale.  mode 2: head-major permuted gamma (input layout p=h*64+d)
__global__ __launch_bounds__(64) void ln768_bf_kernel(const float* __restrict__ in,
    const float* __restrict__ g, const float* __restrict__ bia,
    unsigned short* __restrict__ out, int mode, float scale){
  int tok = blockIdx.x, lane = threadIdx.x;
  const float* row = in + (size_t)tok*C2;
  unsigned short* orow = out + (size_t)tok*C2;
  float v[12]; float s1=0.f,s2=0.f;
#pragma unroll
  for (int i=0;i<12;i++){ float t=row[i*64+lane]; v[i]=t; s1+=t; s2+=t*t; }
#pragma unroll
  for (int off=32;off>0;off>>=1){ s1+=__shfl_xor(s1,off); s2+=__shfl_xor(s2,off); }
  float u=s1*(1.f/C2);
  float inv=rsqrtf(s2*(1.f/C2)-u*u+1e-6f);
  if (mode==0){
#pragma unroll
    for (int i=0;i<12;i++){ int j=i*64+lane; orow[j]=f2bf((v[i]-u)*inv*g[j]+bia[j]); }
  } else if (mode==2){
#pragma unroll
    for (int i=0;i<12;i++){
      int j=i*64+lane;
      int cj = ((j&63)*NH) + (j>>6);
      orow[j]=f2bf((v[i]-u)*inv*g[cj]+bia[cj]);
    }
  } else {
    int pos = tok % LL;
#pragma unroll
    for (int i=0;i<6;i++){
      int j=i*64+lane;
      float xn1=(v[i]-u)*inv*g[j]+bia[j];
      float xn2=(v[i+6]-u)*inv*g[j+384]+bia[j+384];
      float fr=(float)pos*__expf(-0.02398526139f*(float)j);  // 10000^{-j/384}
      float cs=cosf(fr), sn=sinf(fr);
      orow[j]     = f2bf((xn1*cs - xn2*sn)*scale);
      orow[j+384] = f2bf((xn2*cs + xn1*sn)*scale);
    }
  }
}

// ------------- V transpose: vbf [m][768] bf16 -> vT [(b*12+h)*64+d][1728] bf16 -------------
__global__ __launch_bounds__(256) void vtrans_kernel(const unsigned short* __restrict__ vbf,
    unsigned short* __restrict__ vT){
  int idx = blockIdx.x*256 + threadIdx.x;
  int token = idx % LL;
  int rest = idx / LL;
  int dc = rest & 7;
  int hb = rest >> 3;
  int h = hb % NH, b = hb / NH;
  const unsigned short* src = vbf + (size_t)(b*LL+token)*C2 + h*64 + dc*8;
  uint4 d4 = *(const uint4*)src;
  const unsigned short* s = (const unsigned short*)&d4;
#pragma unroll
  for (int i=0;i<8;i++)
    vT[(size_t)((b*NH+h)*HD + dc*8 + i)*LL + token] = s[i];
}

// ---------------- transposed MFMA flash attention ----------------
// S^T = K·Q^T so P^T (C-layout) is directly the B-fragment of 16x16x16 PV mfma.
// Q pre-scaled by 0.125*log2(e); exp in base-2 units throughout.
// out: ao[(b*LL+l)*768 + h*64 + d]  fp32 (head-major; LN perm-compensated downstream)
__global__ __launch_bounds__(256) void attn_kernel(const unsigned short* __restrict__ q,
    const unsigned short* __restrict__ k, const unsigned short* __restrict__ vt,
    float* __restrict__ o){
  __shared__ __align__(16) unsigned short Ks[64*64];   // [key][d], chunk-swizzled
  __shared__ __align__(16) unsigned short Vs[64*64];   // [d][key], chunk-swizzled
  __shared__ __align__(16) float Ot[4*16*72];          // per-wave transpose pad
  int qt=blockIdx.x, h=blockIdx.y, b=blockIdx.z;
  int t=threadIdx.x, w=t>>6, lane=t&63;
  int g=lane>>4, l16=lane&15;
  // Q fragments (B-operand): lane holds Q[q=l16][d=g*8..] ; one-time global read
  const unsigned short* qrow = q + (size_t)(b*LL + qt*64 + w*16 + l16)*C2 + h*64;
  short8 qA = *(const short8*)(qrow + g*8);
  short8 qB = *(const short8*)(qrow + 32 + g*8);
  const unsigned short* kbase = k + (size_t)(b*LL)*C2 + h*64;
  const unsigned short* vbase = vt + (size_t)((b*NH+h)*HD)*LL;
  int sub = lane>>3;                 // row-within-instr (0..7)
  int chs = (lane&7) ^ sub;          // swizzled 16B chunk
  float mrow = -1e30f, lrow = 0.f;
  float4v O4[4] = {};
  for (int kt=0; kt<LL/64; kt++){
    __syncthreads();
#pragma unroll
    for (int cc=0;cc<4;cc++){
      int ii = w*4+cc;
      if (ii<8){
        int key = kt*64 + ii*8 + sub;
        load_lds16(kbase + (size_t)key*C2 + chs*8, &Ks[ii*512]);
      } else {
        int d = (ii-8)*8 + sub;
        load_lds16(vbase + (size_t)d*LL + kt*64 + chs*8, &Vs[(ii-8)*512]);
      }
    }
    __syncthreads();
    // S^T tiles: rows=keys (nt*16+l16), cols=q
    float4v sc[4];
#pragma unroll
    for (int nt=0;nt<4;nt++){
      int row = nt*16 + l16;
      int sw = row & 7;
      short8 k1 = *(const short8*)&Ks[row*64 + ((g^sw))*8];
      short8 k2 = *(const short8*)&Ks[row*64 + (((4+g)^sw))*8];
      float4v z = {};
      z = mfma32(k1, qA, z);
      z = mfma32(k2, qB, z);
      sc[nt] = z;
    }
    // online softmax (per-lane scalar state; q = l16 replicated across quads)
    float mx = -1e30f;
#pragma unroll
    for (int nt=0;nt<4;nt++)
#pragma unroll
      for (int reg=0;reg<4;reg++) mx = fmaxf(mx, sc[nt][reg]);
    mx = fmaxf(mx, __shfl_xor(mx,16));
    mx = fmaxf(mx, __shfl_xor(mx,32));
    float mnew = fmaxf(mrow, mx);
    float alpha = exp2f(mrow - mnew);
    float ps = 0.f;
#pragma unroll
    for (int nt=0;nt<4;nt++)
#pragma unroll
      for (int reg=0;reg<4;reg++){ float e = exp2f(sc[nt][reg]-mnew); sc[nt][reg]=e; ps+=e; }
    ps += __shfl_xor(ps,16);
    ps += __shfl_xor(ps,32);
    lrow = lrow*alpha + ps;
    mrow = mnew;
#pragma unroll
    for (int dt=0;dt<4;dt++)
#pragma unroll
      for (int reg=0;reg<4;reg++) O4[dt][reg] *= alpha;
    // PV: O^T += V^T · P^T, P^T straight from registers
#pragma unroll
    for (int kc=0;kc<4;kc++){
      short4v pb;
      pb[0]=(short)f2bf(sc[kc][0]); pb[1]=(short)f2bf(sc[kc][1]);
      pb[2]=(short)f2bf(sc[kc][2]); pb[3]=(short)f2bf(sc[kc][3]);
#pragma unroll
      for (int dt=0;dt<4;dt++){
        int row = dt*16 + l16;
        int ch = (kc*2 + (g>>1)) ^ (row&7);
        short4v va = *(const short4v*)&Vs[row*64 + ch*8 + (g&1)*4];
        O4[dt] = mfma16(va, pb, O4[dt]);
      }
    }
  }
  // epilogue: normalize, transpose via wave-private LDS, coalesced store
  float invl = 1.f/lrow;
  float* ot = &Ot[w*1152];
#pragma unroll
  for (int dt=0;dt<4;dt++){
    float4 tv = make_float4(O4[dt][0]*invl, O4[dt][1]*invl, O4[dt][2]*invl, O4[dt][3]*invl);
    *(float4*)&ot[l16*72 + dt*16 + g*4] = tv;
  }
  int qq = lane>>2, c4 = lane&3;
  float* orow = o + (size_t)(b*LL + qt*64 + w*16 + qq)*C2 + h*64;
#pragma unroll
  for (int p=0;p<4;p++){
    float4 vv = *(float4*)&ot[qq*72 + p*16 + c4*4];
    *(float4*)&orow[p*16 + c4*4] = vv;
  }
}

// ---------------- LN over 192 + GELU: dh fp32 -> dhb bf16 ----------------
__global__ __launch_bounds__(64) void ln192_gelu_kernel(const float* __restrict__ x,
    const float* __restrict__ g, const float* __restrict__ bia, unsigned short* __restrict__ out){
  int vi=blockIdx.x; int lane=threadIdx.x;
  const float* row = x + (size_t)vi*C1;
  unsigned short* orow = out + (size_t)vi*C1;
  float v[3]; float s1=0.f,s2=0.f;
#pragma unroll
  for (int i=0;i<3;i++){ float t=row[i*64+lane]; v[i]=t; s1+=t; s2+=t*t; }
#pragma unroll
  for (int off=32;off>0;off>>=1){ s1+=__shfl_xor(s1,off); s2+=__shfl_xor(s2,off); }
  float u=s1*(1.f/C1), inv=rsqrtf(s2*(1.f/C1)-u*u+1e-6f);
#pragma unroll
  for (int i=0;i<3;i++){ int j=i*64+lane; float xn=(v[i]-u)*inv*g[j]+bia[j]; orow[j]=f2bf(gelu_exact(xn)); }
}

extern "C" void kernel_launch(void* const* d_in, const int* in_sizes, int n_in,
                              void* d_out, int out_size, void* d_ws, size_t ws_size,
                              hipStream_t stream){
  (void)in_sizes; (void)n_in; (void)out_size; (void)ws_size;
  const float* x    =(const float*)d_in[0];
  const float* skip =(const float*)d_in[1];
  const float* q_w1 =(const float*)d_in[2];
  const float* q_g1 =(const float*)d_in[3];
  const float* q_b1 =(const float*)d_in[4];
  const float* q_w2 =(const float*)d_in[5];
  const float* q_g2 =(const float*)d_in[6];
  const float* q_b2 =(const float*)d_in[7];
  const float* k_w1 =(const float*)d_in[8];
  const float* k_g1 =(const float*)d_in[9];
  const float* k_b1 =(const float*)d_in[10];
  const float* k_w2 =(const float*)d_in[11];
  const float* k_g2 =(const float*)d_in[12];
  const float* k_b2 =(const float*)d_in[13];
  const float* v_w1 =(const float*)d_in[14];
  const float* v_g1 =(const float*)d_in[15];
  const float* v_b1 =(const float*)d_in[16];
  const float* v_w2 =(const float*)d_in[17];
  const float* v_g2 =(const float*)d_in[18];
  const float* v_b2 =(const float*)d_in[19];
  const float* o_tw1=(const float*)d_in[20];
  const float* o_g  =(const float*)d_in[21];
  const float* o_b  =(const float*)d_in[22];
  const float* o_tw2=(const float*)d_in[23];
  const float* o_tb2=(const float*)d_in[24];
  const float* ns_w =(const float*)d_in[25];
  const float* ns_b =(const float*)d_in[26];
  const float* nx_w =(const float*)d_in[27];
  const float* nx_b =(const float*)d_in[28];
  const float* no_w =(const float*)d_in[29];
  const float* no_b =(const float*)d_in[30];
  float* out=(float*)d_out;

  char* W = (char*)d_ws;
  float*          lnS = (float*)(W + 0);                  //  5,308,416 B
  float*          lnX = (float*)(W + 5308416);            //  5,308,416 B
  unsigned short* h1p = (unsigned short*)(W + 10616832);  // 10,616,832 B
  unsigned short* w2t = (unsigned short*)(W + 21233664);  //  2,359,296 B
  float*          cf32= (float*)(W + 23592960);           // 10,616,832 B
  unsigned short* qbf = (unsigned short*)(W + 34209792);  //  5,308,416 B
  unsigned short* kbf = (unsigned short*)(W + 39518208);  //  5,308,416 B
  unsigned short* vbf = (unsigned short*)(W + 44826624);  //  5,308,416 B
  unsigned short* vT  = (unsigned short*)(W + 50135040);  //  5,308,416 B
  float*          ao  = (float*)(W + 55443456);           // 10,616,832 B
  unsigned short* aob = (unsigned short*)(W + 66060288);  //  5,308,416 B
  unsigned short* Btd = (unsigned short*)(W + 71368704);  //  2,359,296 B -> 73,728,000 total
  float*          dh  = (float*)(W + 0);                  // overlay lnS+lnX+h1p
  unsigned short* dhb = (unsigned short*)(W + 23592960);  // overlay cf32 (dead by then)
  unsigned short* Bt48= (unsigned short*)(W + 21233664);  // overlay w2t (dead by then)

  const float QSCALE = 0.125f*1.44269504089f;  // 1/sqrt(64) * log2(e)

  ln6_kernel<<<864,256,0,stream>>>(skip, ns_w, ns_b, lnS);
  ln6_kernel<<<864,256,0,stream>>>(x,    nx_w, nx_b, lnX);

  // q stem
  conv1_kernel<<<864,256,0,stream>>>(lnS, q_w1, q_g1, q_b1, h1p);
  repack_w2_kernel<<<4608,256,0,stream>>>(q_w2, w2t);
  gemm_bf16<0><<<dim3(12,27),256,0,stream>>>(h1p, w2t, cf32, C2, KDIM, nullptr, nullptr);
  ln768_bf_kernel<<<MDIM,64,0,stream>>>(cf32, q_g2, q_b2, qbf, 1, QSCALE);

  // k stem
  conv1_kernel<<<864,256,0,stream>>>(lnX, k_w1, k_g1, k_b1, h1p);
  repack_w2_kernel<<<4608,256,0,stream>>>(k_w2, w2t);
  gemm_bf16<0><<<dim3(12,27),256,0,stream>>>(h1p, w2t, cf32, C2, KDIM, nullptr, nullptr);
  ln768_bf_kernel<<<MDIM,64,0,stream>>>(cf32, k_g2, k_b2, kbf, 1, 1.0f);

  // v stem
  conv1_kernel<<<864,256,0,stream>>>(lnX, v_w1, v_g1, v_b1, h1p);
  repack_w2_kernel<<<4608,256,0,stream>>>(v_w2, w2t);
  gemm_bf16<0><<<dim3(12,27),256,0,stream>>>(h1p, w2t, cf32, C2, KDIM, nullptr, nullptr);
  ln768_bf_kernel<<<MDIM,64,0,stream>>>(cf32, v_g2, v_b2, vbf, 0, 1.0f);
  vtrans_kernel<<<1296,256,0,stream>>>(vbf, vT);

  // attention (writes head-major ao)
  attn_kernel<<<dim3(27,12,2),256,0,stream>>>(qbf, kbf, vT, ao);
  ln768_bf_kernel<<<MDIM,64,0,stream>>>(ao, no_w, no_b, aob, 2, 1.0f);

  // debed
  repack_tw1_kernel<<<4608,256,0,stream>>>(o_tw1, Btd);
  gemm_bf16<1><<<dim3(24,27),256,0,stream>>>(aob, Btd, dh, KDIM, C2, nullptr, nullptr);
  ln192_gelu_kernel<<<BB_*V1,64,0,stream>>>(dh, o_g, o_b, dhb);
  repack_tw2_kernel<<<48,256,0,stream>>>(o_tw2, Bt48);
  gemm_bf16<2><<<dim3(1,216),256,0,stream>>>(dhb, Bt48, out, 0, C1, skip, o_tb2);
}

// Round 4
// 413.453 us; speedup vs baseline: 3.6347x; 1.2374x over previous
//
#include <hip/hip_runtime.h>
#include <math.h>

#define BB_ 2
#define C0 6
#define S0 48
#define V0 (S0*S0*S0)      // 110592
#define C1 192
#define S1 24
#define V1 (S1*S1*S1)      // 13824
#define C2 768
#define S2 12
#define LL (S2*S2*S2)      // 1728
#define NH 12
#define HD 64
#define KDIM (C1*8)        // 1536
#define MDIM (BB_*LL)      // 3456

typedef __attribute__((ext_vector_type(8))) short short8;
typedef __attribute__((ext_vector_type(4))) short short4v;
typedef __attribute__((ext_vector_type(4))) float float4v;

static __device__ __forceinline__ float gelu_exact(float x){
  return 0.5f*x*(1.0f+erff(x*0.70710678118654752440f));
}
static __device__ __forceinline__ unsigned short f2bf(float f){
  unsigned int u = __float_as_uint(f);
  unsigned int r = (u + 0x7fffu + ((u>>16)&1u)) >> 16;
  return (unsigned short)r;
}
static __device__ __forceinline__ float bf2f(unsigned short u){
  return __uint_as_float(((unsigned int)u)<<16);
}
static __device__ __forceinline__ void load_lds16(const void* g, void* l){
  __builtin_amdgcn_global_load_lds((const __attribute__((address_space(1))) unsigned int*)g,
      (__attribute__((address_space(3))) unsigned int*)l, 16, 0, 0);
}
static __device__ __forceinline__ float4v mfma32(short8 a, short8 b, float4v c){
  return __builtin_amdgcn_mfma_f32_16x16x32_bf16(a,b,c,0,0,0);
}
static __device__ __forceinline__ float4v mfma16(short4v a, short4v b, float4v c){
#if __has_builtin(__builtin_amdgcn_mfma_f32_16x16x16bf16_1k)
  return __builtin_amdgcn_mfma_f32_16x16x16bf16_1k(a,b,c,0,0,0);
#else
  asm volatile("v_mfma_f32_16x16x16_bf16 %0, %1, %2, %0" : "+v"(c) : "v"(a), "v"(b));
  return c;
#endif
}

// ---------------- LN over 6 channels, fused for skip(z=0)/x(z=1), bf16 out ----------------
__global__ __launch_bounds__(256) void ln6_kernel(const float* __restrict__ skin,
    const float* __restrict__ xin,
    const float* __restrict__ nsw, const float* __restrict__ nsb,
    const float* __restrict__ nxw, const float* __restrict__ nxb,
    unsigned short* __restrict__ outS, unsigned short* __restrict__ outX){
  int z = blockIdx.y;
  const float* in = z ? xin : skin;
  const float* w  = z ? nxw : nsw;
  const float* bi = z ? nxb : nsb;
  unsigned short* out = z ? outX : outS;
  int idx = blockIdx.x*256 + threadIdx.x;
  int b = idx / V0, vox = idx - b*V0;
  const float* p = in + (size_t)b*(C0*V0) + vox;
  float v[C0]; float s=0.f;
#pragma unroll
  for (int c=0;c<C0;c++){ v[c]=p[(size_t)c*V0]; s+=v[c]; }
  float u = s*(1.f/C0);
  float ss=0.f;
#pragma unroll
  for (int c=0;c<C0;c++){ float d=v[c]-u; ss+=d*d; }
  float inv = rsqrtf(ss*(1.f/C0)+1e-6f);
  unsigned short* o = out + (size_t)b*(C0*V0) + vox;
#pragma unroll
  for (int c=0;c<C0;c++) o[(size_t)c*V0] = f2bf((v[c]-u)*inv*w[c]+bi[c]);
}

// ---------------- all weight repacks in one launch ----------------
__global__ __launch_bounds__(256) void repack_all_kernel(
    const float* __restrict__ qw2, const float* __restrict__ kw2, const float* __restrict__ vw2,
    const float* __restrict__ tw1, const float* __restrict__ tw2,
    unsigned short* __restrict__ w2tq, unsigned short* __restrict__ w2tk,
    unsigned short* __restrict__ w2tv, unsigned short* __restrict__ Btd,
    unsigned short* __restrict__ Bt48){
  int bx = blockIdx.x;
  if (bx < 13824){                       // 3 x 4608 : w2 repacks -> [oc][p*192+ic]
    int z = bx/4608;
    int idx = (bx - z*4608)*256 + threadIdx.x;
    const float* w2 = (z==0)?qw2:((z==1)?kw2:vw2);
    unsigned short* o = (z==0)?w2tq:((z==1)?w2tk:w2tv);
    int oc = idx/KDIM; int r = idx-oc*KDIM; int p = r/C1; int ic = r-p*C1;
    o[idx] = f2bf(w2[(size_t)oc*KDIM + ic*8 + p]);
  } else if (bx < 18432){                // tw1 -> [kpq*192+o][p head-major]
    int idx = (bx-13824)*256 + threadIdx.x;
    int n = idx/C2; int p = idx-n*C2;
    int i = ((p&63)*NH) + (p>>6);
    int kpq = n/C1, o2 = n-kpq*C1;
    Btd[idx] = f2bf(tw1[(size_t)i*KDIM + o2*8 + kpq]);
  } else {                               // 48 blocks: tw2 -> [n=c*8+kpq pad64][i]
    int idx = (bx-18432)*256 + threadIdx.x;
    int n = idx/C1; int i = idx-n*C1;
    Bt48[idx] = (n<48) ? f2bf(tw2[(size_t)i*48 + n]) : (unsigned short)0;
  }
}

// ------------- conv1 fused (z selects stem), bf16 in, bf16 im2col out -------------
__global__ __launch_bounds__(256) void conv1_kernel(
    const unsigned short* __restrict__ lnSb, const unsigned short* __restrict__ lnXb,
    const float* __restrict__ qw1, const float* __restrict__ qg1, const float* __restrict__ qb1,
    const float* __restrict__ kw1, const float* __restrict__ kg1, const float* __restrict__ kb1,
    const float* __restrict__ vw1, const float* __restrict__ vg1, const float* __restrict__ vb1,
    unsigned short* __restrict__ h1q, unsigned short* __restrict__ h1k,
    unsigned short* __restrict__ h1v){
  int z = blockIdx.z;
  const unsigned short* in = (z==0)? lnSb : lnXb;
  const float* w1 = (z==0)?qw1:((z==1)?kw1:vw1);
  const float* g1 = (z==0)?qg1:((z==1)?kg1:vg1);
  const float* b1 = (z==0)?qb1:((z==1)?kb1:vb1);
  unsigned short* h1p = (z==0)?h1q:((z==1)?h1k:h1v);
  __shared__ float ws[C1*50];
  __shared__ float ppat[4*64];
  int t = threadIdx.x, w = t>>6, lane = t&63;
  for (int i=t;i<C1*48;i+=256){ int oc=i/48, j=i-oc*48; ws[oc*50+j]=w1[i]; }
  __syncthreads();
  for (int v = blockIdx.x*4 + w; v < BB_*V1; v += 1728){
    int b = v / V1, v24 = v - b*V1;
    int y = v24/(S1*S1), x=(v24/S1)%S1, zz=v24%S1;
    if (lane < 48){
      int ic=lane>>3, p=lane&7;
      int vox48 = (2*y+((p>>2)&1))*(S0*S0) + (2*x+((p>>1)&1))*S0 + (2*zz+(p&1));
      ppat[w*64+lane] = bf2f(in[(size_t)(b*C0+ic)*V0 + vox48]);
    }
    float a0=0.f,a1=0.f,a2=0.f;
    const float* w0 = &ws[lane*50];
    const float* w1p = &ws[(lane+64)*50];
    const float* w2p = &ws[(lane+128)*50];
#pragma unroll
    for (int j=0;j<48;j+=2){
      float2 pv = *(const float2*)&ppat[w*64+j];
      float2 q0 = *(const float2*)&w0[j];
      float2 q1 = *(const float2*)&w1p[j];
      float2 q2 = *(const float2*)&w2p[j];
      a0 += pv.x*q0.x + pv.y*q0.y;
      a1 += pv.x*q1.x + pv.y*q1.y;
      a2 += pv.x*q2.x + pv.y*q2.y;
    }
    float s1 = a0+a1+a2, s2 = a0*a0+a1*a1+a2*a2;
#pragma unroll
    for (int off=32;off>0;off>>=1){ s1+=__shfl_xor(s1,off); s2+=__shfl_xor(s2,off); }
    float u = s1*(1.f/C1);
    float inv = rsqrtf(s2*(1.f/C1)-u*u+1e-6f);
    int tok=(y>>1)*(S2*S2)+(x>>1)*S2+(zz>>1);
    int p8=(y&1)*4+(x&1)*2+(zz&1);
    unsigned short* hb = h1p + (size_t)(b*LL+tok)*KDIM + p8*C1;
    hb[lane]     = f2bf(gelu_exact((a0-u)*inv*g1[lane]     + b1[lane]));
    hb[lane+64]  = f2bf(gelu_exact((a1-u)*inv*g1[lane+64]  + b1[lane+64]));
    hb[lane+128] = f2bf(gelu_exact((a2-u)*inv*g1[lane+128] + b1[lane+128]));
  }
}

// ---------------- fused stem GEMM (z selects A/B/C), 128x64 tiles, bf16 C ----------------
__global__ __launch_bounds__(256) void gemm_stem_kernel(
    const unsigned short* __restrict__ A0, const unsigned short* __restrict__ A1,
    const unsigned short* __restrict__ A2,
    const unsigned short* __restrict__ B0, const unsigned short* __restrict__ B1,
    const unsigned short* __restrict__ B2,
    unsigned short* __restrict__ Cq, unsigned short* __restrict__ Ck,
    unsigned short* __restrict__ Cv){
  int z = blockIdx.z;
  const unsigned short* A = (z==0)?A0:((z==1)?A1:A2);
  const unsigned short* Bt = (z==0)?B0:((z==1)?B1:B2);
  unsigned short* Cp = (z==0)?Cq:((z==1)?Ck:Cv);
  __shared__ __align__(16) unsigned short Al[128*32];
  __shared__ __align__(16) unsigned short Bl[64*32];
  int t=threadIdx.x, w=t>>6, lane=t&63;
  int g=lane>>4, l16=lane&15, r16=lane>>2, c16=lane&3;
  int m0=blockIdx.y*128, n0=blockIdx.x*64;
  int wm=w>>1, wn=w&1;
  float4v acc[4][2] = {};
  for (int kb=0;kb<KDIM;kb+=32){
    __syncthreads();
#pragma unroll
    for (int cc=0;cc<3;cc++){
      int ch = w*3+cc;
      if (ch<8){
        const unsigned short* gp = A + (size_t)(m0+ch*16+r16)*KDIM + kb + c16*8;
        load_lds16(gp, &Al[ch*512]);
      } else {
        const unsigned short* gp = Bt + (size_t)(n0+(ch-8)*16+r16)*KDIM + kb + c16*8;
        load_lds16(gp, &Bl[(ch-8)*512]);
      }
    }
    __syncthreads();
    short8 af[4], bf[2];
#pragma unroll
    for (int mt=0;mt<4;mt++) af[mt] = *(const short8*)&Al[(wm*64+mt*16+l16)*32 + g*8];
#pragma unroll
    for (int nt=0;nt<2;nt++) bf[nt] = *(const short8*)&Bl[(wn*32+nt*16+l16)*32 + g*8];
#pragma unroll
    for (int mt=0;mt<4;mt++)
#pragma unroll
      for (int nt=0;nt<2;nt++)
        acc[mt][nt] = mfma32(af[mt], bf[nt], acc[mt][nt]);
  }
#pragma unroll
  for (int mt=0;mt<4;mt++){
    int mb = m0 + wm*64 + mt*16 + g*4;
#pragma unroll
    for (int nt=0;nt<2;nt++){
      int col = n0 + wn*32 + nt*16 + l16;
#pragma unroll
      for (int reg=0;reg<4;reg++)
        Cp[(size_t)(mb+reg)*C2 + col] = f2bf(acc[mt][nt][reg]);
    }
  }
}

// ---------------- GEMM template for debed (EPI=1) / final convT2 (EPI=2), fp32 out ----------------
template<int EPI>
__global__ __launch_bounds__(256) void gemm_bf16(const unsigned short* __restrict__ A,
    const unsigned short* __restrict__ Bt, float* __restrict__ C, int Nd, int Kd,
    const float* __restrict__ skipp, const float* __restrict__ tb2s){
  __shared__ __align__(16) unsigned short Al[128*32];
  __shared__ __align__(16) unsigned short Bl[64*32];
  int t=threadIdx.x, w=t>>6, lane=t&63;
  int g=lane>>4, l16=lane&15, r16=lane>>2, c16=lane&3;
  int m0=blockIdx.y*128, n0=blockIdx.x*64;
  int wm=w>>1, wn=w&1;
  float4v acc[4][2] = {};
  for (int kb=0;kb<Kd;kb+=32){
    __syncthreads();
#pragma unroll
    for (int cc=0;cc<3;cc++){
      int ch = w*3+cc;
      if (ch<8){
        const unsigned short* gp = A + (size_t)(m0+ch*16+r16)*Kd + kb + c16*8;
        load_lds16(gp, &Al[ch*512]);
      } else {
        const unsigned short* gp = Bt + (size_t)(n0+(ch-8)*16+r16)*Kd + kb + c16*8;
        load_lds16(gp, &Bl[(ch-8)*512]);
      }
    }
    __syncthreads();
    short8 af[4], bf[2];
#pragma unroll
    for (int mt=0;mt<4;mt++) af[mt] = *(const short8*)&Al[(wm*64+mt*16+l16)*32 + g*8];
#pragma unroll
    for (int nt=0;nt<2;nt++) bf[nt] = *(const short8*)&Bl[(wn*32+nt*16+l16)*32 + g*8];
#pragma unroll
    for (int mt=0;mt<4;mt++)
#pragma unroll
      for (int nt=0;nt<2;nt++)
        acc[mt][nt] = mfma32(af[mt], bf[nt], acc[mt][nt]);
  }
  if (EPI==1){
    int kpq = (n0 + wn*32)/C1;
#pragma unroll
    for (int nt=0;nt<2;nt++){
      int n = n0 + wn*32 + nt*16 + l16;
      int o = n - kpq*C1;
#pragma unroll
      for (int mt=0;mt<4;mt++){
        int mb = m0 + wm*64 + mt*16 + g*4;
#pragma unroll
        for (int reg=0;reg<4;reg++){
          int m = mb + reg;
          int b = m / LL; int tok = m - b*LL;
          int h = tok/(S2*S2), ww=(tok/S2)%S2, d=tok%S2;
          int v24 = (2*h+((kpq>>2)&1))*(S1*S1) + (2*ww+((kpq>>1)&1))*S1 + (2*d+(kpq&1));
          C[(size_t)(b*V1+v24)*C1 + o] = acc[mt][nt][reg];
        }
      }
    }
  } else {
#pragma unroll
    for (int nt=0;nt<2;nt++){
      int n = n0 + wn*32 + nt*16 + l16;
      if (n < 48){
        int c = n>>3, kpq = n&7;
        float bias = tb2s[c];
#pragma unroll
        for (int mt=0;mt<4;mt++){
          int mb = m0 + wm*64 + mt*16 + g*4;
#pragma unroll
          for (int reg=0;reg<4;reg++){
            int m = mb + reg;
            int b = m / V1; int v24 = m - b*V1;
            int y24 = v24/(S1*S1), x24=(v24/S1)%S1, z24=v24%S1;
            int vox = (2*y24+((kpq>>2)&1))*(S0*S0) + (2*x24+((kpq>>1)&1))*S0 + 2*z24+(kpq&1);
            size_t oi = (size_t)(b*C0+c)*V0 + vox;
            C[oi] = acc[mt][nt][reg] + bias + skipp[oi];
          }
        }
      }
    }
  }
}

// ------------- fused stem LN over 768 (in-place bf16): z=0 q(rope,scale) z=1 k(rope) z=2 v -------------
__global__ __launch_bounds__(64) void ln768_stem_kernel(
    unsigned short* __restrict__ qb, unsigned short* __restrict__ kb2,
    unsigned short* __restrict__ vb,
    const float* __restrict__ qg, const float* __restrict__ qbi,
    const float* __restrict__ kg, const float* __restrict__ kbi,
    const float* __restrict__ vg, const float* __restrict__ vbi, float qscale){
  int z = blockIdx.y;
  unsigned short* buf = (z==0)?qb:((z==1)?kb2:vb);
  const float* g  = (z==0)?qg:((z==1)?kg:vg);
  const float* bia= (z==0)?qbi:((z==1)?kbi:vbi);
  float scale = (z==0)? qscale : 1.0f;
  int tok = blockIdx.x, lane = threadIdx.x;
  unsigned short* row = buf + (size_t)tok*C2;
  float v[12]; float s1=0.f,s2=0.f;
#pragma unroll
  for (int i=0;i<12;i++){ float t=bf2f(row[i*64+lane]); v[i]=t; s1+=t; s2+=t*t; }
#pragma unroll
  for (int off=32;off>0;off>>=1){ s1+=__shfl_xor(s1,off); s2+=__shfl_xor(s2,off); }
  float u=s1*(1.f/C2);
  float inv=rsqrtf(s2*(1.f/C2)-u*u+1e-6f);
  if (z==2){
#pragma unroll
    for (int i=0;i<12;i++){ int j=i*64+lane; row[j]=f2bf((v[i]-u)*inv*g[j]+bia[j]); }
  } else {
    int pos = tok % LL;
#pragma unroll
    for (int i=0;i<6;i++){
      int j=i*64+lane;
      float xn1=(v[i]-u)*inv*g[j]+bia[j];
      float xn2=(v[i+6]-u)*inv*g[j+384]+bia[j+384];
      float fr=(float)pos*__expf(-0.02398526139f*(float)j);  // 10000^{-j/384}
      float cs=cosf(fr), sn=sinf(fr);
      row[j]     = f2bf((xn1*cs - xn2*sn)*scale);
      row[j+384] = f2bf((xn2*cs + xn1*sn)*scale);
    }
  }
}

// ------------- post-attn LN over 768 (in-place bf16, head-major input, permuted gamma) -------------
__global__ __launch_bounds__(64) void ln768_post_kernel(unsigned short* __restrict__ x,
    const float* __restrict__ g, const float* __restrict__ bia){
  int tok = blockIdx.x, lane = threadIdx.x;
  unsigned short* row = x + (size_t)tok*C2;
  float v[12]; float s1=0.f,s2=0.f;
#pragma unroll
  for (int i=0;i<12;i++){ float t=bf2f(row[i*64+lane]); v[i]=t; s1+=t; s2+=t*t; }
#pragma unroll
  for (int off=32;off>0;off>>=1){ s1+=__shfl_xor(s1,off); s2+=__shfl_xor(s2,off); }
  float u=s1*(1.f/C2);
  float inv=rsqrtf(s2*(1.f/C2)-u*u+1e-6f);
#pragma unroll
  for (int i=0;i<12;i++){
    int j=i*64+lane;
    int cj = ((j&63)*NH) + (j>>6);
    row[j]=f2bf((v[i]-u)*inv*g[cj]+bia[cj]);
  }
}

// ------------- V transpose: vbf [m][768] bf16 -> vT [(b*12+h)*64+d][1728] bf16 -------------
__global__ __launch_bounds__(256) void vtrans_kernel(const unsigned short* __restrict__ vbf,
    unsigned short* __restrict__ vT){
  int idx = blockIdx.x*256 + threadIdx.x;
  int token = idx % LL;
  int rest = idx / LL;
  int dc = rest & 7;
  int hb = rest >> 3;
  int h = hb % NH, b = hb / NH;
  const unsigned short* src = vbf + (size_t)(b*LL+token)*C2 + h*64 + dc*8;
  uint4 d4 = *(const uint4*)src;
  const unsigned short* s = (const unsigned short*)&d4;
#pragma unroll
  for (int i=0;i<8;i++)
    vT[(size_t)((b*NH+h)*HD + dc*8 + i)*LL + token] = s[i];
}

// ---------------- transposed MFMA flash attention, split-K x2 ----------------
// Writes UNNORMALIZED partial O (fp32, head-major) + per-(split,b,h,q) m,l.
__global__ __launch_bounds__(256) void attn_kernel(const unsigned short* __restrict__ q,
    const unsigned short* __restrict__ k, const unsigned short* __restrict__ vt,
    float* __restrict__ opart, float* __restrict__ mbuf, float* __restrict__ lbuf){
  __shared__ __align__(16) unsigned char smem[18432];
  unsigned short* Ks = (unsigned short*)smem;       // [64 keys][64 d] chunk-swizzled
  unsigned short* Vs = Ks + 4096;                   // [64 d][64 keys]
  int qt=blockIdx.x, h=blockIdx.y;
  int b = blockIdx.z>>1, split = blockIdx.z&1;
  int t=threadIdx.x, w=t>>6, lane=t&63;
  int g=lane>>4, l16=lane&15;
  const unsigned short* qrow = q + (size_t)(b*LL + qt*64 + w*16 + l16)*C2 + h*64;
  short8 qA = *(const short8*)(qrow + g*8);
  short8 qB = *(const short8*)(qrow + 32 + g*8);
  const unsigned short* kbase = k + (size_t)(b*LL)*C2 + h*64;
  const unsigned short* vbase = vt + (size_t)((b*NH+h)*HD)*LL;
  int sub = lane>>3;
  int chs = (lane&7) ^ sub;
  float mrow = -1e30f, lrow = 0.f;
  float4v O4[4] = {};
  int ktb = split ? 14 : 0, kte = split ? 27 : 14;
  for (int kt=ktb; kt<kte; kt++){
    __syncthreads();
#pragma unroll
    for (int cc=0;cc<4;cc++){
      int ii = w*4+cc;
      if (ii<8){
        int key = kt*64 + ii*8 + sub;
        load_lds16(kbase + (size_t)key*C2 + chs*8, &Ks[ii*512]);
      } else {
        int d = (ii-8)*8 + sub;
        load_lds16(vbase + (size_t)d*LL + kt*64 + chs*8, &Vs[(ii-8)*512]);
      }
    }
    __syncthreads();
    float4v sc[4];
#pragma unroll
    for (int nt=0;nt<4;nt++){
      int row = nt*16 + l16;
      int sw = row & 7;
      short8 k1 = *(const short8*)&Ks[row*64 + ((g^sw))*8];
      short8 k2 = *(const short8*)&Ks[row*64 + (((4+g)^sw))*8];
      float4v z = {};
      z = mfma32(k1, qA, z);
      z = mfma32(k2, qB, z);
      sc[nt] = z;
    }
    float mx = -1e30f;
#pragma unroll
    for (int nt=0;nt<4;nt++)
#pragma unroll
      for (int reg=0;reg<4;reg++) mx = fmaxf(mx, sc[nt][reg]);
    mx = fmaxf(mx, __shfl_xor(mx,16));
    mx = fmaxf(mx, __shfl_xor(mx,32));
    float mnew = fmaxf(mrow, mx);
    float alpha = exp2f(mrow - mnew);
    float ps = 0.f;
#pragma unroll
    for (int nt=0;nt<4;nt++)
#pragma unroll
      for (int reg=0;reg<4;reg++){ float e = exp2f(sc[nt][reg]-mnew); sc[nt][reg]=e; ps+=e; }
    ps += __shfl_xor(ps,16);
    ps += __shfl_xor(ps,32);
    lrow = lrow*alpha + ps;
    mrow = mnew;
#pragma unroll
    for (int dt=0;dt<4;dt++)
#pragma unroll
      for (int reg=0;reg<4;reg++) O4[dt][reg] *= alpha;
#pragma unroll
    for (int kc=0;kc<4;kc++){
      short4v pb;
      pb[0]=(short)f2bf(sc[kc][0]); pb[1]=(short)f2bf(sc[kc][1]);
      pb[2]=(short)f2bf(sc[kc][2]); pb[3]=(short)f2bf(sc[kc][3]);
#pragma unroll
      for (int dt=0;dt<4;dt++){
        int row = dt*16 + l16;
        int ch = (kc*2 + (g>>1)) ^ (row&7);
        short4v va = *(const short4v*)&Vs[row*64 + ch*8 + (g&1)*4];
        O4[dt] = mfma16(va, pb, O4[dt]);
      }
    }
  }
  __syncthreads();                       // all compute done -> reuse smem for transpose
  float* Ot = (float*)smem;
  float* ot = Ot + w*1152;
#pragma unroll
  for (int dt=0;dt<4;dt++)
    *(float4*)&ot[l16*72 + dt*16 + g*4] =
        make_float4(O4[dt][0],O4[dt][1],O4[dt][2],O4[dt][3]);
  if (g==0){
    int qi = qt*64 + w*16 + l16;
    mbuf[((size_t)(b*2+split)*NH+h)*LL + qi] = mrow;
    lbuf[((size_t)(b*2+split)*NH+h)*LL + qi] = lrow;
  }
  int qq = lane>>2, c4 = lane&3;
  float* orow = opart + (size_t)split*MDIM*C2
              + (size_t)(b*LL + qt*64 + w*16 + qq)*C2 + h*64;
#pragma unroll
  for (int p=0;p<4;p++)
    *(float4*)&orow[p*16 + c4*4] = *(float4*)&ot[qq*72 + p*16 + c4*4];
}

// ---------------- combine the two K-splits -> bf16 aob ----------------
__global__ __launch_bounds__(256) void attn_combine_kernel(const float* __restrict__ opart,
    const float* __restrict__ mbuf, const float* __restrict__ lbuf,
    unsigned short* __restrict__ aob){
  int t=threadIdx.x, w=t>>6, lane=t&63;
  int m = blockIdx.x*4 + w;               // grid 864
  int b = m / LL, l = m - b*LL;
  const float* o0 = opart + (size_t)m*C2;
  const float* o1 = o0 + (size_t)MDIM*C2;
  unsigned short* orow = aob + (size_t)m*C2;
#pragma unroll
  for (int i=0;i<12;i++){
    float m0 = mbuf[((size_t)(b*2+0)*NH+i)*LL + l];
    float m1 = mbuf[((size_t)(b*2+1)*NH+i)*LL + l];
    float l0 = lbuf[((size_t)(b*2+0)*NH+i)*LL + l];
    float l1 = lbuf[((size_t)(b*2+1)*NH+i)*LL + l];
    float mm = fmaxf(m0,m1);
    float a0 = exp2f(m0-mm), a1 = exp2f(m1-mm);
    float inv = 1.f/(l0*a0 + l1*a1);
    int j = i*64+lane;
    orow[j] = f2bf((o0[j]*a0 + o1[j]*a1)*inv);
  }
}

// ---------------- LN over 192 + GELU: dh fp32 -> dhb bf16 ----------------
__global__ __launch_bounds__(64) void ln192_gelu_kernel(const float* __restrict__ x,
    const float* __restrict__ g, const float* __restrict__ bia, unsigned short* __restrict__ out){
  int vi=blockIdx.x; int lane=threadIdx.x;
  const float* row = x + (size_t)vi*C1;
  unsigned short* orow = out + (size_t)vi*C1;
  float v[3]; float s1=0.f,s2=0.f;
#pragma unroll
  for (int i=0;i<3;i++){ float t=row[i*64+lane]; v[i]=t; s1+=t; s2+=t*t; }
#pragma unroll
  for (int off=32;off>0;off>>=1){ s1+=__shfl_xor(s1,off); s2+=__shfl_xor(s2,off); }
  float u=s1*(1.f/C1), inv=rsqrtf(s2*(1.f/C1)-u*u+1e-6f);
#pragma unroll
  for (int i=0;i<3;i++){ int j=i*64+lane; float xn=(v[i]-u)*inv*g[j]+bia[j]; orow[j]=f2bf(gelu_exact(xn)); }
}

extern "C" void kernel_launch(void* const* d_in, const int* in_sizes, int n_in,
                              void* d_out, int out_size, void* d_ws, size_t ws_size,
                              hipStream_t stream){
  (void)in_sizes; (void)n_in; (void)out_size; (void)ws_size;
  const float* x    =(const float*)d_in[0];
  const float* skip =(const float*)d_in[1];
  const float* q_w1 =(const float*)d_in[2];
  const float* q_g1 =(const float*)d_in[3];
  const float* q_b1 =(const float*)d_in[4];
  const float* q_w2 =(const float*)d_in[5];
  const float* q_g2 =(const float*)d_in[6];
  const float* q_b2 =(const float*)d_in[7];
  const float* k_w1 =(const float*)d_in[8];
  const float* k_g1 =(const float*)d_in[9];
  const float* k_b1 =(const float*)d_in[10];
  const float* k_w2 =(const float*)d_in[11];
  const float* k_g2 =(const float*)d_in[12];
  const float* k_b2 =(const float*)d_in[13];
  const float* v_w1 =(const float*)d_in[14];
  const float* v_g1 =(const float*)d_in[15];
  const float* v_b1 =(const float*)d_in[16];
  const float* v_w2 =(const float*)d_in[17];
  const float* v_g2 =(const float*)d_in[18];
  const float* v_b2 =(const float*)d_in[19];
  const float* o_tw1=(const float*)d_in[20];
  const float* o_g  =(const float*)d_in[21];
  const float* o_b  =(const float*)d_in[22];
  const float* o_tw2=(const float*)d_in[23];
  const float* o_tb2=(const float*)d_in[24];
  const float* ns_w =(const float*)d_in[25];
  const float* ns_b =(const float*)d_in[26];
  const float* nx_w =(const float*)d_in[27];
  const float* nx_b =(const float*)d_in[28];
  const float* no_w =(const float*)d_in[29];
  const float* no_b =(const float*)d_in[30];
  float* out=(float*)d_out;

  char* W = (char*)d_ws;
  // layout (bytes):
  unsigned short* lnSb = (unsigned short*)(W + 0);          //  2,654,208
  unsigned short* lnXb = (unsigned short*)(W + 2654208);    //  2,654,208
  unsigned short* h1q  = (unsigned short*)(W + 5308416);    // 10,616,832
  unsigned short* h1k  = (unsigned short*)(W + 15925248);   // 10,616,832
  unsigned short* h1v  = (unsigned short*)(W + 26542080);   // 10,616,832
  unsigned short* w2tq = (unsigned short*)(W + 37158912);   //  2,359,296
  unsigned short* w2tk = (unsigned short*)(W + 39518208);   //  2,359,296
  unsigned short* w2tv = (unsigned short*)(W + 41877504);   //  2,359,296
  unsigned short* qbf  = (unsigned short*)(W + 44236800);   //  5,308,416
  unsigned short* kbf  = (unsigned short*)(W + 49545216);   //  5,308,416
  unsigned short* vbf  = (unsigned short*)(W + 54853632);   //  5,308,416
  unsigned short* vT   = (unsigned short*)(W + 60162048);   //  5,308,416
  unsigned short* aob  = (unsigned short*)(W + 65470464);   //  5,308,416
  unsigned short* Btd  = (unsigned short*)(W + 70778880);   //  2,359,296
  unsigned short* Bt48 = (unsigned short*)(W + 73138176);   //     24,576  (end 73,162,752)
  // overlays (regions dead by the time they're written):
  float* mbuf  = (float*)(W + 0);          // 331,776   (lnSb dead after conv1)
  float* lbuf  = (float*)(W + 331776);     // 331,776
  float* opart = (float*)(W + 5308416);    // 21,233,664 (h1q+h1k dead after stem gemm)
  float* dh    = (float*)(W + 5308416);    // 21,233,664 (opart dead after combine)
  unsigned short* dhb = (unsigned short*)(W + 26542080);  // 10,616,832 (h1v dead)

  const float QSCALE = 0.125f*1.44269504089f;  // 1/sqrt(64) * log2(e)

  // 1. channels-first LN(6) for skip and x
  ln6_kernel<<<dim3(864,2),256,0,stream>>>(skip, x, ns_w, ns_b, nx_w, nx_b, lnSb, lnXb);
  // 2. all weight repacks
  repack_all_kernel<<<18480,256,0,stream>>>(q_w2,k_w2,v_w2,o_tw1,o_tw2,
                                            w2tq,w2tk,w2tv,Btd,Bt48);
  // 3. conv1+LN+GELU for all three stems
  conv1_kernel<<<dim3(432,1,3),256,0,stream>>>(lnSb,lnXb,
      q_w1,q_g1,q_b1, k_w1,k_g1,k_b1, v_w1,v_g1,v_b1, h1q,h1k,h1v);
  // 4. fused stem GEMMs -> bf16 C
  gemm_stem_kernel<<<dim3(12,27,3),256,0,stream>>>(h1q,h1k,h1v,
      w2tq,w2tk,w2tv, qbf,kbf,vbf);
  // 5. stem LN (+rope/scale), in place
  ln768_stem_kernel<<<dim3(MDIM,3),64,0,stream>>>(qbf,kbf,vbf,
      q_g2,q_b2, k_g2,k_b2, v_g2,v_b2, QSCALE);
  // 6. V transpose
  vtrans_kernel<<<1296,256,0,stream>>>(vbf, vT);
  // 7. split-K attention
  attn_kernel<<<dim3(27,12,4),256,0,stream>>>(qbf, kbf, vT, opart, mbuf, lbuf);
  // 8. combine splits -> bf16 aob (head-major channels)
  attn_combine_kernel<<<864,256,0,stream>>>(opart, mbuf, lbuf, aob);
  // 9. post-attn LN in place
  ln768_post_kernel<<<MDIM,64,0,stream>>>(aob, no_w, no_b);
  // 10. debed convT1 as GEMM with scatter -> dh fp32
  gemm_bf16<1><<<dim3(24,27),256,0,stream>>>(aob, Btd, dh, KDIM, C2, nullptr, nullptr);
  // 11. LN(192)+GELU -> bf16
  ln192_gelu_kernel<<<BB_*V1,64,0,stream>>>(dh, o_g, o_b, dhb);
  // 12. convT2 + bias + residual -> out
  gemm_bf16<2><<<dim3(1,216),256,0,stream>>>(dhb, Bt48, out, 0, C1, skip, o_tb2);
}

// Round 5
// 391.993 us; speedup vs baseline: 3.8337x; 1.0547x over previous
//
#include <hip/hip_runtime.h>
#include <math.h>

#define BB_ 2
#define C0 6
#define S0 48
#define V0 (S0*S0*S0)      // 110592
#define C1 192
#define S1 24
#define V1 (S1*S1*S1)      // 13824
#define C2 768
#define S2 12
#define LL (S2*S2*S2)      // 1728
#define NH 12
#define HD 64
#define KDIM (C1*8)        // 1536
#define MDIM (BB_*LL)      // 3456

typedef __attribute__((ext_vector_type(8))) short short8;
typedef __attribute__((ext_vector_type(4))) short short4v;
typedef __attribute__((ext_vector_type(4))) float float4v;

static __device__ __forceinline__ float gelu_exact(float x){
  return 0.5f*x*(1.0f+erff(x*0.70710678118654752440f));
}
static __device__ __forceinline__ unsigned short f2bf(float f){
  unsigned int u = __float_as_uint(f);
  unsigned int r = (u + 0x7fffu + ((u>>16)&1u)) >> 16;
  return (unsigned short)r;
}
static __device__ __forceinline__ float bf2f(unsigned short u){
  return __uint_as_float(((unsigned int)u)<<16);
}
static __device__ __forceinline__ void load_lds16(const void* g, void* l){
  __builtin_amdgcn_global_load_lds((const __attribute__((address_space(1))) unsigned int*)g,
      (__attribute__((address_space(3))) unsigned int*)l, 16, 0, 0);
}
static __device__ __forceinline__ float4v mfma32(short8 a, short8 b, float4v c){
  return __builtin_amdgcn_mfma_f32_16x16x32_bf16(a,b,c,0,0,0);
}
static __device__ __forceinline__ float4v mfma16(short4v a, short4v b, float4v c){
#if __has_builtin(__builtin_amdgcn_mfma_f32_16x16x16bf16_1k)
  return __builtin_amdgcn_mfma_f32_16x16x16bf16_1k(a,b,c,0,0,0);
#else
  asm volatile("v_mfma_f32_16x16x16_bf16 %0, %1, %2, %0" : "+v"(c) : "v"(a), "v"(b));
  return c;
#endif
}

// ---------------- LN over 6 channels, fused for skip(z=0)/x(z=1), bf16 out ----------------
__global__ __launch_bounds__(256) void ln6_kernel(const float* __restrict__ skin,
    const float* __restrict__ xin,
    const float* __restrict__ nsw, const float* __restrict__ nsb,
    const float* __restrict__ nxw, const float* __restrict__ nxb,
    unsigned short* __restrict__ outS, unsigned short* __restrict__ outX){
  int z = blockIdx.y;
  const float* in = z ? xin : skin;
  const float* w  = z ? nxw : nsw;
  const float* bi = z ? nxb : nsb;
  unsigned short* out = z ? outX : outS;
  int idx = blockIdx.x*256 + threadIdx.x;
  int b = idx / V0, vox = idx - b*V0;
  const float* p = in + (size_t)b*(C0*V0) + vox;
  float v[C0]; float s=0.f;
#pragma unroll
  for (int c=0;c<C0;c++){ v[c]=p[(size_t)c*V0]; s+=v[c]; }
  float u = s*(1.f/C0);
  float ss=0.f;
#pragma unroll
  for (int c=0;c<C0;c++){ float d=v[c]-u; ss+=d*d; }
  float inv = rsqrtf(ss*(1.f/C0)+1e-6f);
  unsigned short* o = out + (size_t)b*(C0*V0) + vox;
#pragma unroll
  for (int c=0;c<C0;c++) o[(size_t)c*V0] = f2bf((v[c]-u)*inv*w[c]+bi[c]);
}

// ---------------- all weight repacks in one launch ----------------
__global__ __launch_bounds__(256) void repack_all_kernel(
    const float* __restrict__ qw2, const float* __restrict__ kw2, const float* __restrict__ vw2,
    const float* __restrict__ tw1, const float* __restrict__ tw2,
    unsigned short* __restrict__ w2tq, unsigned short* __restrict__ w2tk,
    unsigned short* __restrict__ w2tv, unsigned short* __restrict__ Btd,
    unsigned short* __restrict__ Bt48){
  int bx = blockIdx.x;
  if (bx < 13824){                       // 3 x 4608 : w2 repacks -> [oc][p*192+ic]
    int z = bx/4608;
    int idx = (bx - z*4608)*256 + threadIdx.x;
    const float* w2 = (z==0)?qw2:((z==1)?kw2:vw2);
    unsigned short* o = (z==0)?w2tq:((z==1)?w2tk:w2tv);
    int oc = idx/KDIM; int r = idx-oc*KDIM; int p = r/C1; int ic = r-p*C1;
    o[idx] = f2bf(w2[(size_t)oc*KDIM + ic*8 + p]);
  } else if (bx < 18432){                // tw1 -> [kpq*192+o][p head-major]
    int idx = (bx-13824)*256 + threadIdx.x;
    int n = idx/C2; int p = idx-n*C2;
    int i = ((p&63)*NH) + (p>>6);
    int kpq = n/C1, o2 = n-kpq*C1;
    Btd[idx] = f2bf(tw1[(size_t)i*KDIM + o2*8 + kpq]);
  } else {                               // 48 blocks: tw2 -> [n=c*8+kpq pad64][i]
    int idx = (bx-18432)*256 + threadIdx.x;
    int n = idx/C1; int i = idx-n*C1;
    Bt48[idx] = (n<48) ? f2bf(tw2[(size_t)i*48 + n]) : (unsigned short)0;
  }
}

// ------------- conv1 via MFMA (z selects stem), bf16 in, bf16 im2col out -------------
// C^T[oc][m] = sum_k W[oc][k] * A[m][k], K=48 (=32+16), then LN(192)+GELU per m.
// block: (b, y, xhalf); 12 x * 24 z = 288 voxels = 18 m-tiles of 16; waves stride tiles.
__global__ __launch_bounds__(256) void conv1_kernel(
    const unsigned short* __restrict__ lnSb, const unsigned short* __restrict__ lnXb,
    const float* __restrict__ qw1, const float* __restrict__ qg1, const float* __restrict__ qb1,
    const float* __restrict__ kw1, const float* __restrict__ kg1, const float* __restrict__ kb1,
    const float* __restrict__ vw1, const float* __restrict__ vg1, const float* __restrict__ vb1,
    unsigned short* __restrict__ h1q, unsigned short* __restrict__ h1k,
    unsigned short* __restrict__ h1v){
  int z = blockIdx.z;
  const unsigned short* in = (z==0)? lnSb : lnXb;
  const float* w1 = (z==0)?qw1:((z==1)?kw1:vw1);
  const float* g1 = (z==0)?qg1:((z==1)?kg1:vg1);
  const float* b1 = (z==0)?qb1:((z==1)?kb1:vb1);
  unsigned short* h1p = (z==0)?h1q:((z==1)?h1k:h1v);
  __shared__ unsigned short Wl[C1*56];   // rows padded 48->56 shorts
  __shared__ float Gl[C1], Bl2[C1];
  int t = threadIdx.x;
  int bx = blockIdx.x;                    // 0..95
  int b = bx / 48; int rem = bx - b*48; int y = rem >> 1; int xh = rem & 1;
  for (int i = t; i < C1*48; i += 256){
    int oc = i / 48, k2 = i - oc*48;
    Wl[oc*56 + k2] = f2bf(w1[i]);
  }
  if (t < C1){ Gl[t] = g1[t]; Bl2[t] = b1[t]; }
  __syncthreads();
  int w = t>>6, lane = t&63;
  int g = lane>>4, l16 = lane&15;
  const unsigned short* base = in + (size_t)b*C0*V0;
  int y2 = 2*y;
  for (int mt = w; mt < 18; mt += 4){
    int xo = mt / 3, zo = mt - xo*3;       // xo 0..5, zo 0..2
    int xv = xh*12 + xo*2 + (l16>>3);
    int zv = zo*8 + (l16&7);
    int x2 = 2*xv, z2 = 2*zv;
    // A-fragments (B-operand of mfma): lane = column m=l16
    union { short8 v; unsigned int u[4]; } aA;     // k=g*8+j  -> ic=g, p=j
    {
      size_t rb = (size_t)g*V0;
      aA.u[0] = *(const unsigned int*)&base[rb + (y2+0)*(S0*S0) + (x2+0)*S0 + z2];
      aA.u[1] = *(const unsigned int*)&base[rb + (y2+0)*(S0*S0) + (x2+1)*S0 + z2];
      aA.u[2] = *(const unsigned int*)&base[rb + (y2+1)*(S0*S0) + (x2+0)*S0 + z2];
      aA.u[3] = *(const unsigned int*)&base[rb + (y2+1)*(S0*S0) + (x2+1)*S0 + z2];
    }
    union { short4v v; unsigned int u[2]; } aB;    // k=32+g*4+j -> ic=4+(g>>1), p=(g&1)*4+j
    {
      size_t rb = (size_t)(4+(g>>1))*V0 + (y2+(g&1))*(S0*S0);
      aB.u[0] = *(const unsigned int*)&base[rb + (x2+0)*S0 + z2];
      aB.u[1] = *(const unsigned int*)&base[rb + (x2+1)*S0 + z2];
    }
    float4v acc[12];
#pragma unroll
    for (int ot=0; ot<12; ot++){
      short8  wA = *(const short8*)&Wl[(ot*16+l16)*56 + g*8];
      short4v wB = *(const short4v*)&Wl[(ot*16+l16)*56 + 32 + g*4];
      float4v a = {};
      a = mfma32(wA, aA.v, a);
      a = mfma16(wB, aB.v, a);
      acc[ot] = a;
    }
    // LN over 192 (sum over oc = across tiles/regs in-lane, then across quads)
    float s1=0.f, s2=0.f;
#pragma unroll
    for (int ot=0;ot<12;ot++)
#pragma unroll
      for (int reg=0;reg<4;reg++){ float v=acc[ot][reg]; s1+=v; s2+=v*v; }
    s1 += __shfl_xor(s1,16); s1 += __shfl_xor(s1,32);
    s2 += __shfl_xor(s2,16); s2 += __shfl_xor(s2,32);
    float u = s1*(1.f/C1);
    float inv = rsqrtf(s2*(1.f/C1)-u*u+1e-6f);
    int tok = (y>>1)*(S2*S2) + (xv>>1)*S2 + (zv>>1);
    int p8 = (y&1)*4 + (xv&1)*2 + (zv&1);
    unsigned short* hb = h1p + (size_t)(b*LL+tok)*KDIM + p8*C1;
#pragma unroll
    for (int ot=0; ot<12; ot++){
      int oc0 = ot*16 + g*4;
      float4 gg = *(const float4*)&Gl[oc0];
      float4 bb = *(const float4*)&Bl2[oc0];
      unsigned int lo, hi;
      {
        float x0 = gelu_exact((acc[ot][0]-u)*inv*gg.x+bb.x);
        float x1 = gelu_exact((acc[ot][1]-u)*inv*gg.y+bb.y);
        float x2e= gelu_exact((acc[ot][2]-u)*inv*gg.z+bb.z);
        float x3 = gelu_exact((acc[ot][3]-u)*inv*gg.w+bb.w);
        lo = (unsigned int)f2bf(x0) | ((unsigned int)f2bf(x1)<<16);
        hi = (unsigned int)f2bf(x2e) | ((unsigned int)f2bf(x3)<<16);
      }
      uint2 pk; pk.x=lo; pk.y=hi;
      *(uint2*)&hb[oc0] = pk;
    }
  }
}

// ---------------- fused stem GEMM (z selects A/B/C), 128x128 tiles, BK=32, bf16 C ----------------
__global__ __launch_bounds__(256) void gemm_stem_kernel(
    const unsigned short* __restrict__ A0, const unsigned short* __restrict__ A1,
    const unsigned short* __restrict__ A2,
    const unsigned short* __restrict__ B0, const unsigned short* __restrict__ B1,
    const unsigned short* __restrict__ B2,
    unsigned short* __restrict__ Cq, unsigned short* __restrict__ Ck,
    unsigned short* __restrict__ Cv){
  int z = blockIdx.z;
  const unsigned short* A = (z==0)?A0:((z==1)?A1:A2);
  const unsigned short* Bt = (z==0)?B0:((z==1)?B1:B2);
  unsigned short* Cp = (z==0)?Cq:((z==1)?Ck:Cv);
  __shared__ __align__(16) unsigned short Al[128*32];
  __shared__ __align__(16) unsigned short Bl[128*32];
  int t=threadIdx.x, w=t>>6, lane=t&63;
  int g=lane>>4, l16=lane&15, r16=lane>>2, c16=lane&3;
  int m0=blockIdx.y*128, n0=blockIdx.x*128;
  int wm=w>>1, wn=w&1;
  float4v acc[4][4] = {};
  for (int kb=0;kb<KDIM;kb+=32){
    __syncthreads();
#pragma unroll
    for (int cc=0;cc<4;cc++){
      int ch = w*4+cc;
      if (ch<8){
        const unsigned short* gp = A + (size_t)(m0+ch*16+r16)*KDIM + kb + c16*8;
        load_lds16(gp, &Al[ch*512]);
      } else {
        const unsigned short* gp = Bt + (size_t)(n0+(ch-8)*16+r16)*KDIM + kb + c16*8;
        load_lds16(gp, &Bl[(ch-8)*512]);
      }
    }
    __syncthreads();
    short8 af[4], bf[4];
#pragma unroll
    for (int mt=0;mt<4;mt++) af[mt] = *(const short8*)&Al[(wm*64+mt*16+l16)*32 + g*8];
#pragma unroll
    for (int nt=0;nt<4;nt++) bf[nt] = *(const short8*)&Bl[(wn*64+nt*16+l16)*32 + g*8];
#pragma unroll
    for (int mt=0;mt<4;mt++)
#pragma unroll
      for (int nt=0;nt<4;nt++)
        acc[mt][nt] = mfma32(af[mt], bf[nt], acc[mt][nt]);
  }
#pragma unroll
  for (int mt=0;mt<4;mt++){
    int mb = m0 + wm*64 + mt*16 + g*4;
#pragma unroll
    for (int nt=0;nt<4;nt++){
      int col = n0 + wn*64 + nt*16 + l16;
#pragma unroll
      for (int reg=0;reg<4;reg++)
        Cp[(size_t)(mb+reg)*C2 + col] = f2bf(acc[mt][nt][reg]);
    }
  }
}

// ---------------- GEMM template for debed (EPI=1) / final convT2 (EPI=2), fp32 out ----------------
template<int EPI>
__global__ __launch_bounds__(256) void gemm_bf16(const unsigned short* __restrict__ A,
    const unsigned short* __restrict__ Bt, float* __restrict__ C, int Nd, int Kd,
    const float* __restrict__ skipp, const float* __restrict__ tb2s){
  __shared__ __align__(16) unsigned short Al[128*32];
  __shared__ __align__(16) unsigned short Bl[64*32];
  int t=threadIdx.x, w=t>>6, lane=t&63;
  int g=lane>>4, l16=lane&15, r16=lane>>2, c16=lane&3;
  int m0=blockIdx.y*128, n0=blockIdx.x*64;
  int wm=w>>1, wn=w&1;
  float4v acc[4][2] = {};
  for (int kb=0;kb<Kd;kb+=32){
    __syncthreads();
#pragma unroll
    for (int cc=0;cc<3;cc++){
      int ch = w*3+cc;
      if (ch<8){
        const unsigned short* gp = A + (size_t)(m0+ch*16+r16)*Kd + kb + c16*8;
        load_lds16(gp, &Al[ch*512]);
      } else {
        const unsigned short* gp = Bt + (size_t)(n0+(ch-8)*16+r16)*Kd + kb + c16*8;
        load_lds16(gp, &Bl[(ch-8)*512]);
      }
    }
    __syncthreads();
    short8 af[4], bf[2];
#pragma unroll
    for (int mt=0;mt<4;mt++) af[mt] = *(const short8*)&Al[(wm*64+mt*16+l16)*32 + g*8];
#pragma unroll
    for (int nt=0;nt<2;nt++) bf[nt] = *(const short8*)&Bl[(wn*32+nt*16+l16)*32 + g*8];
#pragma unroll
    for (int mt=0;mt<4;mt++)
#pragma unroll
      for (int nt=0;nt<2;nt++)
        acc[mt][nt] = mfma32(af[mt], bf[nt], acc[mt][nt]);
  }
  if (EPI==1){
    int kpq = (n0 + wn*32)/C1;
#pragma unroll
    for (int nt=0;nt<2;nt++){
      int n = n0 + wn*32 + nt*16 + l16;
      int o = n - kpq*C1;
#pragma unroll
      for (int mt=0;mt<4;mt++){
        int mb = m0 + wm*64 + mt*16 + g*4;
#pragma unroll
        for (int reg=0;reg<4;reg++){
          int m = mb + reg;
          int b = m / LL; int tok = m - b*LL;
          int h = tok/(S2*S2), ww=(tok/S2)%S2, d=tok%S2;
          int v24 = (2*h+((kpq>>2)&1))*(S1*S1) + (2*ww+((kpq>>1)&1))*S1 + (2*d+(kpq&1));
          C[(size_t)(b*V1+v24)*C1 + o] = acc[mt][nt][reg];
        }
      }
    }
  } else {
#pragma unroll
    for (int nt=0;nt<2;nt++){
      int n = n0 + wn*32 + nt*16 + l16;
      if (n < 48){
        int c = n>>3, kpq = n&7;
        float bias = tb2s[c];
#pragma unroll
        for (int mt=0;mt<4;mt++){
          int mb = m0 + wm*64 + mt*16 + g*4;
#pragma unroll
          for (int reg=0;reg<4;reg++){
            int m = mb + reg;
            int b = m / V1; int v24 = m - b*V1;
            int y24 = v24/(S1*S1), x24=(v24/S1)%S1, z24=v24%S1;
            int vox = (2*y24+((kpq>>2)&1))*(S0*S0) + (2*x24+((kpq>>1)&1))*S0 + 2*z24+(kpq&1);
            size_t oi = (size_t)(b*C0+c)*V0 + vox;
            C[oi] = acc[mt][nt][reg] + bias + skipp[oi];
          }
        }
      }
    }
  }
}

// ------------- fused stem LN over 768 (in-place bf16): z=0 q(rope,scale) z=1 k(rope) z=2 v -------------
__global__ __launch_bounds__(64) void ln768_stem_kernel(
    unsigned short* __restrict__ qb, unsigned short* __restrict__ kb2,
    unsigned short* __restrict__ vb,
    const float* __restrict__ qg, const float* __restrict__ qbi,
    const float* __restrict__ kg, const float* __restrict__ kbi,
    const float* __restrict__ vg, const float* __restrict__ vbi, float qscale){
  int z = blockIdx.y;
  unsigned short* buf = (z==0)?qb:((z==1)?kb2:vb);
  const float* g  = (z==0)?qg:((z==1)?kg:vg);
  const float* bia= (z==0)?qbi:((z==1)?kbi:vbi);
  float scale = (z==0)? qscale : 1.0f;
  int tok = blockIdx.x, lane = threadIdx.x;
  unsigned short* row = buf + (size_t)tok*C2;
  float v[12]; float s1=0.f,s2=0.f;
#pragma unroll
  for (int i=0;i<12;i++){ float t=bf2f(row[i*64+lane]); v[i]=t; s1+=t; s2+=t*t; }
#pragma unroll
  for (int off=32;off>0;off>>=1){ s1+=__shfl_xor(s1,off); s2+=__shfl_xor(s2,off); }
  float u=s1*(1.f/C2);
  float inv=rsqrtf(s2*(1.f/C2)-u*u+1e-6f);
  if (z==2){
#pragma unroll
    for (int i=0;i<12;i++){ int j=i*64+lane; row[j]=f2bf((v[i]-u)*inv*g[j]+bia[j]); }
  } else {
    int pos = tok % LL;
#pragma unroll
    for (int i=0;i<6;i++){
      int j=i*64+lane;
      float xn1=(v[i]-u)*inv*g[j]+bia[j];
      float xn2=(v[i+6]-u)*inv*g[j+384]+bia[j+384];
      float fr=(float)pos*__expf(-0.02398526139f*(float)j);  // 10000^{-j/384}
      float cs=cosf(fr), sn=sinf(fr);
      row[j]     = f2bf((xn1*cs - xn2*sn)*scale);
      row[j+384] = f2bf((xn2*cs + xn1*sn)*scale);
    }
  }
}

// ------------- post-attn LN over 768 (in-place bf16, head-major input, permuted gamma) -------------
__global__ __launch_bounds__(64) void ln768_post_kernel(unsigned short* __restrict__ x,
    const float* __restrict__ g, const float* __restrict__ bia){
  int tok = blockIdx.x, lane = threadIdx.x;
  unsigned short* row = x + (size_t)tok*C2;
  float v[12]; float s1=0.f,s2=0.f;
#pragma unroll
  for (int i=0;i<12;i++){ float t=bf2f(row[i*64+lane]); v[i]=t; s1+=t; s2+=t*t; }
#pragma unroll
  for (int off=32;off>0;off>>=1){ s1+=__shfl_xor(s1,off); s2+=__shfl_xor(s2,off); }
  float u=s1*(1.f/C2);
  float inv=rsqrtf(s2*(1.f/C2)-u*u+1e-6f);
#pragma unroll
  for (int i=0;i<12;i++){
    int j=i*64+lane;
    int cj = ((j&63)*NH) + (j>>6);
    row[j]=f2bf((v[i]-u)*inv*g[cj]+bia[cj]);
  }
}

// ------------- V transpose: vbf [m][768] bf16 -> vT [(b*12+h)*64+d][1728] bf16 -------------
__global__ __launch_bounds__(256) void vtrans_kernel(const unsigned short* __restrict__ vbf,
    unsigned short* __restrict__ vT){
  int idx = blockIdx.x*256 + threadIdx.x;
  int token = idx % LL;
  int rest = idx / LL;
  int dc = rest & 7;
  int hb = rest >> 3;
  int h = hb % NH, b = hb / NH;
  const unsigned short* src = vbf + (size_t)(b*LL+token)*C2 + h*64 + dc*8;
  uint4 d4 = *(const uint4*)src;
  const unsigned short* s = (const unsigned short*)&d4;
#pragma unroll
  for (int i=0;i<8;i++)
    vT[(size_t)((b*NH+h)*HD + dc*8 + i)*LL + token] = s[i];
}

// ---------------- transposed MFMA flash attention, split-K x2 ----------------
__global__ __launch_bounds__(256) void attn_kernel(const unsigned short* __restrict__ q,
    const unsigned short* __restrict__ k, const unsigned short* __restrict__ vt,
    float* __restrict__ opart, float* __restrict__ mbuf, float* __restrict__ lbuf){
  __shared__ __align__(16) unsigned char smem[18432];
  unsigned short* Ks = (unsigned short*)smem;       // [64 keys][64 d] chunk-swizzled
  unsigned short* Vs = Ks + 4096;                   // [64 d][64 keys]
  int qt=blockIdx.x, h=blockIdx.y;
  int b = blockIdx.z>>1, split = blockIdx.z&1;
  int t=threadIdx.x, w=t>>6, lane=t&63;
  int g=lane>>4, l16=lane&15;
  const unsigned short* qrow = q + (size_t)(b*LL + qt*64 + w*16 + l16)*C2 + h*64;
  short8 qA = *(const short8*)(qrow + g*8);
  short8 qB = *(const short8*)(qrow + 32 + g*8);
  const unsigned short* kbase = k + (size_t)(b*LL)*C2 + h*64;
  const unsigned short* vbase = vt + (size_t)((b*NH+h)*HD)*LL;
  int sub = lane>>3;
  int chs = (lane&7) ^ sub;
  float mrow = -1e30f, lrow = 0.f;
  float4v O4[4] = {};
  int ktb = split ? 14 : 0, kte = split ? 27 : 14;
  for (int kt=ktb; kt<kte; kt++){
    __syncthreads();
#pragma unroll
    for (int cc=0;cc<4;cc++){
      int ii = w*4+cc;
      if (ii<8){
        int key = kt*64 + ii*8 + sub;
        load_lds16(kbase + (size_t)key*C2 + chs*8, &Ks[ii*512]);
      } else {
        int d = (ii-8)*8 + sub;
        load_lds16(vbase + (size_t)d*LL + kt*64 + chs*8, &Vs[(ii-8)*512]);
      }
    }
    __syncthreads();
    float4v sc[4];
#pragma unroll
    for (int nt=0;nt<4;nt++){
      int row = nt*16 + l16;
      int sw = row & 7;
      short8 k1 = *(const short8*)&Ks[row*64 + ((g^sw))*8];
      short8 k2 = *(const short8*)&Ks[row*64 + (((4+g)^sw))*8];
      float4v z = {};
      z = mfma32(k1, qA, z);
      z = mfma32(k2, qB, z);
      sc[nt] = z;
    }
    float mx = -1e30f;
#pragma unroll
    for (int nt=0;nt<4;nt++)
#pragma unroll
      for (int reg=0;reg<4;reg++) mx = fmaxf(mx, sc[nt][reg]);
    mx = fmaxf(mx, __shfl_xor(mx,16));
    mx = fmaxf(mx, __shfl_xor(mx,32));
    float mnew = fmaxf(mrow, mx);
    float alpha = exp2f(mrow - mnew);
    float ps = 0.f;
#pragma unroll
    for (int nt=0;nt<4;nt++)
#pragma unroll
      for (int reg=0;reg<4;reg++){ float e = exp2f(sc[nt][reg]-mnew); sc[nt][reg]=e; ps+=e; }
    ps += __shfl_xor(ps,16);
    ps += __shfl_xor(ps,32);
    lrow = lrow*alpha + ps;
    mrow = mnew;
#pragma unroll
    for (int dt=0;dt<4;dt++)
#pragma unroll
      for (int reg=0;reg<4;reg++) O4[dt][reg] *= alpha;
#pragma unroll
    for (int kc=0;kc<4;kc++){
      short4v pb;
      pb[0]=(short)f2bf(sc[kc][0]); pb[1]=(short)f2bf(sc[kc][1]);
      pb[2]=(short)f2bf(sc[kc][2]); pb[3]=(short)f2bf(sc[kc][3]);
#pragma unroll
      for (int dt=0;dt<4;dt++){
        int row = dt*16 + l16;
        int ch = (kc*2 + (g>>1)) ^ (row&7);
        short4v va = *(const short4v*)&Vs[row*64 + ch*8 + (g&1)*4];
        O4[dt] = mfma16(va, pb, O4[dt]);
      }
    }
  }
  __syncthreads();
  float* Ot = (float*)smem;
  float* ot = Ot + w*1152;
#pragma unroll
  for (int dt=0;dt<4;dt++)
    *(float4*)&ot[l16*72 + dt*16 + g*4] =
        make_float4(O4[dt][0],O4[dt][1],O4[dt][2],O4[dt][3]);
  if (g==0){
    int qi = qt*64 + w*16 + l16;
    mbuf[((size_t)(b*2+split)*NH+h)*LL + qi] = mrow;
    lbuf[((size_t)(b*2+split)*NH+h)*LL + qi] = lrow;
  }
  int qq = lane>>2, c4 = lane&3;
  float* orow = opart + (size_t)split*MDIM*C2
              + (size_t)(b*LL + qt*64 + w*16 + qq)*C2 + h*64;
#pragma unroll
  for (int p=0;p<4;p++)
    *(float4*)&orow[p*16 + c4*4] = *(float4*)&ot[qq*72 + p*16 + c4*4];
}

// ---------------- combine the two K-splits -> bf16 aob ----------------
__global__ __launch_bounds__(256) void attn_combine_kernel(const float* __restrict__ opart,
    const float* __restrict__ mbuf, const float* __restrict__ lbuf,
    unsigned short* __restrict__ aob){
  int t=threadIdx.x, w=t>>6, lane=t&63;
  int m = blockIdx.x*4 + w;               // grid 864
  int b = m / LL, l = m - b*LL;
  const float* o0 = opart + (size_t)m*C2;
  const float* o1 = o0 + (size_t)MDIM*C2;
  unsigned short* orow = aob + (size_t)m*C2;
#pragma unroll
  for (int i=0;i<12;i++){
    float m0 = mbuf[((size_t)(b*2+0)*NH+i)*LL + l];
    float m1 = mbuf[((size_t)(b*2+1)*NH+i)*LL + l];
    float l0 = lbuf[((size_t)(b*2+0)*NH+i)*LL + l];
    float l1 = lbuf[((size_t)(b*2+1)*NH+i)*LL + l];
    float mm = fmaxf(m0,m1);
    float a0 = exp2f(m0-mm), a1 = exp2f(m1-mm);
    float inv = 1.f/(l0*a0 + l1*a1);
    int j = i*64+lane;
    orow[j] = f2bf((o0[j]*a0 + o1[j]*a1)*inv);
  }
}

// ---------------- LN over 192 + GELU: dh fp32 -> dhb bf16 ----------------
__global__ __launch_bounds__(64) void ln192_gelu_kernel(const float* __restrict__ x,
    const float* __restrict__ g, const float* __restrict__ bia, unsigned short* __restrict__ out){
  int vi=blockIdx.x; int lane=threadIdx.x;
  const float* row = x + (size_t)vi*C1;
  unsigned short* orow = out + (size_t)vi*C1;
  float v[3]; float s1=0.f,s2=0.f;
#pragma unroll
  for (int i=0;i<3;i++){ float t=row[i*64+lane]; v[i]=t; s1+=t; s2+=t*t; }
#pragma unroll
  for (int off=32;off>0;off>>=1){ s1+=__shfl_xor(s1,off); s2+=__shfl_xor(s2,off); }
  float u=s1*(1.f/C1), inv=rsqrtf(s2*(1.f/C1)-u*u+1e-6f);
#pragma unroll
  for (int i=0;i<3;i++){ int j=i*64+lane; float xn=(v[i]-u)*inv*g[j]+bia[j]; orow[j]=f2bf(gelu_exact(xn)); }
}

extern "C" void kernel_launch(void* const* d_in, const int* in_sizes, int n_in,
                              void* d_out, int out_size, void* d_ws, size_t ws_size,
                              hipStream_t stream){
  (void)in_sizes; (void)n_in; (void)out_size; (void)ws_size;
  const float* x    =(const float*)d_in[0];
  const float* skip =(const float*)d_in[1];
  const float* q_w1 =(const float*)d_in[2];
  const float* q_g1 =(const float*)d_in[3];
  const float* q_b1 =(const float*)d_in[4];
  const float* q_w2 =(const float*)d_in[5];
  const float* q_g2 =(const float*)d_in[6];
  const float* q_b2 =(const float*)d_in[7];
  const float* k_w1 =(const float*)d_in[8];
  const float* k_g1 =(const float*)d_in[9];
  const float* k_b1 =(const float*)d_in[10];
  const float* k_w2 =(const float*)d_in[11];
  const float* k_g2 =(const float*)d_in[12];
  const float* k_b2 =(const float*)d_in[13];
  const float* v_w1 =(const float*)d_in[14];
  const float* v_g1 =(const float*)d_in[15];
  const float* v_b1 =(const float*)d_in[16];
  const float* v_w2 =(const float*)d_in[17];
  const float* v_g2 =(const float*)d_in[18];
  const float* v_b2 =(const float*)d_in[19];
  const float* o_tw1=(const float*)d_in[20];
  const float* o_g  =(const float*)d_in[21];
  const float* o_b  =(const float*)d_in[22];
  const float* o_tw2=(const float*)d_in[23];
  const float* o_tb2=(const float*)d_in[24];
  const float* ns_w =(const float*)d_in[25];
  const float* ns_b =(const float*)d_in[26];
  const float* nx_w =(const float*)d_in[27];
  const float* nx_b =(const float*)d_in[28];
  const float* no_w =(const float*)d_in[29];
  const float* no_b =(const float*)d_in[30];
  float* out=(float*)d_out;

  char* W = (char*)d_ws;
  unsigned short* lnSb = (unsigned short*)(W + 0);          //  2,654,208
  unsigned short* lnXb = (unsigned short*)(W + 2654208);    //  2,654,208
  unsigned short* h1q  = (unsigned short*)(W + 5308416);    // 10,616,832
  unsigned short* h1k  = (unsigned short*)(W + 15925248);   // 10,616,832
  unsigned short* h1v  = (unsigned short*)(W + 26542080);   // 10,616,832
  unsigned short* w2tq = (unsigned short*)(W + 37158912);   //  2,359,296
  unsigned short* w2tk = (unsigned short*)(W + 39518208);   //  2,359,296
  unsigned short* w2tv = (unsigned short*)(W + 41877504);   //  2,359,296
  unsigned short* qbf  = (unsigned short*)(W + 44236800);   //  5,308,416
  unsigned short* kbf  = (unsigned short*)(W + 49545216);   //  5,308,416
  unsigned short* vbf  = (unsigned short*)(W + 54853632);   //  5,308,416
  unsigned short* vT   = (unsigned short*)(W + 60162048);   //  5,308,416
  unsigned short* aob  = (unsigned short*)(W + 65470464);   //  5,308,416
  unsigned short* Btd  = (unsigned short*)(W + 70778880);   //  2,359,296
  unsigned short* Bt48 = (unsigned short*)(W + 73138176);   //     24,576
  // overlays:
  float* mbuf  = (float*)(W + 0);          // lnSb dead after conv1
  float* lbuf  = (float*)(W + 331776);
  float* opart = (float*)(W + 5308416);    // h1q+h1k dead after stem gemm
  float* dh    = (float*)(W + 5308416);    // opart dead after combine
  unsigned short* dhb = (unsigned short*)(W + 26542080);  // h1v dead

  const float QSCALE = 0.125f*1.44269504089f;  // 1/sqrt(64) * log2(e)

  ln6_kernel<<<dim3(864,2),256,0,stream>>>(skip, x, ns_w, ns_b, nx_w, nx_b, lnSb, lnXb);
  repack_all_kernel<<<18480,256,0,stream>>>(q_w2,k_w2,v_w2,o_tw1,o_tw2,
                                            w2tq,w2tk,w2tv,Btd,Bt48);
  conv1_kernel<<<dim3(96,1,3),256,0,stream>>>(lnSb,lnXb,
      q_w1,q_g1,q_b1, k_w1,k_g1,k_b1, v_w1,v_g1,v_b1, h1q,h1k,h1v);
  gemm_stem_kernel<<<dim3(6,27,3),256,0,stream>>>(h1q,h1k,h1v,
      w2tq,w2tk,w2tv, qbf,kbf,vbf);
  ln768_stem_kernel<<<dim3(MDIM,3),64,0,stream>>>(qbf,kbf,vbf,
      q_g2,q_b2, k_g2,k_b2, v_g2,v_b2, QSCALE);
  vtrans_kernel<<<1296,256,0,stream>>>(vbf, vT);
  attn_kernel<<<dim3(27,12,4),256,0,stream>>>(qbf, kbf, vT, opart, mbuf, lbuf);
  attn_combine_kernel<<<864,256,0,stream>>>(opart, mbuf, lbuf, aob);
  ln768_post_kernel<<<MDIM,64,0,stream>>>(aob, no_w, no_b);
  gemm_bf16<1><<<dim3(24,27),256,0,stream>>>(aob, Btd, dh, KDIM, C2, nullptr, nullptr);
  ln192_gelu_kernel<<<BB_*V1,64,0,stream>>>(dh, o_g, o_b, dhb);
  gemm_bf16<2><<<dim3(1,216),256,0,stream>>>(dhb, Bt48, out, 0, C1, skip, o_tb2);
}

// Round 6
// 347.685 us; speedup vs baseline: 4.3223x; 1.1274x over previous
//
#include <hip/hip_runtime.h>
#include <math.h>

#define BB_ 2
#define C0 6
#define S0 48
#define V0 (S0*S0*S0)      // 110592
#define C1 192
#define S1 24
#define V1 (S1*S1*S1)      // 13824
#define C2 768
#define S2 12
#define LL (S2*S2*S2)      // 1728
#define NH 12
#define HD 64
#define KDIM (C1*8)        // 1536
#define MDIM (BB_*LL)      // 3456

typedef __attribute__((ext_vector_type(8))) short short8;
typedef __attribute__((ext_vector_type(4))) short short4v;
typedef __attribute__((ext_vector_type(4))) float float4v;

static __device__ __forceinline__ float gelu_exact(float x){
  return 0.5f*x*(1.0f+erff(x*0.70710678118654752440f));
}
static __device__ __forceinline__ unsigned short f2bf(float f){
  unsigned int u = __float_as_uint(f);
  unsigned int r = (u + 0x7fffu + ((u>>16)&1u)) >> 16;
  return (unsigned short)r;
}
static __device__ __forceinline__ float bf2f(unsigned short u){
  return __uint_as_float(((unsigned int)u)<<16);
}
static __device__ __forceinline__ void load_lds16(const void* g, void* l){
  __builtin_amdgcn_global_load_lds((const __attribute__((address_space(1))) unsigned int*)g,
      (__attribute__((address_space(3))) unsigned int*)l, 16, 0, 0);
}
static __device__ __forceinline__ float4v mfma32(short8 a, short8 b, float4v c){
  return __builtin_amdgcn_mfma_f32_16x16x32_bf16(a,b,c,0,0,0);
}
static __device__ __forceinline__ float4v mfma16(short4v a, short4v b, float4v c){
#if __has_builtin(__builtin_amdgcn_mfma_f32_16x16x16bf16_1k)
  return __builtin_amdgcn_mfma_f32_16x16x16bf16_1k(a,b,c,0,0,0);
#else
  asm volatile("v_mfma_f32_16x16x16_bf16 %0, %1, %2, %0" : "+v"(c) : "v"(a), "v"(b));
  return c;
#endif
}

// ---------------- prep: LN6 (skip,x) + all weight repacks, one launch ----------------
__global__ __launch_bounds__(256) void prep_kernel(
    const float* __restrict__ skin, const float* __restrict__ xin,
    const float* __restrict__ nsw, const float* __restrict__ nsb,
    const float* __restrict__ nxw, const float* __restrict__ nxb,
    unsigned short* __restrict__ outS, unsigned short* __restrict__ outX,
    const float* __restrict__ qw2, const float* __restrict__ kw2, const float* __restrict__ vw2,
    const float* __restrict__ tw1, const float* __restrict__ tw2,
    unsigned short* __restrict__ w2tq, unsigned short* __restrict__ w2tk,
    unsigned short* __restrict__ w2tv, unsigned short* __restrict__ Btd,
    unsigned short* __restrict__ Bt48){
  int bx = blockIdx.x;
  if (bx < 1728){                         // LN over 6 channels (channels_first)
    int z = bx >= 864;
    const float* in = z ? xin : skin;
    const float* w  = z ? nxw : nsw;
    const float* bi = z ? nxb : nsb;
    unsigned short* out = z ? outX : outS;
    int idx = (bx - z*864)*256 + threadIdx.x;
    int b = idx / V0, vox = idx - b*V0;
    const float* p = in + (size_t)b*(C0*V0) + vox;
    float v[C0]; float s=0.f;
#pragma unroll
    for (int c=0;c<C0;c++){ v[c]=p[(size_t)c*V0]; s+=v[c]; }
    float u = s*(1.f/C0);
    float ss=0.f;
#pragma unroll
    for (int c=0;c<C0;c++){ float d=v[c]-u; ss+=d*d; }
    float inv = rsqrtf(ss*(1.f/C0)+1e-6f);
    unsigned short* o = out + (size_t)b*(C0*V0) + vox;
#pragma unroll
    for (int c=0;c<C0;c++) o[(size_t)c*V0] = f2bf((v[c]-u)*inv*w[c]+bi[c]);
    return;
  }
  bx -= 1728;
  if (bx < 13824){                       // 3 x 4608 : w2 repacks -> [oc][p*192+ic]
    int z = bx/4608;
    int idx = (bx - z*4608)*256 + threadIdx.x;
    const float* w2 = (z==0)?qw2:((z==1)?kw2:vw2);
    unsigned short* o = (z==0)?w2tq:((z==1)?w2tk:w2tv);
    int oc = idx/KDIM; int r = idx-oc*KDIM; int p = r/C1; int ic = r-p*C1;
    o[idx] = f2bf(w2[(size_t)oc*KDIM + ic*8 + p]);
  } else if (bx < 18432){                // tw1 -> [kpq*192+o][p head-major]
    int idx = (bx-13824)*256 + threadIdx.x;
    int n = idx/C2; int p = idx-n*C2;
    int i = ((p&63)*NH) + (p>>6);
    int kpq = n/C1, o2 = n-kpq*C1;
    Btd[idx] = f2bf(tw1[(size_t)i*KDIM + o2*8 + kpq]);
  } else {                               // 48 blocks: tw2 -> [n=c*8+kpq pad64][i]
    int idx = (bx-18432)*256 + threadIdx.x;
    int n = idx/C1; int i = idx-n*C1;
    Bt48[idx] = (n<48) ? f2bf(tw2[(size_t)i*48 + n]) : (unsigned short)0;
  }
}

// ------------- conv1 via MFMA, one tile-job per wave -------------
// tile-job j = bx*4+w in [0,1728): bxh=j/18 -> (b,y,xh), mt=j%18 -> (xo,zo)
__global__ __launch_bounds__(256) void conv1_kernel(
    const unsigned short* __restrict__ lnSb, const unsigned short* __restrict__ lnXb,
    const float* __restrict__ qw1, const float* __restrict__ qg1, const float* __restrict__ qb1,
    const float* __restrict__ kw1, const float* __restrict__ kg1, const float* __restrict__ kb1,
    const float* __restrict__ vw1, const float* __restrict__ vg1, const float* __restrict__ vb1,
    unsigned short* __restrict__ h1q, unsigned short* __restrict__ h1k,
    unsigned short* __restrict__ h1v){
  int z = blockIdx.z;
  const unsigned short* in = (z==0)? lnSb : lnXb;
  const float* w1 = (z==0)?qw1:((z==1)?kw1:vw1);
  const float* g1 = (z==0)?qg1:((z==1)?kg1:vg1);
  const float* b1 = (z==0)?qb1:((z==1)?kb1:vb1);
  unsigned short* h1p = (z==0)?h1q:((z==1)?h1k:h1v);
  __shared__ unsigned short Wl[C1*56];   // rows padded 48->56 shorts
  __shared__ float Gl[C1], Bl2[C1];
  int t = threadIdx.x, w = t>>6, lane = t&63;
  int g = lane>>4, l16 = lane&15;
  // decode tile-job
  int j = blockIdx.x*4 + w;
  int bxh = j/18, mt = j - bxh*18;
  int b = bxh/48; int rem = bxh - b*48; int y = rem>>1, xh = rem&1;
  int xo = mt/3, zo = mt - xo*3;
  int xv = xh*12 + xo*2 + (l16>>3);
  int zv = zo*8 + (l16&7);
  int x2 = 2*xv, z2 = 2*zv, y2 = 2*y;
  const unsigned short* base = in + (size_t)b*C0*V0;
  // issue gathers early (independent of LDS)
  union { short8 v; unsigned int u[4]; } aA;     // k=g*8+jj  -> ic=g, p=jj
  {
    size_t rb = (size_t)g*V0;
    aA.u[0] = *(const unsigned int*)&base[rb + (y2+0)*(S0*S0) + (x2+0)*S0 + z2];
    aA.u[1] = *(const unsigned int*)&base[rb + (y2+0)*(S0*S0) + (x2+1)*S0 + z2];
    aA.u[2] = *(const unsigned int*)&base[rb + (y2+1)*(S0*S0) + (x2+0)*S0 + z2];
    aA.u[3] = *(const unsigned int*)&base[rb + (y2+1)*(S0*S0) + (x2+1)*S0 + z2];
  }
  union { short4v v; unsigned int u[2]; } aB;    // k=32+g*4+jj -> ic=4+(g>>1), p=(g&1)*4+jj
  {
    size_t rb = (size_t)(4+(g>>1))*V0 + (y2+(g&1))*(S0*S0);
    aB.u[0] = *(const unsigned int*)&base[rb + (x2+0)*S0 + z2];
    aB.u[1] = *(const unsigned int*)&base[rb + (x2+1)*S0 + z2];
  }
  // stage W (vectorized): 2304 float4 rows-of-12
  for (int i4 = t; i4 < 2304; i4 += 256){
    int oc = i4/12, kk4 = (i4 - oc*12)*4;
    float4 f4 = *(const float4*)&w1[oc*48 + kk4];
    unsigned int lo = (unsigned int)f2bf(f4.x) | ((unsigned int)f2bf(f4.y)<<16);
    unsigned int hi = (unsigned int)f2bf(f4.z) | ((unsigned int)f2bf(f4.w)<<16);
    uint2 pk; pk.x=lo; pk.y=hi;
    *(uint2*)&Wl[oc*56 + kk4] = pk;
  }
  if (t < C1){ Gl[t] = g1[t]; Bl2[t] = b1[t]; }
  __syncthreads();
  float4v acc[12];
#pragma unroll
  for (int ot=0; ot<12; ot++){
    short8  wA = *(const short8*)&Wl[(ot*16+l16)*56 + g*8];
    short4v wB = *(const short4v*)&Wl[(ot*16+l16)*56 + 32 + g*4];
    float4v a = {};
    a = mfma32(wA, aA.v, a);
    a = mfma16(wB, aB.v, a);
    acc[ot] = a;
  }
  float s1=0.f, s2=0.f;
#pragma unroll
  for (int ot=0;ot<12;ot++)
#pragma unroll
    for (int reg=0;reg<4;reg++){ float v=acc[ot][reg]; s1+=v; s2+=v*v; }
  s1 += __shfl_xor(s1,16); s1 += __shfl_xor(s1,32);
  s2 += __shfl_xor(s2,16); s2 += __shfl_xor(s2,32);
  float u = s1*(1.f/C1);
  float inv = rsqrtf(s2*(1.f/C1)-u*u+1e-6f);
  int tok = (y>>1)*(S2*S2) + (xv>>1)*S2 + (zv>>1);
  int p8 = (y&1)*4 + (xv&1)*2 + (zv&1);
  unsigned short* hb = h1p + (size_t)(b*LL+tok)*KDIM + p8*C1;
#pragma unroll
  for (int ot=0; ot<12; ot++){
    int oc0 = ot*16 + g*4;
    float4 gg = *(const float4*)&Gl[oc0];
    float4 bb = *(const float4*)&Bl2[oc0];
    float x0 = gelu_exact((acc[ot][0]-u)*inv*gg.x+bb.x);
    float x1 = gelu_exact((acc[ot][1]-u)*inv*gg.y+bb.y);
    float x2e= gelu_exact((acc[ot][2]-u)*inv*gg.z+bb.z);
    float x3 = gelu_exact((acc[ot][3]-u)*inv*gg.w+bb.w);
    uint2 pk;
    pk.x = (unsigned int)f2bf(x0) | ((unsigned int)f2bf(x1)<<16);
    pk.y = (unsigned int)f2bf(x2e) | ((unsigned int)f2bf(x3)<<16);
    *(uint2*)&hb[oc0] = pk;
  }
}

// ---------------- fused stem GEMM (z selects A/B/C), 128x128 tiles, BK=32, bf16 C ----------------
__global__ __launch_bounds__(256) void gemm_stem_kernel(
    const unsigned short* __restrict__ A0, const unsigned short* __restrict__ A1,
    const unsigned short* __restrict__ A2,
    const unsigned short* __restrict__ B0, const unsigned short* __restrict__ B1,
    const unsigned short* __restrict__ B2,
    unsigned short* __restrict__ Cq, unsigned short* __restrict__ Ck,
    unsigned short* __restrict__ Cv){
  int z = blockIdx.z;
  const unsigned short* A = (z==0)?A0:((z==1)?A1:A2);
  const unsigned short* Bt = (z==0)?B0:((z==1)?B1:B2);
  unsigned short* Cp = (z==0)?Cq:((z==1)?Ck:Cv);
  __shared__ __align__(16) unsigned short Al[128*32];
  __shared__ __align__(16) unsigned short Bl[128*32];
  int t=threadIdx.x, w=t>>6, lane=t&63;
  int g=lane>>4, l16=lane&15, r16=lane>>2, c16=lane&3;
  int m0=blockIdx.y*128, n0=blockIdx.x*128;
  int wm=w>>1, wn=w&1;
  float4v acc[4][4] = {};
  for (int kb=0;kb<KDIM;kb+=32){
    __syncthreads();
#pragma unroll
    for (int cc=0;cc<4;cc++){
      int ch = w*4+cc;
      if (ch<8){
        const unsigned short* gp = A + (size_t)(m0+ch*16+r16)*KDIM + kb + c16*8;
        load_lds16(gp, &Al[ch*512]);
      } else {
        const unsigned short* gp = Bt + (size_t)(n0+(ch-8)*16+r16)*KDIM + kb + c16*8;
        load_lds16(gp, &Bl[(ch-8)*512]);
      }
    }
    __syncthreads();
    short8 af[4], bf[4];
#pragma unroll
    for (int mt=0;mt<4;mt++) af[mt] = *(const short8*)&Al[(wm*64+mt*16+l16)*32 + g*8];
#pragma unroll
    for (int nt=0;nt<4;nt++) bf[nt] = *(const short8*)&Bl[(wn*64+nt*16+l16)*32 + g*8];
#pragma unroll
    for (int mt=0;mt<4;mt++)
#pragma unroll
      for (int nt=0;nt<4;nt++)
        acc[mt][nt] = mfma32(af[mt], bf[nt], acc[mt][nt]);
  }
#pragma unroll
  for (int mt=0;mt<4;mt++){
    int mb = m0 + wm*64 + mt*16 + g*4;
#pragma unroll
    for (int nt=0;nt<4;nt++){
      int col = n0 + wn*64 + nt*16 + l16;
#pragma unroll
      for (int reg=0;reg<4;reg++)
        Cp[(size_t)(mb+reg)*C2 + col] = f2bf(acc[mt][nt][reg]);
    }
  }
}

// ---------------- debed GEMM: n=kpq*192+o, scatter -> dh[(b*V1+v24)*192+o] fp32 ----------------
__global__ __launch_bounds__(256) void gemm_debed_kernel(const unsigned short* __restrict__ A,
    const unsigned short* __restrict__ Bt, float* __restrict__ C){
  __shared__ __align__(16) unsigned short Al[128*32];
  __shared__ __align__(16) unsigned short Bl[64*32];
  int t=threadIdx.x, w=t>>6, lane=t&63;
  int g=lane>>4, l16=lane&15, r16=lane>>2, c16=lane&3;
  int m0=blockIdx.y*128, n0=blockIdx.x*64;
  int wm=w>>1, wn=w&1;
  float4v acc[4][2] = {};
  for (int kb=0;kb<C2;kb+=32){
    __syncthreads();
#pragma unroll
    for (int cc=0;cc<3;cc++){
      int ch = w*3+cc;
      if (ch<8){
        const unsigned short* gp = A + (size_t)(m0+ch*16+r16)*C2 + kb + c16*8;
        load_lds16(gp, &Al[ch*512]);
      } else {
        const unsigned short* gp = Bt + (size_t)(n0+(ch-8)*16+r16)*C2 + kb + c16*8;
        load_lds16(gp, &Bl[(ch-8)*512]);
      }
    }
    __syncthreads();
    short8 af[4], bf[2];
#pragma unroll
    for (int mt=0;mt<4;mt++) af[mt] = *(const short8*)&Al[(wm*64+mt*16+l16)*32 + g*8];
#pragma unroll
    for (int nt=0;nt<2;nt++) bf[nt] = *(const short8*)&Bl[(wn*32+nt*16+l16)*32 + g*8];
#pragma unroll
    for (int mt=0;mt<4;mt++)
#pragma unroll
      for (int nt=0;nt<2;nt++)
        acc[mt][nt] = mfma32(af[mt], bf[nt], acc[mt][nt]);
  }
  int kpq = (n0 + wn*32)/C1;
#pragma unroll
  for (int nt=0;nt<2;nt++){
    int n = n0 + wn*32 + nt*16 + l16;
    int o = n - kpq*C1;
#pragma unroll
    for (int mt=0;mt<4;mt++){
      int mb = m0 + wm*64 + mt*16 + g*4;
#pragma unroll
      for (int reg=0;reg<4;reg++){
        int m = mb + reg;
        int b = m / LL; int tok = m - b*LL;
        int h = tok/(S2*S2), ww=(tok/S2)%S2, d=tok%S2;
        int v24 = (2*h+((kpq>>2)&1))*(S1*S1) + (2*ww+((kpq>>1)&1))*S1 + (2*d+(kpq&1));
        C[(size_t)(b*V1+v24)*C1 + o] = acc[mt][nt][reg];
      }
    }
  }
}

// ---------------- final: LN(192)+GELU fused into convT2 GEMM + bias + residual ----------------
// 64-row M-tiles; full K=192 in LDS; N=64 (48 live).
__global__ __launch_bounds__(256) void final_kernel(const float* __restrict__ dh,
    const unsigned short* __restrict__ Bt48, const float* __restrict__ og,
    const float* __restrict__ ob, const float* __restrict__ tb2s,
    const float* __restrict__ skipp, float* __restrict__ out){
  __shared__ __align__(16) unsigned short As[64*200];
  __shared__ __align__(16) unsigned short Bs[64*200];
  int t=threadIdx.x, w=t>>6, lane=t&63;
  int g=lane>>4, l16=lane&15;
  int m0 = blockIdx.x*64;
  // stage B: 64x192 bf16, 16B per thread x6
  for (int n8 = t; n8 < 1536; n8 += 256){
    int n64 = n8/24, kk = (n8 - n64*24)*8;
    uint4 d4 = *(const uint4*)&Bt48[n64*192 + kk];
    *(uint4*)&Bs[n64*200 + kk] = d4;
  }
  // stage A: LN+GELU, wave per row, 16 rows per wave
  float g0=og[lane], g1v=og[lane+64], g2v=og[lane+128];
  float b0=ob[lane], b1v=ob[lane+64], b2v=ob[lane+128];
  for (int rr=0; rr<16; rr++){
    int rl = w*16 + rr;
    const float* row = dh + (size_t)(m0+rl)*C1;
    float v0=row[lane], v1=row[lane+64], v2=row[lane+128];
    float s1=v0+v1+v2, s2=v0*v0+v1*v1+v2*v2;
#pragma unroll
    for (int off=32;off>0;off>>=1){ s1+=__shfl_xor(s1,off); s2+=__shfl_xor(s2,off); }
    float u=s1*(1.f/C1), inv=rsqrtf(s2*(1.f/C1)-u*u+1e-6f);
    As[rl*200+lane]     = f2bf(gelu_exact((v0-u)*inv*g0+b0));
    As[rl*200+lane+64]  = f2bf(gelu_exact((v1-u)*inv*g1v+b1v));
    As[rl*200+lane+128] = f2bf(gelu_exact((v2-u)*inv*g2v+b2v));
  }
  __syncthreads();
  int wm=w>>1, wn=w&1;
  float4v acc[2][2] = {};
#pragma unroll
  for (int kb=0;kb<192;kb+=32){
    short8 af[2], bf[2];
#pragma unroll
    for (int mt=0;mt<2;mt++) af[mt] = *(const short8*)&As[(wm*32+mt*16+l16)*200 + kb + g*8];
#pragma unroll
    for (int nt=0;nt<2;nt++) bf[nt] = *(const short8*)&Bs[(wn*32+nt*16+l16)*200 + kb + g*8];
#pragma unroll
    for (int mt=0;mt<2;mt++)
#pragma unroll
      for (int nt=0;nt<2;nt++)
        acc[mt][nt] = mfma32(af[mt], bf[nt], acc[mt][nt]);
  }
#pragma unroll
  for (int nt=0;nt<2;nt++){
    int n = wn*32 + nt*16 + l16;
    if (n < 48){
      int c = n>>3, kpq = n&7;
      float bias = tb2s[c];
#pragma unroll
      for (int mt=0;mt<2;mt++){
        int mb = m0 + wm*32 + mt*16 + g*4;
#pragma unroll
        for (int reg=0;reg<2*2;reg++){}
#pragma unroll
        for (int reg=0;reg<4;reg++){
          int m = mb + reg;
          int b = m / V1; int v24 = m - b*V1;
          int y24 = v24/(S1*S1), x24=(v24/S1)%S1, z24=v24%S1;
          int vox = (2*y24+((kpq>>2)&1))*(S0*S0) + (2*x24+((kpq>>1)&1))*S0 + 2*z24+(kpq&1);
          size_t oi = (size_t)(b*C0+c)*V0 + vox;
          out[oi] = acc[mt][nt][reg] + bias + skipp[oi];
        }
      }
    }
  }
}

// ------------- fused stem LN over 768 (in-place bf16): z=0 q(rope,scale) z=1 k(rope) z=2 v -------------
__global__ __launch_bounds__(64) void ln768_stem_kernel(
    unsigned short* __restrict__ qb, unsigned short* __restrict__ kb2,
    unsigned short* __restrict__ vb,
    const float* __restrict__ qg, const float* __restrict__ qbi,
    const float* __restrict__ kg, const float* __restrict__ kbi,
    const float* __restrict__ vg, const float* __restrict__ vbi, float qscale){
  int z = blockIdx.y;
  unsigned short* buf = (z==0)?qb:((z==1)?kb2:vb);
  const float* g  = (z==0)?qg:((z==1)?kg:vg);
  const float* bia= (z==0)?qbi:((z==1)?kbi:vbi);
  float scale = (z==0)? qscale : 1.0f;
  int tok = blockIdx.x, lane = threadIdx.x;
  unsigned short* row = buf + (size_t)tok*C2;
  float v[12]; float s1=0.f,s2=0.f;
#pragma unroll
  for (int i=0;i<12;i++){ float t=bf2f(row[i*64+lane]); v[i]=t; s1+=t; s2+=t*t; }
#pragma unroll
  for (int off=32;off>0;off>>=1){ s1+=__shfl_xor(s1,off); s2+=__shfl_xor(s2,off); }
  float u=s1*(1.f/C2);
  float inv=rsqrtf(s2*(1.f/C2)-u*u+1e-6f);
  if (z==2){
#pragma unroll
    for (int i=0;i<12;i++){ int j=i*64+lane; row[j]=f2bf((v[i]-u)*inv*g[j]+bia[j]); }
  } else {
    int pos = tok % LL;
#pragma unroll
    for (int i=0;i<6;i++){
      int j=i*64+lane;
      float xn1=(v[i]-u)*inv*g[j]+bia[j];
      float xn2=(v[i+6]-u)*inv*g[j+384]+bia[j+384];
      float fr=(float)pos*__expf(-0.02398526139f*(float)j);  // 10000^{-j/384}
      float cs=cosf(fr), sn=sinf(fr);
      row[j]     = f2bf((xn1*cs - xn2*sn)*scale);
      row[j+384] = f2bf((xn2*cs + xn1*sn)*scale);
    }
  }
}

// ------------- V transpose: vbf [m][768] bf16 -> vT [(b*12+h)*64+d][1728] bf16 -------------
__global__ __launch_bounds__(256) void vtrans_kernel(const unsigned short* __restrict__ vbf,
    unsigned short* __restrict__ vT){
  int idx = blockIdx.x*256 + threadIdx.x;
  int token = idx % LL;
  int rest = idx / LL;
  int dc = rest & 7;
  int hb = rest >> 3;
  int h = hb % NH, b = hb / NH;
  const unsigned short* src = vbf + (size_t)(b*LL+token)*C2 + h*64 + dc*8;
  uint4 d4 = *(const uint4*)src;
  const unsigned short* s = (const unsigned short*)&d4;
#pragma unroll
  for (int i=0;i<8;i++)
    vT[(size_t)((b*NH+h)*HD + dc*8 + i)*LL + token] = s[i];
}

// ---------------- transposed MFMA flash attention, split-K x2 ----------------
__global__ __launch_bounds__(256) void attn_kernel(const unsigned short* __restrict__ q,
    const unsigned short* __restrict__ k, const unsigned short* __restrict__ vt,
    float* __restrict__ opart, float* __restrict__ mbuf, float* __restrict__ lbuf){
  __shared__ __align__(16) unsigned char smem[18432];
  unsigned short* Ks = (unsigned short*)smem;       // [64 keys][64 d] chunk-swizzled
  unsigned short* Vs = Ks + 4096;                   // [64 d][64 keys]
  int qt=blockIdx.x, h=blockIdx.y;
  int b = blockIdx.z>>1, split = blockIdx.z&1;
  int t=threadIdx.x, w=t>>6, lane=t&63;
  int g=lane>>4, l16=lane&15;
  const unsigned short* qrow = q + (size_t)(b*LL + qt*64 + w*16 + l16)*C2 + h*64;
  short8 qA = *(const short8*)(qrow + g*8);
  short8 qB = *(const short8*)(qrow + 32 + g*8);
  const unsigned short* kbase = k + (size_t)(b*LL)*C2 + h*64;
  const unsigned short* vbase = vt + (size_t)((b*NH+h)*HD)*LL;
  int sub = lane>>3;
  int chs = (lane&7) ^ sub;
  float mrow = -1e30f, lrow = 0.f;
  float4v O4[4] = {};
  int ktb = split ? 14 : 0, kte = split ? 27 : 14;
  for (int kt=ktb; kt<kte; kt++){
    __syncthreads();
#pragma unroll
    for (int cc=0;cc<4;cc++){
      int ii = w*4+cc;
      if (ii<8){
        int key = kt*64 + ii*8 + sub;
        load_lds16(kbase + (size_t)key*C2 + chs*8, &Ks[ii*512]);
      } else {
        int d = (ii-8)*8 + sub;
        load_lds16(vbase + (size_t)d*LL + kt*64 + chs*8, &Vs[(ii-8)*512]);
      }
    }
    __syncthreads();
    float4v sc[4];
#pragma unroll
    for (int nt=0;nt<4;nt++){
      int row = nt*16 + l16;
      int sw = row & 7;
      short8 k1 = *(const short8*)&Ks[row*64 + ((g^sw))*8];
      short8 k2 = *(const short8*)&Ks[row*64 + (((4+g)^sw))*8];
      float4v z = {};
      z = mfma32(k1, qA, z);
      z = mfma32(k2, qB, z);
      sc[nt] = z;
    }
    float mx = -1e30f;
#pragma unroll
    for (int nt=0;nt<4;nt++)
#pragma unroll
      for (int reg=0;reg<4;reg++) mx = fmaxf(mx, sc[nt][reg]);
    mx = fmaxf(mx, __shfl_xor(mx,16));
    mx = fmaxf(mx, __shfl_xor(mx,32));
    float mnew = fmaxf(mrow, mx);
    float alpha = exp2f(mrow - mnew);
    float ps = 0.f;
#pragma unroll
    for (int nt=0;nt<4;nt++)
#pragma unroll
      for (int reg=0;reg<4;reg++){ float e = exp2f(sc[nt][reg]-mnew); sc[nt][reg]=e; ps+=e; }
    ps += __shfl_xor(ps,16);
    ps += __shfl_xor(ps,32);
    lrow = lrow*alpha + ps;
    mrow = mnew;
#pragma unroll
    for (int dt=0;dt<4;dt++)
#pragma unroll
      for (int reg=0;reg<4;reg++) O4[dt][reg] *= alpha;
#pragma unroll
    for (int kc=0;kc<4;kc++){
      short4v pb;
      pb[0]=(short)f2bf(sc[kc][0]); pb[1]=(short)f2bf(sc[kc][1]);
      pb[2]=(short)f2bf(sc[kc][2]); pb[3]=(short)f2bf(sc[kc][3]);
#pragma unroll
      for (int dt=0;dt<4;dt++){
        int row = dt*16 + l16;
        int ch = (kc*2 + (g>>1)) ^ (row&7);
        short4v va = *(const short4v*)&Vs[row*64 + ch*8 + (g&1)*4];
        O4[dt] = mfma16(va, pb, O4[dt]);
      }
    }
  }
  __syncthreads();
  float* Ot = (float*)smem;
  float* ot = Ot + w*1152;
#pragma unroll
  for (int dt=0;dt<4;dt++)
    *(float4*)&ot[l16*72 + dt*16 + g*4] =
        make_float4(O4[dt][0],O4[dt][1],O4[dt][2],O4[dt][3]);
  if (g==0){
    int qi = qt*64 + w*16 + l16;
    mbuf[((size_t)(b*2+split)*NH+h)*LL + qi] = mrow;
    lbuf[((size_t)(b*2+split)*NH+h)*LL + qi] = lrow;
  }
  int qq = lane>>2, c4 = lane&3;
  float* orow = opart + (size_t)split*MDIM*C2
              + (size_t)(b*LL + qt*64 + w*16 + qq)*C2 + h*64;
#pragma unroll
  for (int p=0;p<4;p++)
    *(float4*)&orow[p*16 + c4*4] = *(float4*)&ot[qq*72 + p*16 + c4*4];
}

// ---------------- combine splits + post-attn LN (permuted gamma) -> bf16 aob ----------------
__global__ __launch_bounds__(256) void attn_post_kernel(const float* __restrict__ opart,
    const float* __restrict__ mbuf, const float* __restrict__ lbuf,
    const float* __restrict__ g, const float* __restrict__ bia,
    unsigned short* __restrict__ aob){
  int t=threadIdx.x, w=t>>6, lane=t&63;
  int m = blockIdx.x*4 + w;               // grid 864
  int b = m / LL, l = m - b*LL;
  const float* o0 = opart + (size_t)m*C2;
  const float* o1 = o0 + (size_t)MDIM*C2;
  unsigned short* orow = aob + (size_t)m*C2;
  float vv[12]; float s1=0.f, s2=0.f;
#pragma unroll
  for (int i=0;i<12;i++){
    float m0 = mbuf[((size_t)(b*2+0)*NH+i)*LL + l];
    float m1 = mbuf[((size_t)(b*2+1)*NH+i)*LL + l];
    float l0 = lbuf[((size_t)(b*2+0)*NH+i)*LL + l];
    float l1 = lbuf[((size_t)(b*2+1)*NH+i)*LL + l];
    float mm = fmaxf(m0,m1);
    float a0 = exp2f(m0-mm), a1 = exp2f(m1-mm);
    float inv = 1.f/(l0*a0 + l1*a1);
    int j = i*64+lane;
    float val = (o0[j]*a0 + o1[j]*a1)*inv;
    vv[i]=val; s1+=val; s2+=val*val;
  }
#pragma unroll
  for (int off=32;off>0;off>>=1){ s1+=__shfl_xor(s1,off); s2+=__shfl_xor(s2,off); }
  float u=s1*(1.f/C2);
  float invs=rsqrtf(s2*(1.f/C2)-u*u+1e-6f);
#pragma unroll
  for (int i=0;i<12;i++){
    int cj = lane*NH + i;                 // permuted gamma: channel p=h*64+d -> c=d*12+h
    orow[i*64+lane] = f2bf((vv[i]-u)*invs*g[cj]+bia[cj]);
  }
}

extern "C" void kernel_launch(void* const* d_in, const int* in_sizes, int n_in,
                              void* d_out, int out_size, void* d_ws, size_t ws_size,
                              hipStream_t stream){
  (void)in_sizes; (void)n_in; (void)out_size; (void)ws_size;
  const float* x    =(const float*)d_in[0];
  const float* skip =(const float*)d_in[1];
  const float* q_w1 =(const float*)d_in[2];
  const float* q_g1 =(const float*)d_in[3];
  const float* q_b1 =(const float*)d_in[4];
  const float* q_w2 =(const float*)d_in[5];
  const float* q_g2 =(const float*)d_in[6];
  const float* q_b2 =(const float*)d_in[7];
  const float* k_w1 =(const float*)d_in[8];
  const float* k_g1 =(const float*)d_in[9];
  const float* k_b1 =(const float*)d_in[10];
  const float* k_w2 =(const float*)d_in[11];
  const float* k_g2 =(const float*)d_in[12];
  const float* k_b2 =(const float*)d_in[13];
  const float* v_w1 =(const float*)d_in[14];
  const float* v_g1 =(const float*)d_in[15];
  const float* v_b1 =(const float*)d_in[16];
  const float* v_w2 =(const float*)d_in[17];
  const float* v_g2 =(const float*)d_in[18];
  const float* v_b2 =(const float*)d_in[19];
  const float* o_tw1=(const float*)d_in[20];
  const float* o_g  =(const float*)d_in[21];
  const float* o_b  =(const float*)d_in[22];
  const float* o_tw2=(const float*)d_in[23];
  const float* o_tb2=(const float*)d_in[24];
  const float* ns_w =(const float*)d_in[25];
  const float* ns_b =(const float*)d_in[26];
  const float* nx_w =(const float*)d_in[27];
  const float* nx_b =(const float*)d_in[28];
  const float* no_w =(const float*)d_in[29];
  const float* no_b =(const float*)d_in[30];
  float* out=(float*)d_out;

  char* W = (char*)d_ws;
  unsigned short* lnSb = (unsigned short*)(W + 0);          //  2,654,208
  unsigned short* lnXb = (unsigned short*)(W + 2654208);    //  2,654,208
  unsigned short* h1q  = (unsigned short*)(W + 5308416);    // 10,616,832
  unsigned short* h1k  = (unsigned short*)(W + 15925248);   // 10,616,832
  unsigned short* h1v  = (unsigned short*)(W + 26542080);   // 10,616,832
  unsigned short* w2tq = (unsigned short*)(W + 37158912);   //  2,359,296
  unsigned short* w2tk = (unsigned short*)(W + 39518208);   //  2,359,296
  unsigned short* w2tv = (unsigned short*)(W + 41877504);   //  2,359,296
  unsigned short* qbf  = (unsigned short*)(W + 44236800);   //  5,308,416
  unsigned short* kbf  = (unsigned short*)(W + 49545216);   //  5,308,416
  unsigned short* vbf  = (unsigned short*)(W + 54853632);   //  5,308,416
  unsigned short* vT   = (unsigned short*)(W + 60162048);   //  5,308,416
  unsigned short* aob  = (unsigned short*)(W + 65470464);   //  5,308,416
  unsigned short* Btd  = (unsigned short*)(W + 70778880);   //  2,359,296
  unsigned short* Bt48 = (unsigned short*)(W + 73138176);   //     24,576
  // overlays:
  float* mbuf  = (float*)(W + 0);          // lnSb dead after conv1
  float* lbuf  = (float*)(W + 331776);
  float* opart = (float*)(W + 5308416);    // h1q+h1k dead after stem gemm
  float* dh    = (float*)(W + 5308416);    // opart dead after attn_post

  const float QSCALE = 0.125f*1.44269504089f;  // 1/sqrt(64) * log2(e)

  prep_kernel<<<20208,256,0,stream>>>(skip, x, ns_w, ns_b, nx_w, nx_b, lnSb, lnXb,
      q_w2,k_w2,v_w2,o_tw1,o_tw2, w2tq,w2tk,w2tv,Btd,Bt48);
  conv1_kernel<<<dim3(432,1,3),256,0,stream>>>(lnSb,lnXb,
      q_w1,q_g1,q_b1, k_w1,k_g1,k_b1, v_w1,v_g1,v_b1, h1q,h1k,h1v);
  gemm_stem_kernel<<<dim3(6,27,3),256,0,stream>>>(h1q,h1k,h1v,
      w2tq,w2tk,w2tv, qbf,kbf,vbf);
  ln768_stem_kernel<<<dim3(MDIM,3),64,0,stream>>>(qbf,kbf,vbf,
      q_g2,q_b2, k_g2,k_b2, v_g2,v_b2, QSCALE);
  vtrans_kernel<<<1296,256,0,stream>>>(vbf, vT);
  attn_kernel<<<dim3(27,12,4),256,0,stream>>>(qbf, kbf, vT, opart, mbuf, lbuf);
  attn_post_kernel<<<864,256,0,stream>>>(opart, mbuf, lbuf, no_w, no_b, aob);
  gemm_debed_kernel<<<dim3(24,27),256,0,stream>>>(aob, Btd, dh);
  final_kernel<<<432,256,0,stream>>>(dh, Bt48, o_g, o_b, o_tb2, skip, out);
}

// Round 7
// 342.625 us; speedup vs baseline: 4.3861x; 1.0148x over previous
//
#include <hip/hip_runtime.h>
#include <math.h>

#define BB_ 2
#define C0 6
#define S0 48
#define V0 (S0*S0*S0)      // 110592
#define C1 192
#define S1 24
#define V1 (S1*S1*S1)      // 13824
#define C2 768
#define S2 12
#define LL (S2*S2*S2)      // 1728
#define NH 12
#define HD 64
#define KDIM (C1*8)        // 1536
#define MDIM (BB_*LL)      // 3456

typedef __attribute__((ext_vector_type(8))) short short8;
typedef __attribute__((ext_vector_type(4))) short short4v;
typedef __attribute__((ext_vector_type(4))) float float4v;

static __device__ __forceinline__ float gelu_exact(float x){
  return 0.5f*x*(1.0f+erff(x*0.70710678118654752440f));
}
static __device__ __forceinline__ unsigned short f2bf(float f){
  unsigned int u = __float_as_uint(f);
  unsigned int r = (u + 0x7fffu + ((u>>16)&1u)) >> 16;
  return (unsigned short)r;
}
static __device__ __forceinline__ unsigned int pk_bf16(float a, float b){
#if __has_builtin(__builtin_amdgcn_cvt_pk_bf16_f32)
  typedef __attribute__((ext_vector_type(2))) __bf16 bf2;
  bf2 r = __builtin_amdgcn_cvt_pk_bf16_f32(a,b);
  union { bf2 v; unsigned int u; } cv; cv.v = r;
  return cv.u;
#else
  return (unsigned int)f2bf(a) | ((unsigned int)f2bf(b)<<16);
#endif
}
static __device__ __forceinline__ float bf2f(unsigned short u){
  return __uint_as_float(((unsigned int)u)<<16);
}
static __device__ __forceinline__ void load_lds16(const void* g, void* l){
  __builtin_amdgcn_global_load_lds((const __attribute__((address_space(1))) unsigned int*)g,
      (__attribute__((address_space(3))) unsigned int*)l, 16, 0, 0);
}
static __device__ __forceinline__ float4v mfma32(short8 a, short8 b, float4v c){
  return __builtin_amdgcn_mfma_f32_16x16x32_bf16(a,b,c,0,0,0);
}
static __device__ __forceinline__ float4v mfma16(short4v a, short4v b, float4v c){
#if __has_builtin(__builtin_amdgcn_mfma_f32_16x16x16bf16_1k)
  return __builtin_amdgcn_mfma_f32_16x16x16bf16_1k(a,b,c,0,0,0);
#else
  asm volatile("v_mfma_f32_16x16x16_bf16 %0, %1, %2, %0" : "+v"(c) : "v"(a), "v"(b));
  return c;
#endif
}

// ---------------- prep: LN6 (skip,x) + all weight repacks, one launch ----------------
__global__ __launch_bounds__(256) void prep_kernel(
    const float* __restrict__ skin, const float* __restrict__ xin,
    const float* __restrict__ nsw, const float* __restrict__ nsb,
    const float* __restrict__ nxw, const float* __restrict__ nxb,
    unsigned short* __restrict__ outS, unsigned short* __restrict__ outX,
    const float* __restrict__ qw2, const float* __restrict__ kw2, const float* __restrict__ vw2,
    const float* __restrict__ tw1, const float* __restrict__ tw2,
    unsigned short* __restrict__ w2tq, unsigned short* __restrict__ w2tk,
    unsigned short* __restrict__ w2tv, unsigned short* __restrict__ Btd,
    unsigned short* __restrict__ Bt48){
  int bx = blockIdx.x;
  if (bx < 1728){                         // LN over 6 channels (channels_first)
    int z = bx >= 864;
    const float* in = z ? xin : skin;
    const float* w  = z ? nxw : nsw;
    const float* bi = z ? nxb : nsb;
    unsigned short* out = z ? outX : outS;
    int idx = (bx - z*864)*256 + threadIdx.x;
    int b = idx / V0, vox = idx - b*V0;
    const float* p = in + (size_t)b*(C0*V0) + vox;
    float v[C0]; float s=0.f;
#pragma unroll
    for (int c=0;c<C0;c++){ v[c]=p[(size_t)c*V0]; s+=v[c]; }
    float u = s*(1.f/C0);
    float ss=0.f;
#pragma unroll
    for (int c=0;c<C0;c++){ float d=v[c]-u; ss+=d*d; }
    float inv = rsqrtf(ss*(1.f/C0)+1e-6f);
    unsigned short* o = out + (size_t)b*(C0*V0) + vox;
#pragma unroll
    for (int c=0;c<C0;c++) o[(size_t)c*V0] = f2bf((v[c]-u)*inv*w[c]+bi[c]);
    return;
  }
  bx -= 1728;
  if (bx < 13824){                       // 3 x 4608 : w2 repacks -> [oc][p*192+ic]
    int z = bx/4608;
    int idx = (bx - z*4608)*256 + threadIdx.x;
    const float* w2 = (z==0)?qw2:((z==1)?kw2:vw2);
    unsigned short* o = (z==0)?w2tq:((z==1)?w2tk:w2tv);
    int oc = idx/KDIM; int r = idx-oc*KDIM; int p = r/C1; int ic = r-p*C1;
    o[idx] = f2bf(w2[(size_t)oc*KDIM + ic*8 + p]);
  } else if (bx < 18432){                // tw1 -> [kpq*192+o][p head-major]
    int idx = (bx-13824)*256 + threadIdx.x;
    int n = idx/C2; int p = idx-n*C2;
    int i = ((p&63)*NH) + (p>>6);
    int kpq = n/C1, o2 = n-kpq*C1;
    Btd[idx] = f2bf(tw1[(size_t)i*KDIM + o2*8 + kpq]);
  } else {                               // 48 blocks: tw2 -> [n=c*8+kpq pad64][i]
    int idx = (bx-18432)*256 + threadIdx.x;
    int n = idx/C1; int i = idx-n*C1;
    Bt48[idx] = (n<48) ? f2bf(tw2[(size_t)i*48 + n]) : (unsigned short)0;
  }
}

// ------------- conv1 via MFMA, one tile-job per wave -------------
__global__ __launch_bounds__(256) void conv1_kernel(
    const unsigned short* __restrict__ lnSb, const unsigned short* __restrict__ lnXb,
    const float* __restrict__ qw1, const float* __restrict__ qg1, const float* __restrict__ qb1,
    const float* __restrict__ kw1, const float* __restrict__ kg1, const float* __restrict__ kb1,
    const float* __restrict__ vw1, const float* __restrict__ vg1, const float* __restrict__ vb1,
    unsigned short* __restrict__ h1q, unsigned short* __restrict__ h1k,
    unsigned short* __restrict__ h1v){
  int z = blockIdx.z;
  const unsigned short* in = (z==0)? lnSb : lnXb;
  const float* w1 = (z==0)?qw1:((z==1)?kw1:vw1);
  const float* g1 = (z==0)?qg1:((z==1)?kg1:vg1);
  const float* b1 = (z==0)?qb1:((z==1)?kb1:vb1);
  unsigned short* h1p = (z==0)?h1q:((z==1)?h1k:h1v);
  __shared__ unsigned short Wl[C1*56];   // rows padded 48->56 shorts
  __shared__ float Gl[C1], Bl2[C1];
  int t = threadIdx.x, w = t>>6, lane = t&63;
  int g = lane>>4, l16 = lane&15;
  int j = blockIdx.x*4 + w;
  int bxh = j/18, mt = j - bxh*18;
  int b = bxh/48; int rem = bxh - b*48; int y = rem>>1, xh = rem&1;
  int xo = mt/3, zo = mt - xo*3;
  int xv = xh*12 + xo*2 + (l16>>3);
  int zv = zo*8 + (l16&7);
  int x2 = 2*xv, z2 = 2*zv, y2 = 2*y;
  const unsigned short* base = in + (size_t)b*C0*V0;
  union { short8 v; unsigned int u[4]; } aA;     // k=g*8+jj  -> ic=g, p=jj
  {
    size_t rb = (size_t)g*V0;
    aA.u[0] = *(const unsigned int*)&base[rb + (y2+0)*(S0*S0) + (x2+0)*S0 + z2];
    aA.u[1] = *(const unsigned int*)&base[rb + (y2+0)*(S0*S0) + (x2+1)*S0 + z2];
    aA.u[2] = *(const unsigned int*)&base[rb + (y2+1)*(S0*S0) + (x2+0)*S0 + z2];
    aA.u[3] = *(const unsigned int*)&base[rb + (y2+1)*(S0*S0) + (x2+1)*S0 + z2];
  }
  union { short4v v; unsigned int u[2]; } aB;    // k=32+g*4+jj -> ic=4+(g>>1), p=(g&1)*4+jj
  {
    size_t rb = (size_t)(4+(g>>1))*V0 + (y2+(g&1))*(S0*S0);
    aB.u[0] = *(const unsigned int*)&base[rb + (x2+0)*S0 + z2];
    aB.u[1] = *(const unsigned int*)&base[rb + (x2+1)*S0 + z2];
  }
  for (int i4 = t; i4 < 2304; i4 += 256){
    int oc = i4/12, kk4 = (i4 - oc*12)*4;
    float4 f4 = *(const float4*)&w1[oc*48 + kk4];
    uint2 pk; pk.x = pk_bf16(f4.x,f4.y); pk.y = pk_bf16(f4.z,f4.w);
    *(uint2*)&Wl[oc*56 + kk4] = pk;
  }
  if (t < C1){ Gl[t] = g1[t]; Bl2[t] = b1[t]; }
  __syncthreads();
  float4v acc[12];
#pragma unroll
  for (int ot=0; ot<12; ot++){
    short8  wA = *(const short8*)&Wl[(ot*16+l16)*56 + g*8];
    short4v wB = *(const short4v*)&Wl[(ot*16+l16)*56 + 32 + g*4];
    float4v a = {};
    a = mfma32(wA, aA.v, a);
    a = mfma16(wB, aB.v, a);
    acc[ot] = a;
  }
  float s1=0.f, s2=0.f;
#pragma unroll
  for (int ot=0;ot<12;ot++)
#pragma unroll
    for (int reg=0;reg<4;reg++){ float v=acc[ot][reg]; s1+=v; s2+=v*v; }
  s1 += __shfl_xor(s1,16); s1 += __shfl_xor(s1,32);
  s2 += __shfl_xor(s2,16); s2 += __shfl_xor(s2,32);
  float u = s1*(1.f/C1);
  float inv = rsqrtf(s2*(1.f/C1)-u*u+1e-6f);
  int tok = (y>>1)*(S2*S2) + (xv>>1)*S2 + (zv>>1);
  int p8 = (y&1)*4 + (xv&1)*2 + (zv&1);
  unsigned short* hb = h1p + (size_t)(b*LL+tok)*KDIM + p8*C1;
#pragma unroll
  for (int ot=0; ot<12; ot++){
    int oc0 = ot*16 + g*4;
    float4 gg = *(const float4*)&Gl[oc0];
    float4 bb = *(const float4*)&Bl2[oc0];
    float x0 = gelu_exact((acc[ot][0]-u)*inv*gg.x+bb.x);
    float x1 = gelu_exact((acc[ot][1]-u)*inv*gg.y+bb.y);
    float x2e= gelu_exact((acc[ot][2]-u)*inv*gg.z+bb.z);
    float x3 = gelu_exact((acc[ot][3]-u)*inv*gg.w+bb.w);
    uint2 pk; pk.x = pk_bf16(x0,x1); pk.y = pk_bf16(x2e,x3);
    *(uint2*)&hb[oc0] = pk;
  }
}

// ---------------- fused stem GEMM (z selects A/B/C), 128x128 tiles, BK=32, bf16 C ----------------
__global__ __launch_bounds__(256) void gemm_stem_kernel(
    const unsigned short* __restrict__ A0, const unsigned short* __restrict__ A1,
    const unsigned short* __restrict__ A2,
    const unsigned short* __restrict__ B0, const unsigned short* __restrict__ B1,
    const unsigned short* __restrict__ B2,
    unsigned short* __restrict__ Cq, unsigned short* __restrict__ Ck,
    unsigned short* __restrict__ Cv){
  int z = blockIdx.z;
  const unsigned short* A = (z==0)?A0:((z==1)?A1:A2);
  const unsigned short* Bt = (z==0)?B0:((z==1)?B1:B2);
  unsigned short* Cp = (z==0)?Cq:((z==1)?Ck:Cv);
  __shared__ __align__(16) unsigned short Al[128*32];
  __shared__ __align__(16) unsigned short Bl[128*32];
  int t=threadIdx.x, w=t>>6, lane=t&63;
  int g=lane>>4, l16=lane&15, r16=lane>>2, c16=lane&3;
  int m0=blockIdx.y*128, n0=blockIdx.x*128;
  int wm=w>>1, wn=w&1;
  float4v acc[4][4] = {};
  for (int kb=0;kb<KDIM;kb+=32){
    __syncthreads();
#pragma unroll
    for (int cc=0;cc<4;cc++){
      int ch = w*4+cc;
      if (ch<8){
        const unsigned short* gp = A + (size_t)(m0+ch*16+r16)*KDIM + kb + c16*8;
        load_lds16(gp, &Al[ch*512]);
      } else {
        const unsigned short* gp = Bt + (size_t)(n0+(ch-8)*16+r16)*KDIM + kb + c16*8;
        load_lds16(gp, &Bl[(ch-8)*512]);
      }
    }
    __syncthreads();
    short8 af[4], bf[4];
#pragma unroll
    for (int mt=0;mt<4;mt++) af[mt] = *(const short8*)&Al[(wm*64+mt*16+l16)*32 + g*8];
#pragma unroll
    for (int nt=0;nt<4;nt++) bf[nt] = *(const short8*)&Bl[(wn*64+nt*16+l16)*32 + g*8];
#pragma unroll
    for (int mt=0;mt<4;mt++)
#pragma unroll
      for (int nt=0;nt<4;nt++)
        acc[mt][nt] = mfma32(af[mt], bf[nt], acc[mt][nt]);
  }
#pragma unroll
  for (int mt=0;mt<4;mt++){
    int mb = m0 + wm*64 + mt*16 + g*4;
#pragma unroll
    for (int nt=0;nt<4;nt++){
      int col = n0 + wn*64 + nt*16 + l16;
#pragma unroll
      for (int reg=0;reg<4;reg++)
        Cp[(size_t)(mb+reg)*C2 + col] = f2bf(acc[mt][nt][reg]);
    }
  }
}

// ---------------- debed GEMM: n=kpq*192+o, scatter -> dh[(b*V1+v24)*192+o] fp32 ----------------
__global__ __launch_bounds__(256) void gemm_debed_kernel(const unsigned short* __restrict__ A,
    const unsigned short* __restrict__ Bt, float* __restrict__ C){
  __shared__ __align__(16) unsigned short Al[128*32];
  __shared__ __align__(16) unsigned short Bl[64*32];
  int t=threadIdx.x, w=t>>6, lane=t&63;
  int g=lane>>4, l16=lane&15, r16=lane>>2, c16=lane&3;
  int m0=blockIdx.y*128, n0=blockIdx.x*64;
  int wm=w>>1, wn=w&1;
  float4v acc[4][2] = {};
  for (int kb=0;kb<C2;kb+=32){
    __syncthreads();
#pragma unroll
    for (int cc=0;cc<3;cc++){
      int ch = w*3+cc;
      if (ch<8){
        const unsigned short* gp = A + (size_t)(m0+ch*16+r16)*C2 + kb + c16*8;
        load_lds16(gp, &Al[ch*512]);
      } else {
        const unsigned short* gp = Bt + (size_t)(n0+(ch-8)*16+r16)*C2 + kb + c16*8;
        load_lds16(gp, &Bl[(ch-8)*512]);
      }
    }
    __syncthreads();
    short8 af[4], bf[2];
#pragma unroll
    for (int mt=0;mt<4;mt++) af[mt] = *(const short8*)&Al[(wm*64+mt*16+l16)*32 + g*8];
#pragma unroll
    for (int nt=0;nt<2;nt++) bf[nt] = *(const short8*)&Bl[(wn*32+nt*16+l16)*32 + g*8];
#pragma unroll
    for (int mt=0;mt<4;mt++)
#pragma unroll
      for (int nt=0;nt<2;nt++)
        acc[mt][nt] = mfma32(af[mt], bf[nt], acc[mt][nt]);
  }
  int kpq = (n0 + wn*32)/C1;
#pragma unroll
  for (int nt=0;nt<2;nt++){
    int n = n0 + wn*32 + nt*16 + l16;
    int o = n - kpq*C1;
#pragma unroll
    for (int mt=0;mt<4;mt++){
      int mb = m0 + wm*64 + mt*16 + g*4;
#pragma unroll
      for (int reg=0;reg<4;reg++){
        int m = mb + reg;
        int b = m / LL; int tok = m - b*LL;
        int h = tok/(S2*S2), ww=(tok/S2)%S2, d=tok%S2;
        int v24 = (2*h+((kpq>>2)&1))*(S1*S1) + (2*ww+((kpq>>1)&1))*S1 + (2*d+(kpq&1));
        C[(size_t)(b*V1+v24)*C1 + o] = acc[mt][nt][reg];
      }
    }
  }
}

// ---------------- final: LN(192)+GELU fused into convT2 GEMM + bias + residual ----------------
__global__ __launch_bounds__(256) void final_kernel(const float* __restrict__ dh,
    const unsigned short* __restrict__ Bt48, const float* __restrict__ og,
    const float* __restrict__ ob, const float* __restrict__ tb2s,
    const float* __restrict__ skipp, float* __restrict__ out){
  __shared__ __align__(16) unsigned short As[64*200];
  __shared__ __align__(16) unsigned short Bs[64*200];
  int t=threadIdx.x, w=t>>6, lane=t&63;
  int g=lane>>4, l16=lane&15;
  int m0 = blockIdx.x*64;
  for (int n8 = t; n8 < 1536; n8 += 256){
    int n64 = n8/24, kk = (n8 - n64*24)*8;
    uint4 d4 = *(const uint4*)&Bt48[n64*192 + kk];
    *(uint4*)&Bs[n64*200 + kk] = d4;
  }
  float g0=og[lane], g1v=og[lane+64], g2v=og[lane+128];
  float b0=ob[lane], b1v=ob[lane+64], b2v=ob[lane+128];
  for (int rr=0; rr<16; rr++){
    int rl = w*16 + rr;
    const float* row = dh + (size_t)(m0+rl)*C1;
    float v0=row[lane], v1=row[lane+64], v2=row[lane+128];
    float s1=v0+v1+v2, s2=v0*v0+v1*v1+v2*v2;
#pragma unroll
    for (int off=32;off>0;off>>=1){ s1+=__shfl_xor(s1,off); s2+=__shfl_xor(s2,off); }
    float u=s1*(1.f/C1), inv=rsqrtf(s2*(1.f/C1)-u*u+1e-6f);
    As[rl*200+lane]     = f2bf(gelu_exact((v0-u)*inv*g0+b0));
    As[rl*200+lane+64]  = f2bf(gelu_exact((v1-u)*inv*g1v+b1v));
    As[rl*200+lane+128] = f2bf(gelu_exact((v2-u)*inv*g2v+b2v));
  }
  __syncthreads();
  int wm=w>>1, wn=w&1;
  float4v acc[2][2] = {};
#pragma unroll
  for (int kb=0;kb<192;kb+=32){
    short8 af[2], bf[2];
#pragma unroll
    for (int mt=0;mt<2;mt++) af[mt] = *(const short8*)&As[(wm*32+mt*16+l16)*200 + kb + g*8];
#pragma unroll
    for (int nt=0;nt<2;nt++) bf[nt] = *(const short8*)&Bs[(wn*32+nt*16+l16)*200 + kb + g*8];
#pragma unroll
    for (int mt=0;mt<2;mt++)
#pragma unroll
      for (int nt=0;nt<2;nt++)
        acc[mt][nt] = mfma32(af[mt], bf[nt], acc[mt][nt]);
  }
#pragma unroll
  for (int nt=0;nt<2;nt++){
    int n = wn*32 + nt*16 + l16;
    if (n < 48){
      int c = n>>3, kpq = n&7;
      float bias = tb2s[c];
#pragma unroll
      for (int mt=0;mt<2;mt++){
        int mb = m0 + wm*32 + mt*16 + g*4;
#pragma unroll
        for (int reg=0;reg<4;reg++){
          int m = mb + reg;
          int b = m / V1; int v24 = m - b*V1;
          int y24 = v24/(S1*S1), x24=(v24/S1)%S1, z24=v24%S1;
          int vox = (2*y24+((kpq>>2)&1))*(S0*S0) + (2*x24+((kpq>>1)&1))*S0 + 2*z24+(kpq&1);
          size_t oi = (size_t)(b*C0+c)*V0 + vox;
          out[oi] = acc[mt][nt][reg] + bias + skipp[oi];
        }
      }
    }
  }
}

// ------------- fused stem LN over 768 (in-place bf16): z=0 q(rope,scale) z=1 k(rope) z=2 v -------------
__global__ __launch_bounds__(64) void ln768_stem_kernel(
    unsigned short* __restrict__ qb, unsigned short* __restrict__ kb2,
    unsigned short* __restrict__ vb,
    const float* __restrict__ qg, const float* __restrict__ qbi,
    const float* __restrict__ kg, const float* __restrict__ kbi,
    const float* __restrict__ vg, const float* __restrict__ vbi, float qscale){
  int z = blockIdx.y;
  unsigned short* buf = (z==0)?qb:((z==1)?kb2:vb);
  const float* g  = (z==0)?qg:((z==1)?kg:vg);
  const float* bia= (z==0)?qbi:((z==1)?kbi:vbi);
  float scale = (z==0)? qscale : 1.0f;
  int tok = blockIdx.x, lane = threadIdx.x;
  unsigned short* row = buf + (size_t)tok*C2;
  float v[12]; float s1=0.f,s2=0.f;
#pragma unroll
  for (int i=0;i<12;i++){ float t=bf2f(row[i*64+lane]); v[i]=t; s1+=t; s2+=t*t; }
#pragma unroll
  for (int off=32;off>0;off>>=1){ s1+=__shfl_xor(s1,off); s2+=__shfl_xor(s2,off); }
  float u=s1*(1.f/C2);
  float inv=rsqrtf(s2*(1.f/C2)-u*u+1e-6f);
  if (z==2){
#pragma unroll
    for (int i=0;i<12;i++){ int j=i*64+lane; row[j]=f2bf((v[i]-u)*inv*g[j]+bia[j]); }
  } else {
    int pos = tok % LL;
#pragma unroll
    for (int i=0;i<6;i++){
      int j=i*64+lane;
      float xn1=(v[i]-u)*inv*g[j]+bia[j];
      float xn2=(v[i+6]-u)*inv*g[j+384]+bia[j+384];
      float fr=(float)pos*__expf(-0.02398526139f*(float)j);  // 10000^{-j/384}
      float cs=cosf(fr), sn=sinf(fr);
      row[j]     = f2bf((xn1*cs - xn2*sn)*scale);
      row[j+384] = f2bf((xn2*cs + xn1*sn)*scale);
    }
  }
}

// ------------- V transpose: vbf [m][768] bf16 -> vT [(b*12+h)*64+d][1728] bf16 -------------
__global__ __launch_bounds__(256) void vtrans_kernel(const unsigned short* __restrict__ vbf,
    unsigned short* __restrict__ vT){
  int idx = blockIdx.x*256 + threadIdx.x;
  int token = idx % LL;
  int rest = idx / LL;
  int dc = rest & 7;
  int hb = rest >> 3;
  int h = hb % NH, b = hb / NH;
  const unsigned short* src = vbf + (size_t)(b*LL+token)*C2 + h*64 + dc*8;
  uint4 d4 = *(const uint4*)src;
  const unsigned short* s = (const unsigned short*)&d4;
#pragma unroll
  for (int i=0;i<8;i++)
    vT[(size_t)((b*NH+h)*HD + dc*8 + i)*LL + token] = s[i];
}

// ---------------- transposed MFMA flash attention, split-K x2, FIXED-MAX softmax ----------------
// P = exp2(s - 32); scores carry log2(e) via QSCALE. No max tracking / rescale.
__global__ __launch_bounds__(256) void attn_kernel(const unsigned short* __restrict__ q,
    const unsigned short* __restrict__ k, const unsigned short* __restrict__ vt,
    float* __restrict__ opart, float* __restrict__ lbuf){
  __shared__ __align__(16) unsigned char smem[18432];
  unsigned short* Ks = (unsigned short*)smem;       // [64 keys][64 d] chunk-swizzled
  unsigned short* Vs = Ks + 4096;                   // [64 d][64 keys]
  int qt=blockIdx.x, h=blockIdx.y;
  int b = blockIdx.z>>1, split = blockIdx.z&1;
  int t=threadIdx.x, w=t>>6, lane=t&63;
  int g=lane>>4, l16=lane&15;
  const unsigned short* qrow = q + (size_t)(b*LL + qt*64 + w*16 + l16)*C2 + h*64;
  short8 qA = *(const short8*)(qrow + g*8);
  short8 qB = *(const short8*)(qrow + 32 + g*8);
  const unsigned short* kbase = k + (size_t)(b*LL)*C2 + h*64;
  const unsigned short* vbase = vt + (size_t)((b*NH+h)*HD)*LL;
  int sub = lane>>3;
  int chs = (lane&7) ^ sub;
  float lrow = 0.f;                 // per-lane partial sum (keys owned by this lane)
  float4v O4[4] = {};
  int ktb = split ? 14 : 0, kte = split ? 27 : 14;
  for (int kt=ktb; kt<kte; kt++){
    __syncthreads();
#pragma unroll
    for (int cc=0;cc<4;cc++){
      int ii = w*4+cc;
      if (ii<8){
        int key = kt*64 + ii*8 + sub;
        load_lds16(kbase + (size_t)key*C2 + chs*8, &Ks[ii*512]);
      } else {
        int d = (ii-8)*8 + sub;
        load_lds16(vbase + (size_t)d*LL + kt*64 + chs*8, &Vs[(ii-8)*512]);
      }
    }
    __syncthreads();
    float4v sc[4];
#pragma unroll
    for (int nt=0;nt<4;nt++){
      int row = nt*16 + l16;
      int sw = row & 7;
      short8 k1 = *(const short8*)&Ks[row*64 + ((g^sw))*8];
      short8 k2 = *(const short8*)&Ks[row*64 + (((4+g)^sw))*8];
      float4v z = {};
      z = mfma32(k1, qA, z);
      z = mfma32(k2, qB, z);
      sc[nt] = z;
    }
    // P = exp2(s - 32), accumulate l per-lane
#pragma unroll
    for (int nt=0;nt<4;nt++)
#pragma unroll
      for (int reg=0;reg<4;reg++){
        float e = exp2f(sc[nt][reg]-32.f); sc[nt][reg]=e; lrow+=e;
      }
    // P^T -> bf16 B-fragments, PV accumulate
#pragma unroll
    for (int kc=0;kc<4;kc++){
      union { short4v v; unsigned int u[2]; } pb;
      pb.u[0] = pk_bf16(sc[kc][0], sc[kc][1]);
      pb.u[1] = pk_bf16(sc[kc][2], sc[kc][3]);
#pragma unroll
      for (int dt=0;dt<4;dt++){
        int row = dt*16 + l16;
        int ch = (kc*2 + (g>>1)) ^ (row&7);
        short4v va = *(const short4v*)&Vs[row*64 + ch*8 + (g&1)*4];
        O4[dt] = mfma16(va, pb.v, O4[dt]);
      }
    }
  }
  // reduce l across the 4 quads (same q = l16)
  lrow += __shfl_xor(lrow,16);
  lrow += __shfl_xor(lrow,32);
  __syncthreads();                       // reuse smem for transpose
  float* Ot = (float*)smem;
  float* ot = Ot + w*1152;
#pragma unroll
  for (int dt=0;dt<4;dt++)
    *(float4*)&ot[l16*72 + dt*16 + g*4] =
        make_float4(O4[dt][0],O4[dt][1],O4[dt][2],O4[dt][3]);
  if (g==0){
    int qi = qt*64 + w*16 + l16;
    lbuf[((size_t)(b*2+split)*NH+h)*LL + qi] = lrow;
  }
  int qq = lane>>2, c4 = lane&3;
  float* orow = opart + (size_t)split*MDIM*C2
              + (size_t)(b*LL + qt*64 + w*16 + qq)*C2 + h*64;
#pragma unroll
  for (int p=0;p<4;p++)
    *(float4*)&orow[p*16 + c4*4] = *(float4*)&ot[qq*72 + p*16 + c4*4];
}

// ---------------- combine splits + post-attn LN (permuted gamma) -> bf16 aob ----------------
__global__ __launch_bounds__(256) void attn_post_kernel(const float* __restrict__ opart,
    const float* __restrict__ lbuf,
    const float* __restrict__ g, const float* __restrict__ bia,
    unsigned short* __restrict__ aob){
  int t=threadIdx.x, w=t>>6, lane=t&63;
  int m = blockIdx.x*4 + w;               // grid 864
  int b = m / LL, l = m - b*LL;
  const float* o0 = opart + (size_t)m*C2;
  const float* o1 = o0 + (size_t)MDIM*C2;
  unsigned short* orow = aob + (size_t)m*C2;
  float vv[12]; float s1=0.f, s2=0.f;
#pragma unroll
  for (int i=0;i<12;i++){
    float l0 = lbuf[((size_t)(b*2+0)*NH+i)*LL + l];
    float l1 = lbuf[((size_t)(b*2+1)*NH+i)*LL + l];
    float inv = 1.f/(l0+l1);
    int j = i*64+lane;
    float val = (o0[j] + o1[j])*inv;
    vv[i]=val; s1+=val; s2+=val*val;
  }
#pragma unroll
  for (int off=32;off>0;off>>=1){ s1+=__shfl_xor(s1,off); s2+=__shfl_xor(s2,off); }
  float u=s1*(1.f/C2);
  float invs=rsqrtf(s2*(1.f/C2)-u*u+1e-6f);
#pragma unroll
  for (int i=0;i<12;i++){
    int cj = lane*NH + i;                 // permuted gamma: channel p=h*64+d -> c=d*12+h
    orow[i*64+lane] = f2bf((vv[i]-u)*invs*g[cj]+bia[cj]);
  }
}

extern "C" void kernel_launch(void* const* d_in, const int* in_sizes, int n_in,
                              void* d_out, int out_size, void* d_ws, size_t ws_size,
                              hipStream_t stream){
  (void)in_sizes; (void)n_in; (void)out_size; (void)ws_size;
  const float* x    =(const float*)d_in[0];
  const float* skip =(const float*)d_in[1];
  const float* q_w1 =(const float*)d_in[2];
  const float* q_g1 =(const float*)d_in[3];
  const float* q_b1 =(const float*)d_in[4];
  const float* q_w2 =(const float*)d_in[5];
  const float* q_g2 =(const float*)d_in[6];
  const float* q_b2 =(const float*)d_in[7];
  const float* k_w1 =(const float*)d_in[8];
  const float* k_g1 =(const float*)d_in[9];
  const float* k_b1 =(const float*)d_in[10];
  const float* k_w2 =(const float*)d_in[11];
  const float* k_g2 =(const float*)d_in[12];
  const float* k_b2 =(const float*)d_in[13];
  const float* v_w1 =(const float*)d_in[14];
  const float* v_g1 =(const float*)d_in[15];
  const float* v_b1 =(const float*)d_in[16];
  const float* v_w2 =(const float*)d_in[17];
  const float* v_g2 =(const float*)d_in[18];
  const float* v_b2 =(const float*)d_in[19];
  const float* o_tw1=(const float*)d_in[20];
  const float* o_g  =(const float*)d_in[21];
  const float* o_b  =(const float*)d_in[22];
  const float* o_tw2=(const float*)d_in[23];
  const float* o_tb2=(const float*)d_in[24];
  const float* ns_w =(const float*)d_in[25];
  const float* ns_b =(const float*)d_in[26];
  const float* nx_w =(const float*)d_in[27];
  const float* nx_b =(const float*)d_in[28];
  const float* no_w =(const float*)d_in[29];
  const float* no_b =(const float*)d_in[30];
  float* out=(float*)d_out;

  char* W = (char*)d_ws;
  unsigned short* lnSb = (unsigned short*)(W + 0);          //  2,654,208
  unsigned short* lnXb = (unsigned short*)(W + 2654208);    //  2,654,208
  unsigned short* h1q  = (unsigned short*)(W + 5308416);    // 10,616,832
  unsigned short* h1k  = (unsigned short*)(W + 15925248);   // 10,616,832
  unsigned short* h1v  = (unsigned short*)(W + 26542080);   // 10,616,832
  unsigned short* w2tq = (unsigned short*)(W + 37158912);   //  2,359,296
  unsigned short* w2tk = (unsigned short*)(W + 39518208);   //  2,359,296
  unsigned short* w2tv = (unsigned short*)(W + 41877504);   //  2,359,296
  unsigned short* qbf  = (unsigned short*)(W + 44236800);   //  5,308,416
  unsigned short* kbf  = (unsigned short*)(W + 49545216);   //  5,308,416
  unsigned short* vbf  = (unsigned short*)(W + 54853632);   //  5,308,416
  unsigned short* vT   = (unsigned short*)(W + 60162048);   //  5,308,416
  unsigned short* aob  = (unsigned short*)(W + 65470464);   //  5,308,416
  unsigned short* Btd  = (unsigned short*)(W + 70778880);   //  2,359,296
  unsigned short* Bt48 = (unsigned short*)(W + 73138176);   //     24,576
  // overlays:
  float* lbuf  = (float*)(W + 0);          // lnSb dead after conv1
  float* opart = (float*)(W + 5308416);    // h1q+h1k dead after stem gemm
  float* dh    = (float*)(W + 5308416);    // opart dead after attn_post

  const float QSCALE = 0.125f*1.44269504089f;  // 1/sqrt(64) * log2(e)

  prep_kernel<<<20208,256,0,stream>>>(skip, x, ns_w, ns_b, nx_w, nx_b, lnSb, lnXb,
      q_w2,k_w2,v_w2,o_tw1,o_tw2, w2tq,w2tk,w2tv,Btd,Bt48);
  conv1_kernel<<<dim3(432,1,3),256,0,stream>>>(lnSb,lnXb,
      q_w1,q_g1,q_b1, k_w1,k_g1,k_b1, v_w1,v_g1,v_b1, h1q,h1k,h1v);
  gemm_stem_kernel<<<dim3(6,27,3),256,0,stream>>>(h1q,h1k,h1v,
      w2tq,w2tk,w2tv, qbf,kbf,vbf);
  ln768_stem_kernel<<<dim3(MDIM,3),64,0,stream>>>(qbf,kbf,vbf,
      q_g2,q_b2, k_g2,k_b2, v_g2,v_b2, QSCALE);
  vtrans_kernel<<<1296,256,0,stream>>>(vbf, vT);
  attn_kernel<<<dim3(27,12,4),256,0,stream>>>(qbf, kbf, vT, opart, lbuf);
  attn_post_kernel<<<864,256,0,stream>>>(opart, lbuf, no_w, no_b, aob);
  gemm_debed_kernel<<<dim3(24,27),256,0,stream>>>(aob, Btd, dh);
  final_kernel<<<432,256,0,stream>>>(dh, Bt48, o_g, o_b, o_tb2, skip, out);
}

// Round 8
// 342.602 us; speedup vs baseline: 4.3864x; 1.0001x over previous
//
#include <hip/hip_runtime.h>
#include <math.h>

#define BB_ 2
#define C0 6
#define S0 48
#define V0 (S0*S0*S0)      // 110592
#define C1 192
#define S1 24
#define V1 (S1*S1*S1)      // 13824
#define C2 768
#define S2 12
#define LL (S2*S2*S2)      // 1728
#define NH 12
#define HD 64
#define KDIM (C1*8)        // 1536
#define MDIM (BB_*LL)      // 3456

typedef __attribute__((ext_vector_type(8))) short short8;
typedef __attribute__((ext_vector_type(4))) short short4v;
typedef __attribute__((ext_vector_type(4))) float float4v;

static __device__ __forceinline__ float gelu_exact(float x){
  return 0.5f*x*(1.0f+erff(x*0.70710678118654752440f));
}
static __device__ __forceinline__ unsigned short f2bf(float f){
  unsigned int u = __float_as_uint(f);
  unsigned int r = (u + 0x7fffu + ((u>>16)&1u)) >> 16;
  return (unsigned short)r;
}
static __device__ __forceinline__ unsigned int pk_bf16(float a, float b){
#if __has_builtin(__builtin_amdgcn_cvt_pk_bf16_f32)
  typedef __attribute__((ext_vector_type(2))) __bf16 bf2;
  bf2 r = __builtin_amdgcn_cvt_pk_bf16_f32(a,b);
  union { bf2 v; unsigned int u; } cv; cv.v = r;
  return cv.u;
#else
  return (unsigned int)f2bf(a) | ((unsigned int)f2bf(b)<<16);
#endif
}
static __device__ __forceinline__ float bf2f(unsigned short u){
  return __uint_as_float(((unsigned int)u)<<16);
}
static __device__ __forceinline__ void load_lds16(const void* g, void* l){
  __builtin_amdgcn_global_load_lds((const __attribute__((address_space(1))) unsigned int*)g,
      (__attribute__((address_space(3))) unsigned int*)l, 16, 0, 0);
}
static __device__ __forceinline__ float4v mfma32(short8 a, short8 b, float4v c){
  return __builtin_amdgcn_mfma_f32_16x16x32_bf16(a,b,c,0,0,0);
}
static __device__ __forceinline__ float4v mfma16(short4v a, short4v b, float4v c){
#if __has_builtin(__builtin_amdgcn_mfma_f32_16x16x16bf16_1k)
  return __builtin_amdgcn_mfma_f32_16x16x16bf16_1k(a,b,c,0,0,0);
#else
  asm volatile("v_mfma_f32_16x16x16_bf16 %0, %1, %2, %0" : "+v"(c) : "v"(a), "v"(b));
  return c;
#endif
}

// ---------------- prep: LN6 (skip,x) + all weight repacks, one launch ----------------
__global__ __launch_bounds__(256) void prep_kernel(
    const float* __restrict__ skin, const float* __restrict__ xin,
    const float* __restrict__ nsw, const float* __restrict__ nsb,
    const float* __restrict__ nxw, const float* __restrict__ nxb,
    unsigned short* __restrict__ outS, unsigned short* __restrict__ outX,
    const float* __restrict__ qw2, const float* __restrict__ kw2, const float* __restrict__ vw2,
    const float* __restrict__ tw1, const float* __restrict__ tw2,
    unsigned short* __restrict__ w2tq, unsigned short* __restrict__ w2tk,
    unsigned short* __restrict__ w2tv, unsigned short* __restrict__ Btd,
    unsigned short* __restrict__ Bt48){
  int bx = blockIdx.x;
  if (bx < 1728){                         // LN over 6 channels (channels_first)
    int z = bx >= 864;
    const float* in = z ? xin : skin;
    const float* w  = z ? nxw : nsw;
    const float* bi = z ? nxb : nsb;
    unsigned short* out = z ? outX : outS;
    int idx = (bx - z*864)*256 + threadIdx.x;
    int b = idx / V0, vox = idx - b*V0;
    const float* p = in + (size_t)b*(C0*V0) + vox;
    float v[C0]; float s=0.f;
#pragma unroll
    for (int c=0;c<C0;c++){ v[c]=p[(size_t)c*V0]; s+=v[c]; }
    float u = s*(1.f/C0);
    float ss=0.f;
#pragma unroll
    for (int c=0;c<C0;c++){ float d=v[c]-u; ss+=d*d; }
    float inv = rsqrtf(ss*(1.f/C0)+1e-6f);
    unsigned short* o = out + (size_t)b*(C0*V0) + vox;
#pragma unroll
    for (int c=0;c<C0;c++) o[(size_t)c*V0] = f2bf((v[c]-u)*inv*w[c]+bi[c]);
    return;
  }
  bx -= 1728;
  if (bx < 13824){                       // 3 x 4608 : w2 repacks -> [oc][p*192+ic]
    int z = bx/4608;
    int idx = (bx - z*4608)*256 + threadIdx.x;
    const float* w2 = (z==0)?qw2:((z==1)?kw2:vw2);
    unsigned short* o = (z==0)?w2tq:((z==1)?w2tk:w2tv);
    int oc = idx/KDIM; int r = idx-oc*KDIM; int p = r/C1; int ic = r-p*C1;
    o[idx] = f2bf(w2[(size_t)oc*KDIM + ic*8 + p]);
  } else if (bx < 18432){                // tw1 -> [kpq*192+o][p head-major]
    int idx = (bx-13824)*256 + threadIdx.x;
    int n = idx/C2; int p = idx-n*C2;
    int i = ((p&63)*NH) + (p>>6);
    int kpq = n/C1, o2 = n-kpq*C1;
    Btd[idx] = f2bf(tw1[(size_t)i*KDIM + o2*8 + kpq]);
  } else {                               // 48 blocks: tw2 -> [n=c*8+kpq pad64][i]
    int idx = (bx-18432)*256 + threadIdx.x;
    int n = idx/C1; int i = idx-n*C1;
    Bt48[idx] = (n<48) ? f2bf(tw2[(size_t)i*48 + n]) : (unsigned short)0;
  }
}

// ------------- conv1 via MFMA, one tile-job per wave -------------
__global__ __launch_bounds__(256) void conv1_kernel(
    const unsigned short* __restrict__ lnSb, const unsigned short* __restrict__ lnXb,
    const float* __restrict__ qw1, const float* __restrict__ qg1, const float* __restrict__ qb1,
    const float* __restrict__ kw1, const float* __restrict__ kg1, const float* __restrict__ kb1,
    const float* __restrict__ vw1, const float* __restrict__ vg1, const float* __restrict__ vb1,
    unsigned short* __restrict__ h1q, unsigned short* __restrict__ h1k,
    unsigned short* __restrict__ h1v){
  int z = blockIdx.z;
  const unsigned short* in = (z==0)? lnSb : lnXb;
  const float* w1 = (z==0)?qw1:((z==1)?kw1:vw1);
  const float* g1 = (z==0)?qg1:((z==1)?kg1:vg1);
  const float* b1 = (z==0)?qb1:((z==1)?kb1:vb1);
  unsigned short* h1p = (z==0)?h1q:((z==1)?h1k:h1v);
  __shared__ unsigned short Wl[C1*56];   // rows padded 48->56 shorts
  __shared__ float Gl[C1], Bl2[C1];
  int t = threadIdx.x, w = t>>6, lane = t&63;
  int g = lane>>4, l16 = lane&15;
  int j = blockIdx.x*4 + w;
  int bxh = j/18, mt = j - bxh*18;
  int b = bxh/48; int rem = bxh - b*48; int y = rem>>1, xh = rem&1;
  int xo = mt/3, zo = mt - xo*3;
  int xv = xh*12 + xo*2 + (l16>>3);
  int zv = zo*8 + (l16&7);
  int x2 = 2*xv, z2 = 2*zv, y2 = 2*y;
  const unsigned short* base = in + (size_t)b*C0*V0;
  union { short8 v; unsigned int u[4]; } aA;     // k=g*8+jj  -> ic=g, p=jj
  {
    size_t rb = (size_t)g*V0;
    aA.u[0] = *(const unsigned int*)&base[rb + (y2+0)*(S0*S0) + (x2+0)*S0 + z2];
    aA.u[1] = *(const unsigned int*)&base[rb + (y2+0)*(S0*S0) + (x2+1)*S0 + z2];
    aA.u[2] = *(const unsigned int*)&base[rb + (y2+1)*(S0*S0) + (x2+0)*S0 + z2];
    aA.u[3] = *(const unsigned int*)&base[rb + (y2+1)*(S0*S0) + (x2+1)*S0 + z2];
  }
  union { short4v v; unsigned int u[2]; } aB;    // k=32+g*4+jj -> ic=4+(g>>1), p=(g&1)*4+jj
  {
    size_t rb = (size_t)(4+(g>>1))*V0 + (y2+(g&1))*(S0*S0);
    aB.u[0] = *(const unsigned int*)&base[rb + (x2+0)*S0 + z2];
    aB.u[1] = *(const unsigned int*)&base[rb + (x2+1)*S0 + z2];
  }
  for (int i4 = t; i4 < 2304; i4 += 256){
    int oc = i4/12, kk4 = (i4 - oc*12)*4;
    float4 f4 = *(const float4*)&w1[oc*48 + kk4];
    uint2 pk; pk.x = pk_bf16(f4.x,f4.y); pk.y = pk_bf16(f4.z,f4.w);
    *(uint2*)&Wl[oc*56 + kk4] = pk;
  }
  if (t < C1){ Gl[t] = g1[t]; Bl2[t] = b1[t]; }
  __syncthreads();
  float4v acc[12];
#pragma unroll
  for (int ot=0; ot<12; ot++){
    short8  wA = *(const short8*)&Wl[(ot*16+l16)*56 + g*8];
    short4v wB = *(const short4v*)&Wl[(ot*16+l16)*56 + 32 + g*4];
    float4v a = {};
    a = mfma32(wA, aA.v, a);
    a = mfma16(wB, aB.v, a);
    acc[ot] = a;
  }
  float s1=0.f, s2=0.f;
#pragma unroll
  for (int ot=0;ot<12;ot++)
#pragma unroll
    for (int reg=0;reg<4;reg++){ float v=acc[ot][reg]; s1+=v; s2+=v*v; }
  s1 += __shfl_xor(s1,16); s1 += __shfl_xor(s1,32);
  s2 += __shfl_xor(s2,16); s2 += __shfl_xor(s2,32);
  float u = s1*(1.f/C1);
  float inv = rsqrtf(s2*(1.f/C1)-u*u+1e-6f);
  int tok = (y>>1)*(S2*S2) + (xv>>1)*S2 + (zv>>1);
  int p8 = (y&1)*4 + (xv&1)*2 + (zv&1);
  unsigned short* hb = h1p + (size_t)(b*LL+tok)*KDIM + p8*C1;
#pragma unroll
  for (int ot=0; ot<12; ot++){
    int oc0 = ot*16 + g*4;
    float4 gg = *(const float4*)&Gl[oc0];
    float4 bb = *(const float4*)&Bl2[oc0];
    float x0 = gelu_exact((acc[ot][0]-u)*inv*gg.x+bb.x);
    float x1 = gelu_exact((acc[ot][1]-u)*inv*gg.y+bb.y);
    float x2e= gelu_exact((acc[ot][2]-u)*inv*gg.z+bb.z);
    float x3 = gelu_exact((acc[ot][3]-u)*inv*gg.w+bb.w);
    uint2 pk; pk.x = pk_bf16(x0,x1); pk.y = pk_bf16(x2e,x3);
    *(uint2*)&hb[oc0] = pk;
  }
}

// ---------------- fused stem GEMM (z selects A/B/C), 128x64 tiles, BK=32, bf16 C ----------------
__global__ __launch_bounds__(256) void gemm_stem_kernel(
    const unsigned short* __restrict__ A0, const unsigned short* __restrict__ A1,
    const unsigned short* __restrict__ A2,
    const unsigned short* __restrict__ B0, const unsigned short* __restrict__ B1,
    const unsigned short* __restrict__ B2,
    unsigned short* __restrict__ Cq, unsigned short* __restrict__ Ck,
    unsigned short* __restrict__ Cv){
  int z = blockIdx.z;
  const unsigned short* A = (z==0)?A0:((z==1)?A1:A2);
  const unsigned short* Bt = (z==0)?B0:((z==1)?B1:B2);
  unsigned short* Cp = (z==0)?Cq:((z==1)?Ck:Cv);
  __shared__ __align__(16) unsigned short Al[128*32];
  __shared__ __align__(16) unsigned short Bl[64*32];
  int t=threadIdx.x, w=t>>6, lane=t&63;
  int g=lane>>4, l16=lane&15, r16=lane>>2, c16=lane&3;
  int m0=blockIdx.y*128, n0=blockIdx.x*64;
  int wm=w>>1, wn=w&1;
  float4v acc[4][2] = {};
  for (int kb=0;kb<KDIM;kb+=32){
    __syncthreads();
#pragma unroll
    for (int cc=0;cc<3;cc++){
      int ch = w*3+cc;
      if (ch<8){
        const unsigned short* gp = A + (size_t)(m0+ch*16+r16)*KDIM + kb + c16*8;
        load_lds16(gp, &Al[ch*512]);
      } else {
        const unsigned short* gp = Bt + (size_t)(n0+(ch-8)*16+r16)*KDIM + kb + c16*8;
        load_lds16(gp, &Bl[(ch-8)*512]);
      }
    }
    __syncthreads();
    short8 af[4], bf[2];
#pragma unroll
    for (int mt=0;mt<4;mt++) af[mt] = *(const short8*)&Al[(wm*64+mt*16+l16)*32 + g*8];
#pragma unroll
    for (int nt=0;nt<2;nt++) bf[nt] = *(const short8*)&Bl[(wn*32+nt*16+l16)*32 + g*8];
#pragma unroll
    for (int mt=0;mt<4;mt++)
#pragma unroll
      for (int nt=0;nt<2;nt++)
        acc[mt][nt] = mfma32(af[mt], bf[nt], acc[mt][nt]);
  }
#pragma unroll
  for (int mt=0;mt<4;mt++){
    int mb = m0 + wm*64 + mt*16 + g*4;
#pragma unroll
    for (int nt=0;nt<2;nt++){
      int col = n0 + wn*32 + nt*16 + l16;
#pragma unroll
      for (int reg=0;reg<4;reg++)
        Cp[(size_t)(mb+reg)*C2 + col] = f2bf(acc[mt][nt][reg]);
    }
  }
}

// ---------------- debed GEMM: n=kpq*192+o, scatter -> dh[(b*V1+v24)*192+o] fp32 ----------------
__global__ __launch_bounds__(256) void gemm_debed_kernel(const unsigned short* __restrict__ A,
    const unsigned short* __restrict__ Bt, float* __restrict__ C){
  __shared__ __align__(16) unsigned short Al[128*32];
  __shared__ __align__(16) unsigned short Bl[64*32];
  int t=threadIdx.x, w=t>>6, lane=t&63;
  int g=lane>>4, l16=lane&15, r16=lane>>2, c16=lane&3;
  int m0=blockIdx.y*128, n0=blockIdx.x*64;
  int wm=w>>1, wn=w&1;
  float4v acc[4][2] = {};
  for (int kb=0;kb<C2;kb+=32){
    __syncthreads();
#pragma unroll
    for (int cc=0;cc<3;cc++){
      int ch = w*3+cc;
      if (ch<8){
        const unsigned short* gp = A + (size_t)(m0+ch*16+r16)*C2 + kb + c16*8;
        load_lds16(gp, &Al[ch*512]);
      } else {
        const unsigned short* gp = Bt + (size_t)(n0+(ch-8)*16+r16)*C2 + kb + c16*8;
        load_lds16(gp, &Bl[(ch-8)*512]);
      }
    }
    __syncthreads();
    short8 af[4], bf[2];
#pragma unroll
    for (int mt=0;mt<4;mt++) af[mt] = *(const short8*)&Al[(wm*64+mt*16+l16)*32 + g*8];
#pragma unroll
    for (int nt=0;nt<2;nt++) bf[nt] = *(const short8*)&Bl[(wn*32+nt*16+l16)*32 + g*8];
#pragma unroll
    for (int mt=0;mt<4;mt++)
#pragma unroll
      for (int nt=0;nt<2;nt++)
        acc[mt][nt] = mfma32(af[mt], bf[nt], acc[mt][nt]);
  }
  int kpq = (n0 + wn*32)/C1;
#pragma unroll
  for (int nt=0;nt<2;nt++){
    int n = n0 + wn*32 + nt*16 + l16;
    int o = n - kpq*C1;
#pragma unroll
    for (int mt=0;mt<4;mt++){
      int mb = m0 + wm*64 + mt*16 + g*4;
#pragma unroll
      for (int reg=0;reg<4;reg++){
        int m = mb + reg;
        int b = m / LL; int tok = m - b*LL;
        int h = tok/(S2*S2), ww=(tok/S2)%S2, d=tok%S2;
        int v24 = (2*h+((kpq>>2)&1))*(S1*S1) + (2*ww+((kpq>>1)&1))*S1 + (2*d+(kpq&1));
        C[(size_t)(b*V1+v24)*C1 + o] = acc[mt][nt][reg];
      }
    }
  }
}

// ---------------- final: LN(192)+GELU fused into convT2 GEMM + bias + residual ----------------
__global__ __launch_bounds__(256) void final_kernel(const float* __restrict__ dh,
    const unsigned short* __restrict__ Bt48, const float* __restrict__ og,
    const float* __restrict__ ob, const float* __restrict__ tb2s,
    const float* __restrict__ skipp, float* __restrict__ out){
  __shared__ __align__(16) unsigned short As[64*200];
  __shared__ __align__(16) unsigned short Bs[64*200];
  int t=threadIdx.x, w=t>>6, lane=t&63;
  int g=lane>>4, l16=lane&15;
  int m0 = blockIdx.x*64;
  for (int n8 = t; n8 < 1536; n8 += 256){
    int n64 = n8/24, kk = (n8 - n64*24)*8;
    uint4 d4 = *(const uint4*)&Bt48[n64*192 + kk];
    *(uint4*)&Bs[n64*200 + kk] = d4;
  }
  float g0=og[lane], g1v=og[lane+64], g2v=og[lane+128];
  float b0=ob[lane], b1v=ob[lane+64], b2v=ob[lane+128];
  for (int rr=0; rr<16; rr++){
    int rl = w*16 + rr;
    const float* row = dh + (size_t)(m0+rl)*C1;
    float v0=row[lane], v1=row[lane+64], v2=row[lane+128];
    float s1=v0+v1+v2, s2=v0*v0+v1*v1+v2*v2;
#pragma unroll
    for (int off=32;off>0;off>>=1){ s1+=__shfl_xor(s1,off); s2+=__shfl_xor(s2,off); }
    float u=s1*(1.f/C1), inv=rsqrtf(s2*(1.f/C1)-u*u+1e-6f);
    As[rl*200+lane]     = f2bf(gelu_exact((v0-u)*inv*g0+b0));
    As[rl*200+lane+64]  = f2bf(gelu_exact((v1-u)*inv*g1v+b1v));
    As[rl*200+lane+128] = f2bf(gelu_exact((v2-u)*inv*g2v+b2v));
  }
  __syncthreads();
  int wm=w>>1, wn=w&1;
  float4v acc[2][2] = {};
#pragma unroll
  for (int kb=0;kb<192;kb+=32){
    short8 af[2], bf[2];
#pragma unroll
    for (int mt=0;mt<2;mt++) af[mt] = *(const short8*)&As[(wm*32+mt*16+l16)*200 + kb + g*8];
#pragma unroll
    for (int nt=0;nt<2;nt++) bf[nt] = *(const short8*)&Bs[(wn*32+nt*16+l16)*200 + kb + g*8];
#pragma unroll
    for (int mt=0;mt<2;mt++)
#pragma unroll
      for (int nt=0;nt<2;nt++)
        acc[mt][nt] = mfma32(af[mt], bf[nt], acc[mt][nt]);
  }
#pragma unroll
  for (int nt=0;nt<2;nt++){
    int n = wn*32 + nt*16 + l16;
    if (n < 48){
      int c = n>>3, kpq = n&7;
      float bias = tb2s[c];
#pragma unroll
      for (int mt=0;mt<2;mt++){
        int mb = m0 + wm*32 + mt*16 + g*4;
#pragma unroll
        for (int reg=0;reg<4;reg++){
          int m = mb + reg;
          int b = m / V1; int v24 = m - b*V1;
          int y24 = v24/(S1*S1), x24=(v24/S1)%S1, z24=v24%S1;
          int vox = (2*y24+((kpq>>2)&1))*(S0*S0) + (2*x24+((kpq>>1)&1))*S0 + 2*z24+(kpq&1);
          size_t oi = (size_t)(b*C0+c)*V0 + vox;
          out[oi] = acc[mt][nt][reg] + bias + skipp[oi];
        }
      }
    }
  }
}

// ------------- fused stem LN over 768 (in-place bf16): z=0 q(rope,scale) z=1 k(rope) z=2 v -------------
__global__ __launch_bounds__(64) void ln768_stem_kernel(
    unsigned short* __restrict__ qb, unsigned short* __restrict__ kb2,
    unsigned short* __restrict__ vb,
    const float* __restrict__ qg, const float* __restrict__ qbi,
    const float* __restrict__ kg, const float* __restrict__ kbi,
    const float* __restrict__ vg, const float* __restrict__ vbi, float qscale){
  int z = blockIdx.y;
  unsigned short* buf = (z==0)?qb:((z==1)?kb2:vb);
  const float* g  = (z==0)?qg:((z==1)?kg:vg);
  const float* bia= (z==0)?qbi:((z==1)?kbi:vbi);
  float scale = (z==0)? qscale : 1.0f;
  int tok = blockIdx.x, lane = threadIdx.x;
  unsigned short* row = buf + (size_t)tok*C2;
  float v[12]; float s1=0.f,s2=0.f;
#pragma unroll
  for (int i=0;i<12;i++){ float t=bf2f(row[i*64+lane]); v[i]=t; s1+=t; s2+=t*t; }
#pragma unroll
  for (int off=32;off>0;off>>=1){ s1+=__shfl_xor(s1,off); s2+=__shfl_xor(s2,off); }
  float u=s1*(1.f/C2);
  float inv=rsqrtf(s2*(1.f/C2)-u*u+1e-6f);
  if (z==2){
#pragma unroll
    for (int i=0;i<12;i++){ int j=i*64+lane; row[j]=f2bf((v[i]-u)*inv*g[j]+bia[j]); }
  } else {
    int pos = tok % LL;
#pragma unroll
    for (int i=0;i<6;i++){
      int j=i*64+lane;
      float xn1=(v[i]-u)*inv*g[j]+bia[j];
      float xn2=(v[i+6]-u)*inv*g[j+384]+bia[j+384];
      float fr=(float)pos*__expf(-0.02398526139f*(float)j);  // 10000^{-j/384}
      float cs=cosf(fr), sn=sinf(fr);
      row[j]     = f2bf((xn1*cs - xn2*sn)*scale);
      row[j+384] = f2bf((xn2*cs + xn1*sn)*scale);
    }
  }
}

// ------------- V transpose: vbf [m][768] bf16 -> vT [(b*12+h)*64+d][1728] bf16 -------------
__global__ __launch_bounds__(256) void vtrans_kernel(const unsigned short* __restrict__ vbf,
    unsigned short* __restrict__ vT){
  int idx = blockIdx.x*256 + threadIdx.x;
  int token = idx % LL;
  int rest = idx / LL;
  int dc = rest & 7;
  int hb = rest >> 3;
  int h = hb % NH, b = hb / NH;
  const unsigned short* src = vbf + (size_t)(b*LL+token)*C2 + h*64 + dc*8;
  uint4 d4 = *(const uint4*)src;
  const unsigned short* s = (const unsigned short*)&d4;
#pragma unroll
  for (int i=0;i<8;i++)
    vT[(size_t)((b*NH+h)*HD + dc*8 + i)*LL + token] = s[i];
}

// ---------------- transposed MFMA flash attention, split-K x4, raw exp2 (no max) ----------------
// P = exp2(s); scores carry log2(e) via QSCALE; normalization absorbs scale exactly.
// O-partials stored bf16.
__global__ __launch_bounds__(256) void attn_kernel(const unsigned short* __restrict__ q,
    const unsigned short* __restrict__ k, const unsigned short* __restrict__ vt,
    unsigned short* __restrict__ opart, float* __restrict__ lbuf){
  __shared__ __align__(16) unsigned char smem[18432];
  unsigned short* Ks = (unsigned short*)smem;       // [64 keys][64 d] chunk-swizzled
  unsigned short* Vs = Ks + 4096;                   // [64 d][64 keys]
  int qt=blockIdx.x, h=blockIdx.y;
  int b = blockIdx.z>>2, split = blockIdx.z&3;
  int t=threadIdx.x, w=t>>6, lane=t&63;
  int g=lane>>4, l16=lane&15;
  const unsigned short* qrow = q + (size_t)(b*LL + qt*64 + w*16 + l16)*C2 + h*64;
  short8 qA = *(const short8*)(qrow + g*8);
  short8 qB = *(const short8*)(qrow + 32 + g*8);
  const unsigned short* kbase = k + (size_t)(b*LL)*C2 + h*64;
  const unsigned short* vbase = vt + (size_t)((b*NH+h)*HD)*LL;
  int sub = lane>>3;
  int chs = (lane&7) ^ sub;
  float lrow = 0.f;
  float4v O4[4] = {};
  int ktb = split*7, kte = (split==3)? 27 : (split*7+7);
  for (int kt=ktb; kt<kte; kt++){
    __syncthreads();
#pragma unroll
    for (int cc=0;cc<4;cc++){
      int ii = w*4+cc;
      if (ii<8){
        int key = kt*64 + ii*8 + sub;
        load_lds16(kbase + (size_t)key*C2 + chs*8, &Ks[ii*512]);
      } else {
        int d = (ii-8)*8 + sub;
        load_lds16(vbase + (size_t)d*LL + kt*64 + chs*8, &Vs[(ii-8)*512]);
      }
    }
    __syncthreads();
    float4v sc[4];
#pragma unroll
    for (int nt=0;nt<4;nt++){
      int row = nt*16 + l16;
      int sw = row & 7;
      short8 k1 = *(const short8*)&Ks[row*64 + ((g^sw))*8];
      short8 k2 = *(const short8*)&Ks[row*64 + (((4+g)^sw))*8];
      float4v z = {};
      z = mfma32(k1, qA, z);
      z = mfma32(k2, qB, z);
      sc[nt] = z;
    }
#pragma unroll
    for (int nt=0;nt<4;nt++)
#pragma unroll
      for (int reg=0;reg<4;reg++){
        float e = exp2f(sc[nt][reg]); sc[nt][reg]=e; lrow+=e;
      }
#pragma unroll
    for (int kc=0;kc<4;kc++){
      union { short4v v; unsigned int u[2]; } pb;
      pb.u[0] = pk_bf16(sc[kc][0], sc[kc][1]);
      pb.u[1] = pk_bf16(sc[kc][2], sc[kc][3]);
#pragma unroll
      for (int dt=0;dt<4;dt++){
        int row = dt*16 + l16;
        int ch = (kc*2 + (g>>1)) ^ (row&7);
        short4v va = *(const short4v*)&Vs[row*64 + ch*8 + (g&1)*4];
        O4[dt] = mfma16(va, pb.v, O4[dt]);
      }
    }
  }
  lrow += __shfl_xor(lrow,16);
  lrow += __shfl_xor(lrow,32);
  __syncthreads();                       // reuse smem for transpose
  float* Ot = (float*)smem;
  float* ot = Ot + w*1152;
#pragma unroll
  for (int dt=0;dt<4;dt++)
    *(float4*)&ot[l16*72 + dt*16 + g*4] =
        make_float4(O4[dt][0],O4[dt][1],O4[dt][2],O4[dt][3]);
  if (g==0){
    int qi = qt*64 + w*16 + l16;
    lbuf[((size_t)(b*4+split)*NH+h)*LL + qi] = lrow;
  }
  int qq = lane>>2, c4 = lane&3;
  unsigned short* orow = opart + (size_t)split*MDIM*C2
              + (size_t)(b*LL + qt*64 + w*16 + qq)*C2 + h*64;
#pragma unroll
  for (int p=0;p<4;p++){
    float4 vv = *(float4*)&ot[qq*72 + p*16 + c4*4];
    uint2 pk; pk.x = pk_bf16(vv.x,vv.y); pk.y = pk_bf16(vv.z,vv.w);
    *(uint2*)&orow[p*16 + c4*4] = pk;
  }
}

// ---------------- combine 4 splits + post-attn LN (permuted gamma) -> bf16 aob ----------------
__global__ __launch_bounds__(256) void attn_post_kernel(const unsigned short* __restrict__ opart,
    const float* __restrict__ lbuf,
    const float* __restrict__ g, const float* __restrict__ bia,
    unsigned short* __restrict__ aob){
  int t=threadIdx.x, w=t>>6, lane=t&63;
  int m = blockIdx.x*4 + w;               // grid 864
  int b = m / LL, l = m - b*LL;
  const unsigned short* o0 = opart + (size_t)m*C2;
  unsigned short* orow = aob + (size_t)m*C2;
  float vv[12]; float s1=0.f, s2=0.f;
#pragma unroll
  for (int i=0;i<12;i++){
    float ls = 0.f;
#pragma unroll
    for (int s=0;s<4;s++) ls += lbuf[((size_t)(b*4+s)*NH+i)*LL + l];
    float inv = 1.f/ls;
    int j = i*64+lane;
    float val = 0.f;
#pragma unroll
    for (int s=0;s<4;s++) val += bf2f(o0[(size_t)s*MDIM*C2 + j]);
    val *= inv;
    vv[i]=val; s1+=val; s2+=val*val;
  }
#pragma unroll
  for (int off=32;off>0;off>>=1){ s1+=__shfl_xor(s1,off); s2+=__shfl_xor(s2,off); }
  float u=s1*(1.f/C2);
  float invs=rsqrtf(s2*(1.f/C2)-u*u+1e-6f);
#pragma unroll
  for (int i=0;i<12;i++){
    int cj = lane*NH + i;                 // permuted gamma: channel p=h*64+d -> c=d*12+h
    orow[i*64+lane] = f2bf((vv[i]-u)*invs*g[cj]+bia[cj]);
  }
}

extern "C" void kernel_launch(void* const* d_in, const int* in_sizes, int n_in,
                              void* d_out, int out_size, void* d_ws, size_t ws_size,
                              hipStream_t stream){
  (void)in_sizes; (void)n_in; (void)out_size; (void)ws_size;
  const float* x    =(const float*)d_in[0];
  const float* skip =(const float*)d_in[1];
  const float* q_w1 =(const float*)d_in[2];
  const float* q_g1 =(const float*)d_in[3];
  const float* q_b1 =(const float*)d_in[4];
  const float* q_w2 =(const float*)d_in[5];
  const float* q_g2 =(const float*)d_in[6];
  const float* q_b2 =(const float*)d_in[7];
  const float* k_w1 =(const float*)d_in[8];
  const float* k_g1 =(const float*)d_in[9];
  const float* k_b1 =(const float*)d_in[10];
  const float* k_w2 =(const float*)d_in[11];
  const float* k_g2 =(const float*)d_in[12];
  const float* k_b2 =(const float*)d_in[13];
  const float* v_w1 =(const float*)d_in[14];
  const float* v_g1 =(const float*)d_in[15];
  const float* v_b1 =(const float*)d_in[16];
  const float* v_w2 =(const float*)d_in[17];
  const float* v_g2 =(const float*)d_in[18];
  const float* v_b2 =(const float*)d_in[19];
  const float* o_tw1=(const float*)d_in[20];
  const float* o_g  =(const float*)d_in[21];
  const float* o_b  =(const float*)d_in[22];
  const float* o_tw2=(const float*)d_in[23];
  const float* o_tb2=(const float*)d_in[24];
  const float* ns_w =(const float*)d_in[25];
  const float* ns_b =(const float*)d_in[26];
  const float* nx_w =(const float*)d_in[27];
  const float* nx_b =(const float*)d_in[28];
  const float* no_w =(const float*)d_in[29];
  const float* no_b =(const float*)d_in[30];
  float* out=(float*)d_out;

  char* W = (char*)d_ws;
  unsigned short* lnSb = (unsigned short*)(W + 0);          //  2,654,208
  unsigned short* lnXb = (unsigned short*)(W + 2654208);    //  2,654,208
  unsigned short* h1q  = (unsigned short*)(W + 5308416);    // 10,616,832
  unsigned short* h1k  = (unsigned short*)(W + 15925248);   // 10,616,832
  unsigned short* h1v  = (unsigned short*)(W + 26542080);   // 10,616,832
  unsigned short* w2tq = (unsigned short*)(W + 37158912);   //  2,359,296
  unsigned short* w2tk = (unsigned short*)(W + 39518208);   //  2,359,296
  unsigned short* w2tv = (unsigned short*)(W + 41877504);   //  2,359,296
  unsigned short* qbf  = (unsigned short*)(W + 44236800);   //  5,308,416
  unsigned short* kbf  = (unsigned short*)(W + 49545216);   //  5,308,416
  unsigned short* vbf  = (unsigned short*)(W + 54853632);   //  5,308,416
  unsigned short* vT   = (unsigned short*)(W + 60162048);   //  5,308,416
  unsigned short* aob  = (unsigned short*)(W + 65470464);   //  5,308,416
  unsigned short* Btd  = (unsigned short*)(W + 70778880);   //  2,359,296
  unsigned short* Bt48 = (unsigned short*)(W + 73138176);   //     24,576
  // overlays:
  float* lbuf  = (float*)(W + 0);                     // 663,552 (lnSb dead after conv1)
  unsigned short* opart = (unsigned short*)(W + 5308416);  // 4x5,308,416 bf16 (h1q+h1k dead)
  float* dh    = (float*)(W + 5308416);               // 21,233,664 (opart dead after attn_post)

  const float QSCALE = 0.125f*1.44269504089f;  // 1/sqrt(64) * log2(e)

  prep_kernel<<<20208,256,0,stream>>>(skip, x, ns_w, ns_b, nx_w, nx_b, lnSb, lnXb,
      q_w2,k_w2,v_w2,o_tw1,o_tw2, w2tq,w2tk,w2tv,Btd,Bt48);
  conv1_kernel<<<dim3(432,1,3),256,0,stream>>>(lnSb,lnXb,
      q_w1,q_g1,q_b1, k_w1,k_g1,k_b1, v_w1,v_g1,v_b1, h1q,h1k,h1v);
  gemm_stem_kernel<<<dim3(12,27,3),256,0,stream>>>(h1q,h1k,h1v,
      w2tq,w2tk,w2tv, qbf,kbf,vbf);
  ln768_stem_kernel<<<dim3(MDIM,3),64,0,stream>>>(qbf,kbf,vbf,
      q_g2,q_b2, k_g2,k_b2, v_g2,v_b2, QSCALE);
  vtrans_kernel<<<1296,256,0,stream>>>(vbf, vT);
  attn_kernel<<<dim3(27,12,8),256,0,stream>>>(qbf, kbf, vT, opart, lbuf);
  attn_post_kernel<<<864,256,0,stream>>>(opart, lbuf, no_w, no_b, aob);
  gemm_debed_kernel<<<dim3(24,27),256,0,stream>>>(aob, Btd, dh);
  final_kernel<<<432,256,0,stream>>>(dh, Bt48, o_g, o_b, o_tb2, skip, out);
}

// Round 9
// 338.015 us; speedup vs baseline: 4.4459x; 1.0136x over previous
//
#include <hip/hip_runtime.h>
#include <math.h>

#define BB_ 2
#define C0 6
#define S0 48
#define V0 (S0*S0*S0)      // 110592
#define C1 192
#define S1 24
#define V1 (S1*S1*S1)      // 13824
#define C2 768
#define S2 12
#define LL (S2*S2*S2)      // 1728
#define NH 12
#define HD 64
#define KDIM (C1*8)        // 1536
#define MDIM (BB_*LL)      // 3456

typedef __attribute__((ext_vector_type(8))) short short8;
typedef __attribute__((ext_vector_type(4))) short short4v;
typedef __attribute__((ext_vector_type(4))) float float4v;

static __device__ __forceinline__ float gelu_exact(float x){
  return 0.5f*x*(1.0f+erff(x*0.70710678118654752440f));
}
static __device__ __forceinline__ unsigned short f2bf(float f){
  unsigned int u = __float_as_uint(f);
  unsigned int r = (u + 0x7fffu + ((u>>16)&1u)) >> 16;
  return (unsigned short)r;
}
static __device__ __forceinline__ unsigned int pk_bf16(float a, float b){
#if __has_builtin(__builtin_amdgcn_cvt_pk_bf16_f32)
  typedef __attribute__((ext_vector_type(2))) __bf16 bf2;
  bf2 r = __builtin_amdgcn_cvt_pk_bf16_f32(a,b);
  union { bf2 v; unsigned int u; } cv; cv.v = r;
  return cv.u;
#else
  return (unsigned int)f2bf(a) | ((unsigned int)f2bf(b)<<16);
#endif
}
static __device__ __forceinline__ float bf2f(unsigned short u){
  return __uint_as_float(((unsigned int)u)<<16);
}
static __device__ __forceinline__ void load_lds16(const void* g, void* l){
  __builtin_amdgcn_global_load_lds((const __attribute__((address_space(1))) unsigned int*)g,
      (__attribute__((address_space(3))) unsigned int*)l, 16, 0, 0);
}
static __device__ __forceinline__ float4v mfma32(short8 a, short8 b, float4v c){
  return __builtin_amdgcn_mfma_f32_16x16x32_bf16(a,b,c,0,0,0);
}
static __device__ __forceinline__ float4v mfma16(short4v a, short4v b, float4v c){
#if __has_builtin(__builtin_amdgcn_mfma_f32_16x16x16bf16_1k)
  return __builtin_amdgcn_mfma_f32_16x16x16bf16_1k(a,b,c,0,0,0);
#else
  asm volatile("v_mfma_f32_16x16x16_bf16 %0, %1, %2, %0" : "+v"(c) : "v"(a), "v"(b));
  return c;
#endif
}

// ---------------- prep: LN6 (skip,x) + all weight repacks, one launch ----------------
__global__ __launch_bounds__(256) void prep_kernel(
    const float* __restrict__ skin, const float* __restrict__ xin,
    const float* __restrict__ nsw, const float* __restrict__ nsb,
    const float* __restrict__ nxw, const float* __restrict__ nxb,
    unsigned short* __restrict__ outS, unsigned short* __restrict__ outX,
    const float* __restrict__ qw2, const float* __restrict__ kw2, const float* __restrict__ vw2,
    const float* __restrict__ tw1, const float* __restrict__ tw2,
    unsigned short* __restrict__ w2tq, unsigned short* __restrict__ w2tk,
    unsigned short* __restrict__ w2tv, unsigned short* __restrict__ Btd,
    unsigned short* __restrict__ Bt48){
  int bx = blockIdx.x;
  if (bx < 1728){                         // LN over 6 channels (channels_first)
    int z = bx >= 864;
    const float* in = z ? xin : skin;
    const float* w  = z ? nxw : nsw;
    const float* bi = z ? nxb : nsb;
    unsigned short* out = z ? outX : outS;
    int idx = (bx - z*864)*256 + threadIdx.x;
    int b = idx / V0, vox = idx - b*V0;
    const float* p = in + (size_t)b*(C0*V0) + vox;
    float v[C0]; float s=0.f;
#pragma unroll
    for (int c=0;c<C0;c++){ v[c]=p[(size_t)c*V0]; s+=v[c]; }
    float u = s*(1.f/C0);
    float ss=0.f;
#pragma unroll
    for (int c=0;c<C0;c++){ float d=v[c]-u; ss+=d*d; }
    float inv = rsqrtf(ss*(1.f/C0)+1e-6f);
    unsigned short* o = out + (size_t)b*(C0*V0) + vox;
#pragma unroll
    for (int c=0;c<C0;c++) o[(size_t)c*V0] = f2bf((v[c]-u)*inv*w[c]+bi[c]);
    return;
  }
  bx -= 1728;
  if (bx < 13824){                       // 3 x 4608 : w2 repacks -> [oc][p*192+ic]
    int z = bx/4608;
    int idx = (bx - z*4608)*256 + threadIdx.x;
    const float* w2 = (z==0)?qw2:((z==1)?kw2:vw2);
    unsigned short* o = (z==0)?w2tq:((z==1)?w2tk:w2tv);
    int oc = idx/KDIM; int r = idx-oc*KDIM; int p = r/C1; int ic = r-p*C1;
    o[idx] = f2bf(w2[(size_t)oc*KDIM + ic*8 + p]);
  } else if (bx < 18432){                // tw1 -> [kpq*192+o][p head-major]
    int idx = (bx-13824)*256 + threadIdx.x;
    int n = idx/C2; int p = idx-n*C2;
    int i = ((p&63)*NH) + (p>>6);
    int kpq = n/C1, o2 = n-kpq*C1;
    Btd[idx] = f2bf(tw1[(size_t)i*KDIM + o2*8 + kpq]);
  } else {                               // 48 blocks: tw2 -> [n=c*8+kpq pad64][i]
    int idx = (bx-18432)*256 + threadIdx.x;
    int n = idx/C1; int i = idx-n*C1;
    Bt48[idx] = (n<48) ? f2bf(tw2[(size_t)i*48 + n]) : (unsigned short)0;
  }
}

// ------------- conv1 via MFMA, one tile-job per wave -------------
__global__ __launch_bounds__(256) void conv1_kernel(
    const unsigned short* __restrict__ lnSb, const unsigned short* __restrict__ lnXb,
    const float* __restrict__ qw1, const float* __restrict__ qg1, const float* __restrict__ qb1,
    const float* __restrict__ kw1, const float* __restrict__ kg1, const float* __restrict__ kb1,
    const float* __restrict__ vw1, const float* __restrict__ vg1, const float* __restrict__ vb1,
    unsigned short* __restrict__ h1q, unsigned short* __restrict__ h1k,
    unsigned short* __restrict__ h1v){
  int z = blockIdx.z;
  const unsigned short* in = (z==0)? lnSb : lnXb;
  const float* w1 = (z==0)?qw1:((z==1)?kw1:vw1);
  const float* g1 = (z==0)?qg1:((z==1)?kg1:vg1);
  const float* b1 = (z==0)?qb1:((z==1)?kb1:vb1);
  unsigned short* h1p = (z==0)?h1q:((z==1)?h1k:h1v);
  __shared__ unsigned short Wl[C1*56];   // rows padded 48->56 shorts
  __shared__ float Gl[C1], Bl2[C1];
  int t = threadIdx.x, w = t>>6, lane = t&63;
  int g = lane>>4, l16 = lane&15;
  int j = blockIdx.x*4 + w;
  int bxh = j/18, mt = j - bxh*18;
  int b = bxh/48; int rem = bxh - b*48; int y = rem>>1, xh = rem&1;
  int xo = mt/3, zo = mt - xo*3;
  int xv = xh*12 + xo*2 + (l16>>3);
  int zv = zo*8 + (l16&7);
  int x2 = 2*xv, z2 = 2*zv, y2 = 2*y;
  const unsigned short* base = in + (size_t)b*C0*V0;
  union { short8 v; unsigned int u[4]; } aA;     // k=g*8+jj  -> ic=g, p=jj
  {
    size_t rb = (size_t)g*V0;
    aA.u[0] = *(const unsigned int*)&base[rb + (y2+0)*(S0*S0) + (x2+0)*S0 + z2];
    aA.u[1] = *(const unsigned int*)&base[rb + (y2+0)*(S0*S0) + (x2+1)*S0 + z2];
    aA.u[2] = *(const unsigned int*)&base[rb + (y2+1)*(S0*S0) + (x2+0)*S0 + z2];
    aA.u[3] = *(const unsigned int*)&base[rb + (y2+1)*(S0*S0) + (x2+1)*S0 + z2];
  }
  union { short4v v; unsigned int u[2]; } aB;    // k=32+g*4+jj -> ic=4+(g>>1), p=(g&1)*4+jj
  {
    size_t rb = (size_t)(4+(g>>1))*V0 + (y2+(g&1))*(S0*S0);
    aB.u[0] = *(const unsigned int*)&base[rb + (x2+0)*S0 + z2];
    aB.u[1] = *(const unsigned int*)&base[rb + (x2+1)*S0 + z2];
  }
  for (int i4 = t; i4 < 2304; i4 += 256){
    int oc = i4/12, kk4 = (i4 - oc*12)*4;
    float4 f4 = *(const float4*)&w1[oc*48 + kk4];
    uint2 pk; pk.x = pk_bf16(f4.x,f4.y); pk.y = pk_bf16(f4.z,f4.w);
    *(uint2*)&Wl[oc*56 + kk4] = pk;
  }
  if (t < C1){ Gl[t] = g1[t]; Bl2[t] = b1[t]; }
  __syncthreads();
  float4v acc[12];
#pragma unroll
  for (int ot=0; ot<12; ot++){
    short8  wA = *(const short8*)&Wl[(ot*16+l16)*56 + g*8];
    short4v wB = *(const short4v*)&Wl[(ot*16+l16)*56 + 32 + g*4];
    float4v a = {};
    a = mfma32(wA, aA.v, a);
    a = mfma16(wB, aB.v, a);
    acc[ot] = a;
  }
  float s1=0.f, s2=0.f;
#pragma unroll
  for (int ot=0;ot<12;ot++)
#pragma unroll
    for (int reg=0;reg<4;reg++){ float v=acc[ot][reg]; s1+=v; s2+=v*v; }
  s1 += __shfl_xor(s1,16); s1 += __shfl_xor(s1,32);
  s2 += __shfl_xor(s2,16); s2 += __shfl_xor(s2,32);
  float u = s1*(1.f/C1);
  float inv = rsqrtf(s2*(1.f/C1)-u*u+1e-6f);
  int tok = (y>>1)*(S2*S2) + (xv>>1)*S2 + (zv>>1);
  int p8 = (y&1)*4 + (xv&1)*2 + (zv&1);
  unsigned short* hb = h1p + (size_t)(b*LL+tok)*KDIM + p8*C1;
#pragma unroll
  for (int ot=0; ot<12; ot++){
    int oc0 = ot*16 + g*4;
    float4 gg = *(const float4*)&Gl[oc0];
    float4 bb = *(const float4*)&Bl2[oc0];
    float x0 = gelu_exact((acc[ot][0]-u)*inv*gg.x+bb.x);
    float x1 = gelu_exact((acc[ot][1]-u)*inv*gg.y+bb.y);
    float x2e= gelu_exact((acc[ot][2]-u)*inv*gg.z+bb.z);
    float x3 = gelu_exact((acc[ot][3]-u)*inv*gg.w+bb.w);
    uint2 pk; pk.x = pk_bf16(x0,x1); pk.y = pk_bf16(x2e,x3);
    *(uint2*)&hb[oc0] = pk;
  }
}

// ---------------- fused stem GEMM (z selects A/B/C), 128x128 tiles, BK=32, bf16 C ----------------
__global__ __launch_bounds__(256) void gemm_stem_kernel(
    const unsigned short* __restrict__ A0, const unsigned short* __restrict__ A1,
    const unsigned short* __restrict__ A2,
    const unsigned short* __restrict__ B0, const unsigned short* __restrict__ B1,
    const unsigned short* __restrict__ B2,
    unsigned short* __restrict__ Cq, unsigned short* __restrict__ Ck,
    unsigned short* __restrict__ Cv){
  int z = blockIdx.z;
  const unsigned short* A = (z==0)?A0:((z==1)?A1:A2);
  const unsigned short* Bt = (z==0)?B0:((z==1)?B1:B2);
  unsigned short* Cp = (z==0)?Cq:((z==1)?Ck:Cv);
  __shared__ __align__(16) unsigned short Al[128*32];
  __shared__ __align__(16) unsigned short Bl[128*32];
  int t=threadIdx.x, w=t>>6, lane=t&63;
  int g=lane>>4, l16=lane&15, r16=lane>>2, c16=lane&3;
  int m0=blockIdx.y*128, n0=blockIdx.x*128;
  int wm=w>>1, wn=w&1;
  float4v acc[4][4] = {};
  for (int kb=0;kb<KDIM;kb+=32){
    __syncthreads();
#pragma unroll
    for (int cc=0;cc<4;cc++){
      int ch = w*4+cc;
      if (ch<8){
        const unsigned short* gp = A + (size_t)(m0+ch*16+r16)*KDIM + kb + c16*8;
        load_lds16(gp, &Al[ch*512]);
      } else {
        const unsigned short* gp = Bt + (size_t)(n0+(ch-8)*16+r16)*KDIM + kb + c16*8;
        load_lds16(gp, &Bl[(ch-8)*512]);
      }
    }
    __syncthreads();
    short8 af[4], bf[4];
#pragma unroll
    for (int mt=0;mt<4;mt++) af[mt] = *(const short8*)&Al[(wm*64+mt*16+l16)*32 + g*8];
#pragma unroll
    for (int nt=0;nt<4;nt++) bf[nt] = *(const short8*)&Bl[(wn*64+nt*16+l16)*32 + g*8];
#pragma unroll
    for (int mt=0;mt<4;mt++)
#pragma unroll
      for (int nt=0;nt<4;nt++)
        acc[mt][nt] = mfma32(af[mt], bf[nt], acc[mt][nt]);
  }
#pragma unroll
  for (int mt=0;mt<4;mt++){
    int mb = m0 + wm*64 + mt*16 + g*4;
#pragma unroll
    for (int nt=0;nt<4;nt++){
      int col = n0 + wn*64 + nt*16 + l16;
#pragma unroll
      for (int reg=0;reg<4;reg++)
        Cp[(size_t)(mb+reg)*C2 + col] = f2bf(acc[mt][nt][reg]);
    }
  }
}

// ---------------- debed GEMM: n=kpq*192+o, scatter -> dh[(b*V1+v24)*192+o] bf16 ----------------
__global__ __launch_bounds__(256) void gemm_debed_kernel(const unsigned short* __restrict__ A,
    const unsigned short* __restrict__ Bt, unsigned short* __restrict__ C){
  __shared__ __align__(16) unsigned short Al[128*32];
  __shared__ __align__(16) unsigned short Bl[64*32];
  int t=threadIdx.x, w=t>>6, lane=t&63;
  int g=lane>>4, l16=lane&15, r16=lane>>2, c16=lane&3;
  int m0=blockIdx.y*128, n0=blockIdx.x*64;
  int wm=w>>1, wn=w&1;
  float4v acc[4][2] = {};
  for (int kb=0;kb<C2;kb+=32){
    __syncthreads();
#pragma unroll
    for (int cc=0;cc<3;cc++){
      int ch = w*3+cc;
      if (ch<8){
        const unsigned short* gp = A + (size_t)(m0+ch*16+r16)*C2 + kb + c16*8;
        load_lds16(gp, &Al[ch*512]);
      } else {
        const unsigned short* gp = Bt + (size_t)(n0+(ch-8)*16+r16)*C2 + kb + c16*8;
        load_lds16(gp, &Bl[(ch-8)*512]);
      }
    }
    __syncthreads();
    short8 af[4], bf[2];
#pragma unroll
    for (int mt=0;mt<4;mt++) af[mt] = *(const short8*)&Al[(wm*64+mt*16+l16)*32 + g*8];
#pragma unroll
    for (int nt=0;nt<2;nt++) bf[nt] = *(const short8*)&Bl[(wn*32+nt*16+l16)*32 + g*8];
#pragma unroll
    for (int mt=0;mt<4;mt++)
#pragma unroll
      for (int nt=0;nt<2;nt++)
        acc[mt][nt] = mfma32(af[mt], bf[nt], acc[mt][nt]);
  }
  int kpq = (n0 + wn*32)/C1;
#pragma unroll
  for (int nt=0;nt<2;nt++){
    int n = n0 + wn*32 + nt*16 + l16;
    int o = n - kpq*C1;
#pragma unroll
    for (int mt=0;mt<4;mt++){
      int mb = m0 + wm*64 + mt*16 + g*4;
#pragma unroll
      for (int reg=0;reg<4;reg++){
        int m = mb + reg;
        int b = m / LL; int tok = m - b*LL;
        int h = tok/(S2*S2), ww=(tok/S2)%S2, d=tok%S2;
        int v24 = (2*h+((kpq>>2)&1))*(S1*S1) + (2*ww+((kpq>>1)&1))*S1 + (2*d+(kpq&1));
        C[(size_t)(b*V1+v24)*C1 + o] = f2bf(acc[mt][nt][reg]);
      }
    }
  }
}

// ---------------- final: LN(192)+GELU fused into convT2 GEMM + bias + residual ----------------
// dh is bf16 now.
__global__ __launch_bounds__(256) void final_kernel(const unsigned short* __restrict__ dh,
    const unsigned short* __restrict__ Bt48, const float* __restrict__ og,
    const float* __restrict__ ob, const float* __restrict__ tb2s,
    const float* __restrict__ skipp, float* __restrict__ out){
  __shared__ __align__(16) unsigned short As[64*200];
  __shared__ __align__(16) unsigned short Bs[64*200];
  int t=threadIdx.x, w=t>>6, lane=t&63;
  int g=lane>>4, l16=lane&15;
  int m0 = blockIdx.x*64;
  for (int n8 = t; n8 < 1536; n8 += 256){
    int n64 = n8/24, kk = (n8 - n64*24)*8;
    uint4 d4 = *(const uint4*)&Bt48[n64*192 + kk];
    *(uint4*)&Bs[n64*200 + kk] = d4;
  }
  float g0=og[lane], g1v=og[lane+64], g2v=og[lane+128];
  float b0=ob[lane], b1v=ob[lane+64], b2v=ob[lane+128];
  for (int rr=0; rr<16; rr++){
    int rl = w*16 + rr;
    const unsigned short* row = dh + (size_t)(m0+rl)*C1;
    float v0=bf2f(row[lane]), v1=bf2f(row[lane+64]), v2=bf2f(row[lane+128]);
    float s1=v0+v1+v2, s2=v0*v0+v1*v1+v2*v2;
#pragma unroll
    for (int off=32;off>0;off>>=1){ s1+=__shfl_xor(s1,off); s2+=__shfl_xor(s2,off); }
    float u=s1*(1.f/C1), inv=rsqrtf(s2*(1.f/C1)-u*u+1e-6f);
    As[rl*200+lane]     = f2bf(gelu_exact((v0-u)*inv*g0+b0));
    As[rl*200+lane+64]  = f2bf(gelu_exact((v1-u)*inv*g1v+b1v));
    As[rl*200+lane+128] = f2bf(gelu_exact((v2-u)*inv*g2v+b2v));
  }
  __syncthreads();
  int wm=w>>1, wn=w&1;
  float4v acc[2][2] = {};
#pragma unroll
  for (int kb=0;kb<192;kb+=32){
    short8 af[2], bf[2];
#pragma unroll
    for (int mt=0;mt<2;mt++) af[mt] = *(const short8*)&As[(wm*32+mt*16+l16)*200 + kb + g*8];
#pragma unroll
    for (int nt=0;nt<2;nt++) bf[nt] = *(const short8*)&Bs[(wn*32+nt*16+l16)*200 + kb + g*8];
#pragma unroll
    for (int mt=0;mt<2;mt++)
#pragma unroll
      for (int nt=0;nt<2;nt++)
        acc[mt][nt] = mfma32(af[mt], bf[nt], acc[mt][nt]);
  }
#pragma unroll
  for (int nt=0;nt<2;nt++){
    int n = wn*32 + nt*16 + l16;
    if (n < 48){
      int c = n>>3, kpq = n&7;
      float bias = tb2s[c];
#pragma unroll
      for (int mt=0;mt<2;mt++){
        int mb = m0 + wm*32 + mt*16 + g*4;
#pragma unroll
        for (int reg=0;reg<4;reg++){
          int m = mb + reg;
          int b = m / V1; int v24 = m - b*V1;
          int y24 = v24/(S1*S1), x24=(v24/S1)%S1, z24=v24%S1;
          int vox = (2*y24+((kpq>>2)&1))*(S0*S0) + (2*x24+((kpq>>1)&1))*S0 + 2*z24+(kpq&1);
          size_t oi = (size_t)(b*C0+c)*V0 + vox;
          out[oi] = acc[mt][nt][reg] + bias + skipp[oi];
        }
      }
    }
  }
}

// ------------- fused stem LN over 768 (in-place bf16): z=0 q(rope,scale) z=1 k(rope) z=2 v -------------
__global__ __launch_bounds__(64) void ln768_stem_kernel(
    unsigned short* __restrict__ qb, unsigned short* __restrict__ kb2,
    unsigned short* __restrict__ vb,
    const float* __restrict__ qg, const float* __restrict__ qbi,
    const float* __restrict__ kg, const float* __restrict__ kbi,
    const float* __restrict__ vg, const float* __restrict__ vbi, float qscale){
  int z = blockIdx.y;
  unsigned short* buf = (z==0)?qb:((z==1)?kb2:vb);
  const float* g  = (z==0)?qg:((z==1)?kg:vg);
  const float* bia= (z==0)?qbi:((z==1)?kbi:vbi);
  float scale = (z==0)? qscale : 1.0f;
  int tok = blockIdx.x, lane = threadIdx.x;
  unsigned short* row = buf + (size_t)tok*C2;
  float v[12]; float s1=0.f,s2=0.f;
#pragma unroll
  for (int i=0;i<12;i++){ float t=bf2f(row[i*64+lane]); v[i]=t; s1+=t; s2+=t*t; }
#pragma unroll
  for (int off=32;off>0;off>>=1){ s1+=__shfl_xor(s1,off); s2+=__shfl_xor(s2,off); }
  float u=s1*(1.f/C2);
  float inv=rsqrtf(s2*(1.f/C2)-u*u+1e-6f);
  if (z==2){
#pragma unroll
    for (int i=0;i<12;i++){ int j=i*64+lane; row[j]=f2bf((v[i]-u)*inv*g[j]+bia[j]); }
  } else {
    int pos = tok % LL;
#pragma unroll
    for (int i=0;i<6;i++){
      int j=i*64+lane;
      float xn1=(v[i]-u)*inv*g[j]+bia[j];
      float xn2=(v[i+6]-u)*inv*g[j+384]+bia[j+384];
      float fr=(float)pos*__expf(-0.02398526139f*(float)j);  // 10000^{-j/384}
      float cs=cosf(fr), sn=sinf(fr);
      row[j]     = f2bf((xn1*cs - xn2*sn)*scale);
      row[j+384] = f2bf((xn2*cs + xn1*sn)*scale);
    }
  }
}

// ------------- V transpose: vbf [m][768] bf16 -> vT [(b*12+h)*64+d][1728] bf16 -------------
__global__ __launch_bounds__(256) void vtrans_kernel(const unsigned short* __restrict__ vbf,
    unsigned short* __restrict__ vT){
  int idx = blockIdx.x*256 + threadIdx.x;
  int token = idx % LL;
  int rest = idx / LL;
  int dc = rest & 7;
  int hb = rest >> 3;
  int h = hb % NH, b = hb / NH;
  const unsigned short* src = vbf + (size_t)(b*LL+token)*C2 + h*64 + dc*8;
  uint4 d4 = *(const uint4*)src;
  const unsigned short* s = (const unsigned short*)&d4;
#pragma unroll
  for (int i=0;i<8;i++)
    vT[(size_t)((b*NH+h)*HD + dc*8 + i)*LL + token] = s[i];
}

// ---------------- transposed MFMA flash attention, split-K x4, raw exp2 (no max) ----------------
__global__ __launch_bounds__(256) void attn_kernel(const unsigned short* __restrict__ q,
    const unsigned short* __restrict__ k, const unsigned short* __restrict__ vt,
    unsigned short* __restrict__ opart, float* __restrict__ lbuf){
  __shared__ __align__(16) unsigned char smem[18432];
  unsigned short* Ks = (unsigned short*)smem;       // [64 keys][64 d] chunk-swizzled
  unsigned short* Vs = Ks + 4096;                   // [64 d][64 keys]
  int qt=blockIdx.x, h=blockIdx.y;
  int b = blockIdx.z>>2, split = blockIdx.z&3;
  int t=threadIdx.x, w=t>>6, lane=t&63;
  int g=lane>>4, l16=lane&15;
  const unsigned short* qrow = q + (size_t)(b*LL + qt*64 + w*16 + l16)*C2 + h*64;
  short8 qA = *(const short8*)(qrow + g*8);
  short8 qB = *(const short8*)(qrow + 32 + g*8);
  const unsigned short* kbase = k + (size_t)(b*LL)*C2 + h*64;
  const unsigned short* vbase = vt + (size_t)((b*NH+h)*HD)*LL;
  int sub = lane>>3;
  int chs = (lane&7) ^ sub;
  float lrow = 0.f;
  float4v O4[4] = {};
  int ktb = split*7, kte = (split==3)? 27 : (split*7+7);
  for (int kt=ktb; kt<kte; kt++){
    __syncthreads();
#pragma unroll
    for (int cc=0;cc<4;cc++){
      int ii = w*4+cc;
      if (ii<8){
        int key = kt*64 + ii*8 + sub;
        load_lds16(kbase + (size_t)key*C2 + chs*8, &Ks[ii*512]);
      } else {
        int d = (ii-8)*8 + sub;
        load_lds16(vbase + (size_t)d*LL + kt*64 + chs*8, &Vs[(ii-8)*512]);
      }
    }
    __syncthreads();
    float4v sc[4];
#pragma unroll
    for (int nt=0;nt<4;nt++){
      int row = nt*16 + l16;
      int sw = row & 7;
      short8 k1 = *(const short8*)&Ks[row*64 + ((g^sw))*8];
      short8 k2 = *(const short8*)&Ks[row*64 + (((4+g)^sw))*8];
      float4v z = {};
      z = mfma32(k1, qA, z);
      z = mfma32(k2, qB, z);
      sc[nt] = z;
    }
#pragma unroll
    for (int nt=0;nt<4;nt++)
#pragma unroll
      for (int reg=0;reg<4;reg++){
        float e = exp2f(sc[nt][reg]); sc[nt][reg]=e; lrow+=e;
      }
#pragma unroll
    for (int kc=0;kc<4;kc++){
      union { short4v v; unsigned int u[2]; } pb;
      pb.u[0] = pk_bf16(sc[kc][0], sc[kc][1]);
      pb.u[1] = pk_bf16(sc[kc][2], sc[kc][3]);
#pragma unroll
      for (int dt=0;dt<4;dt++){
        int row = dt*16 + l16;
        int ch = (kc*2 + (g>>1)) ^ (row&7);
        short4v va = *(const short4v*)&Vs[row*64 + ch*8 + (g&1)*4];
        O4[dt] = mfma16(va, pb.v, O4[dt]);
      }
    }
  }
  lrow += __shfl_xor(lrow,16);
  lrow += __shfl_xor(lrow,32);
  __syncthreads();                       // reuse smem for transpose
  float* Ot = (float*)smem;
  float* ot = Ot + w*1152;
#pragma unroll
  for (int dt=0;dt<4;dt++)
    *(float4*)&ot[l16*72 + dt*16 + g*4] =
        make_float4(O4[dt][0],O4[dt][1],O4[dt][2],O4[dt][3]);
  if (g==0){
    int qi = qt*64 + w*16 + l16;
    lbuf[((size_t)(b*4+split)*NH+h)*LL + qi] = lrow;
  }
  int qq = lane>>2, c4 = lane&3;
  unsigned short* orow = opart + (size_t)split*MDIM*C2
              + (size_t)(b*LL + qt*64 + w*16 + qq)*C2 + h*64;
#pragma unroll
  for (int p=0;p<4;p++){
    float4 vv = *(float4*)&ot[qq*72 + p*16 + c4*4];
    uint2 pk; pk.x = pk_bf16(vv.x,vv.y); pk.y = pk_bf16(vv.z,vv.w);
    *(uint2*)&orow[p*16 + c4*4] = pk;
  }
}

// ---------------- combine 4 splits + post-attn LN (permuted gamma) -> bf16 aob ----------------
__global__ __launch_bounds__(256) void attn_post_kernel(const unsigned short* __restrict__ opart,
    const float* __restrict__ lbuf,
    const float* __restrict__ g, const float* __restrict__ bia,
    unsigned short* __restrict__ aob){
  int t=threadIdx.x, w=t>>6, lane=t&63;
  int m = blockIdx.x*4 + w;               // grid 864
  int b = m / LL, l = m - b*LL;
  const unsigned short* o0 = opart + (size_t)m*C2;
  unsigned short* orow = aob + (size_t)m*C2;
  float vv[12]; float s1=0.f, s2=0.f;
#pragma unroll
  for (int i=0;i<12;i++){
    float ls = 0.f;
#pragma unroll
    for (int s=0;s<4;s++) ls += lbuf[((size_t)(b*4+s)*NH+i)*LL + l];
    float inv = 1.f/ls;
    int j = i*64+lane;
    float val = 0.f;
#pragma unroll
    for (int s=0;s<4;s++) val += bf2f(o0[(size_t)s*MDIM*C2 + j]);
    val *= inv;
    vv[i]=val; s1+=val; s2+=val*val;
  }
#pragma unroll
  for (int off=32;off>0;off>>=1){ s1+=__shfl_xor(s1,off); s2+=__shfl_xor(s2,off); }
  float u=s1*(1.f/C2);
  float invs=rsqrtf(s2*(1.f/C2)-u*u+1e-6f);
#pragma unroll
  for (int i=0;i<12;i++){
    int cj = lane*NH + i;                 // permuted gamma: channel p=h*64+d -> c=d*12+h
    orow[i*64+lane] = f2bf((vv[i]-u)*invs*g[cj]+bia[cj]);
  }
}

extern "C" void kernel_launch(void* const* d_in, const int* in_sizes, int n_in,
                              void* d_out, int out_size, void* d_ws, size_t ws_size,
                              hipStream_t stream){
  (void)in_sizes; (void)n_in; (void)out_size; (void)ws_size;
  const float* x    =(const float*)d_in[0];
  const float* skip =(const float*)d_in[1];
  const float* q_w1 =(const float*)d_in[2];
  const float* q_g1 =(const float*)d_in[3];
  const float* q_b1 =(const float*)d_in[4];
  const float* q_w2 =(const float*)d_in[5];
  const float* q_g2 =(const float*)d_in[6];
  const float* q_b2 =(const float*)d_in[7];
  const float* k_w1 =(const float*)d_in[8];
  const float* k_g1 =(const float*)d_in[9];
  const float* k_b1 =(const float*)d_in[10];
  const float* k_w2 =(const float*)d_in[11];
  const float* k_g2 =(const float*)d_in[12];
  const float* k_b2 =(const float*)d_in[13];
  const float* v_w1 =(const float*)d_in[14];
  const float* v_g1 =(const float*)d_in[15];
  const float* v_b1 =(const float*)d_in[16];
  const float* v_w2 =(const float*)d_in[17];
  const float* v_g2 =(const float*)d_in[18];
  const float* v_b2 =(const float*)d_in[19];
  const float* o_tw1=(const float*)d_in[20];
  const float* o_g  =(const float*)d_in[21];
  const float* o_b  =(const float*)d_in[22];
  const float* o_tw2=(const float*)d_in[23];
  const float* o_tb2=(const float*)d_in[24];
  const float* ns_w =(const float*)d_in[25];
  const float* ns_b =(const float*)d_in[26];
  const float* nx_w =(const float*)d_in[27];
  const float* nx_b =(const float*)d_in[28];
  const float* no_w =(const float*)d_in[29];
  const float* no_b =(const float*)d_in[30];
  float* out=(float*)d_out;

  char* W = (char*)d_ws;
  unsigned short* lnSb = (unsigned short*)(W + 0);          //  2,654,208
  unsigned short* lnXb = (unsigned short*)(W + 2654208);    //  2,654,208
  unsigned short* h1q  = (unsigned short*)(W + 5308416);    // 10,616,832
  unsigned short* h1k  = (unsigned short*)(W + 15925248);   // 10,616,832
  unsigned short* h1v  = (unsigned short*)(W + 26542080);   // 10,616,832
  unsigned short* w2tq = (unsigned short*)(W + 37158912);   //  2,359,296
  unsigned short* w2tk = (unsigned short*)(W + 39518208);   //  2,359,296
  unsigned short* w2tv = (unsigned short*)(W + 41877504);   //  2,359,296
  unsigned short* qbf  = (unsigned short*)(W + 44236800);   //  5,308,416
  unsigned short* kbf  = (unsigned short*)(W + 49545216);   //  5,308,416
  unsigned short* vbf  = (unsigned short*)(W + 54853632);   //  5,308,416
  unsigned short* vT   = (unsigned short*)(W + 60162048);   //  5,308,416
  unsigned short* aob  = (unsigned short*)(W + 65470464);   //  5,308,416
  unsigned short* Btd  = (unsigned short*)(W + 70778880);   //  2,359,296
  unsigned short* Bt48 = (unsigned short*)(W + 73138176);   //     24,576
  // overlays:
  float* lbuf  = (float*)(W + 0);                     // 663,552 (lnSb dead after conv1)
  unsigned short* opart = (unsigned short*)(W + 5308416);  // 4x5,308,416 bf16 (h1q+h1k dead)
  unsigned short* dh   = (unsigned short*)(W + 5308416);   // 10,616,832 bf16 (opart dead after attn_post)

  const float QSCALE = 0.125f*1.44269504089f;  // 1/sqrt(64) * log2(e)

  prep_kernel<<<20208,256,0,stream>>>(skip, x, ns_w, ns_b, nx_w, nx_b, lnSb, lnXb,
      q_w2,k_w2,v_w2,o_tw1,o_tw2, w2tq,w2tk,w2tv,Btd,Bt48);
  conv1_kernel<<<dim3(432,1,3),256,0,stream>>>(lnSb,lnXb,
      q_w1,q_g1,q_b1, k_w1,k_g1,k_b1, v_w1,v_g1,v_b1, h1q,h1k,h1v);
  gemm_stem_kernel<<<dim3(6,27,3),256,0,stream>>>(h1q,h1k,h1v,
      w2tq,w2tk,w2tv, qbf,kbf,vbf);
  ln768_stem_kernel<<<dim3(MDIM,3),64,0,stream>>>(qbf,kbf,vbf,
      q_g2,q_b2, k_g2,k_b2, v_g2,v_b2, QSCALE);
  vtrans_kernel<<<1296,256,0,stream>>>(vbf, vT);
  attn_kernel<<<dim3(27,12,8),256,0,stream>>>(qbf, kbf, vT, opart, lbuf);
  attn_post_kernel<<<864,256,0,stream>>>(opart, lbuf, no_w, no_b, aob);
  gemm_debed_kernel<<<dim3(24,27),256,0,stream>>>(aob, Btd, dh);
  final_kernel<<<432,256,0,stream>>>(dh, Bt48, o_g, o_b, o_tb2, skip, out);
}

// Round 10
// 334.805 us; speedup vs baseline: 4.4886x; 1.0096x over previous
//
#include <hip/hip_runtime.h>
#include <math.h>

#define BB_ 2
#define C0 6
#define S0 48
#define V0 (S0*S0*S0)      // 110592
#define C1 192
#define S1 24
#define V1 (S1*S1*S1)      // 13824
#define C2 768
#define S2 12
#define LL (S2*S2*S2)      // 1728
#define NH 12
#define HD 64
#define KDIM (C1*8)        // 1536
#define MDIM (BB_*LL)      // 3456

typedef __attribute__((ext_vector_type(8))) short short8;
typedef __attribute__((ext_vector_type(4))) short short4v;
typedef __attribute__((ext_vector_type(4))) float float4v;

static __device__ __forceinline__ float gelu_exact(float x){
  return 0.5f*x*(1.0f+erff(x*0.70710678118654752440f));
}
static __device__ __forceinline__ unsigned short f2bf(float f){
  unsigned int u = __float_as_uint(f);
  unsigned int r = (u + 0x7fffu + ((u>>16)&1u)) >> 16;
  return (unsigned short)r;
}
static __device__ __forceinline__ unsigned int pk_bf16(float a, float b){
#if __has_builtin(__builtin_amdgcn_cvt_pk_bf16_f32)
  typedef __attribute__((ext_vector_type(2))) __bf16 bf2;
  bf2 r = __builtin_amdgcn_cvt_pk_bf16_f32(a,b);
  union { bf2 v; unsigned int u; } cv; cv.v = r;
  return cv.u;
#else
  return (unsigned int)f2bf(a) | ((unsigned int)f2bf(b)<<16);
#endif
}
static __device__ __forceinline__ float bf2f(unsigned short u){
  return __uint_as_float(((unsigned int)u)<<16);
}
static __device__ __forceinline__ void load_lds16(const void* g, void* l){
  __builtin_amdgcn_global_load_lds((const __attribute__((address_space(1))) unsigned int*)g,
      (__attribute__((address_space(3))) unsigned int*)l, 16, 0, 0);
}
static __device__ __forceinline__ float4v mfma32(short8 a, short8 b, float4v c){
  return __builtin_amdgcn_mfma_f32_16x16x32_bf16(a,b,c,0,0,0);
}
static __device__ __forceinline__ float4v mfma16(short4v a, short4v b, float4v c){
#if __has_builtin(__builtin_amdgcn_mfma_f32_16x16x16bf16_1k)
  return __builtin_amdgcn_mfma_f32_16x16x16bf16_1k(a,b,c,0,0,0);
#else
  asm volatile("v_mfma_f32_16x16x16_bf16 %0, %1, %2, %0" : "+v"(c) : "v"(a), "v"(b));
  return c;
#endif
}

// ---------------- prep: LN6 (skip,x) + all weight repacks, one launch ----------------
__global__ __launch_bounds__(256) void prep_kernel(
    const float* __restrict__ skin, const float* __restrict__ xin,
    const float* __restrict__ nsw, const float* __restrict__ nsb,
    const float* __restrict__ nxw, const float* __restrict__ nxb,
    unsigned short* __restrict__ outS, unsigned short* __restrict__ outX,
    const float* __restrict__ qw2, const float* __restrict__ kw2, const float* __restrict__ vw2,
    const float* __restrict__ tw1, const float* __restrict__ tw2,
    unsigned short* __restrict__ w2tq, unsigned short* __restrict__ w2tk,
    unsigned short* __restrict__ w2tv, unsigned short* __restrict__ Btd,
    unsigned short* __restrict__ Bt48){
  int bx = blockIdx.x;
  if (bx < 1728){                         // LN over 6 channels (channels_first)
    int z = bx >= 864;
    const float* in = z ? xin : skin;
    const float* w  = z ? nxw : nsw;
    const float* bi = z ? nxb : nsb;
    unsigned short* out = z ? outX : outS;
    int idx = (bx - z*864)*256 + threadIdx.x;
    int b = idx / V0, vox = idx - b*V0;
    const float* p = in + (size_t)b*(C0*V0) + vox;
    float v[C0]; float s=0.f;
#pragma unroll
    for (int c=0;c<C0;c++){ v[c]=p[(size_t)c*V0]; s+=v[c]; }
    float u = s*(1.f/C0);
    float ss=0.f;
#pragma unroll
    for (int c=0;c<C0;c++){ float d=v[c]-u; ss+=d*d; }
    float inv = rsqrtf(ss*(1.f/C0)+1e-6f);
    unsigned short* o = out + (size_t)b*(C0*V0) + vox;
#pragma unroll
    for (int c=0;c<C0;c++) o[(size_t)c*V0] = f2bf((v[c]-u)*inv*w[c]+bi[c]);
    return;
  }
  bx -= 1728;
  if (bx < 13824){                       // 3 x 4608 : w2 repacks -> [oc][p*192+ic]
    int z = bx/4608;
    int idx = (bx - z*4608)*256 + threadIdx.x;
    const float* w2 = (z==0)?qw2:((z==1)?kw2:vw2);
    unsigned short* o = (z==0)?w2tq:((z==1)?w2tk:w2tv);
    int oc = idx/KDIM; int r = idx-oc*KDIM; int p = r/C1; int ic = r-p*C1;
    o[idx] = f2bf(w2[(size_t)oc*KDIM + ic*8 + p]);
  } else if (bx < 18432){                // tw1 -> [kpq*192+o][p head-major]
    int idx = (bx-13824)*256 + threadIdx.x;
    int n = idx/C2; int p = idx-n*C2;
    int i = ((p&63)*NH) + (p>>6);
    int kpq = n/C1, o2 = n-kpq*C1;
    Btd[idx] = f2bf(tw1[(size_t)i*KDIM + o2*8 + kpq]);
  } else {                               // 48 blocks: tw2 -> [n=c*8+kpq pad64][i]
    int idx = (bx-18432)*256 + threadIdx.x;
    int n = idx/C1; int i = idx-n*C1;
    Bt48[idx] = (n<48) ? f2bf(tw2[(size_t)i*48 + n]) : (unsigned short)0;
  }
}

// ------------- conv1 via MFMA, one tile-job per wave -------------
__global__ __launch_bounds__(256) void conv1_kernel(
    const unsigned short* __restrict__ lnSb, const unsigned short* __restrict__ lnXb,
    const float* __restrict__ qw1, const float* __restrict__ qg1, const float* __restrict__ qb1,
    const float* __restrict__ kw1, const float* __restrict__ kg1, const float* __restrict__ kb1,
    const float* __restrict__ vw1, const float* __restrict__ vg1, const float* __restrict__ vb1,
    unsigned short* __restrict__ h1q, unsigned short* __restrict__ h1k,
    unsigned short* __restrict__ h1v){
  int z = blockIdx.z;
  const unsigned short* in = (z==0)? lnSb : lnXb;
  const float* w1 = (z==0)?qw1:((z==1)?kw1:vw1);
  const float* g1 = (z==0)?qg1:((z==1)?kg1:vg1);
  const float* b1 = (z==0)?qb1:((z==1)?kb1:vb1);
  unsigned short* h1p = (z==0)?h1q:((z==1)?h1k:h1v);
  __shared__ unsigned short Wl[C1*56];   // rows padded 48->56 shorts
  __shared__ float Gl[C1], Bl2[C1];
  int t = threadIdx.x, w = t>>6, lane = t&63;
  int g = lane>>4, l16 = lane&15;
  int j = blockIdx.x*4 + w;
  int bxh = j/18, mt = j - bxh*18;
  int b = bxh/48; int rem = bxh - b*48; int y = rem>>1, xh = rem&1;
  int xo = mt/3, zo = mt - xo*3;
  int xv = xh*12 + xo*2 + (l16>>3);
  int zv = zo*8 + (l16&7);
  int x2 = 2*xv, z2 = 2*zv, y2 = 2*y;
  const unsigned short* base = in + (size_t)b*C0*V0;
  union { short8 v; unsigned int u[4]; } aA;     // k=g*8+jj  -> ic=g, p=jj
  {
    size_t rb = (size_t)g*V0;
    aA.u[0] = *(const unsigned int*)&base[rb + (y2+0)*(S0*S0) + (x2+0)*S0 + z2];
    aA.u[1] = *(const unsigned int*)&base[rb + (y2+0)*(S0*S0) + (x2+1)*S0 + z2];
    aA.u[2] = *(const unsigned int*)&base[rb + (y2+1)*(S0*S0) + (x2+0)*S0 + z2];
    aA.u[3] = *(const unsigned int*)&base[rb + (y2+1)*(S0*S0) + (x2+1)*S0 + z2];
  }
  union { short4v v; unsigned int u[2]; } aB;    // k=32+g*4+jj -> ic=4+(g>>1), p=(g&1)*4+jj
  {
    size_t rb = (size_t)(4+(g>>1))*V0 + (y2+(g&1))*(S0*S0);
    aB.u[0] = *(const unsigned int*)&base[rb + (x2+0)*S0 + z2];
    aB.u[1] = *(const unsigned int*)&base[rb + (x2+1)*S0 + z2];
  }
  for (int i4 = t; i4 < 2304; i4 += 256){
    int oc = i4/12, kk4 = (i4 - oc*12)*4;
    float4 f4 = *(const float4*)&w1[oc*48 + kk4];
    uint2 pk; pk.x = pk_bf16(f4.x,f4.y); pk.y = pk_bf16(f4.z,f4.w);
    *(uint2*)&Wl[oc*56 + kk4] = pk;
  }
  if (t < C1){ Gl[t] = g1[t]; Bl2[t] = b1[t]; }
  __syncthreads();
  float4v acc[12];
#pragma unroll
  for (int ot=0; ot<12; ot++){
    short8  wA = *(const short8*)&Wl[(ot*16+l16)*56 + g*8];
    short4v wB = *(const short4v*)&Wl[(ot*16+l16)*56 + 32 + g*4];
    float4v a = {};
    a = mfma32(wA, aA.v, a);
    a = mfma16(wB, aB.v, a);
    acc[ot] = a;
  }
  float s1=0.f, s2=0.f;
#pragma unroll
  for (int ot=0;ot<12;ot++)
#pragma unroll
    for (int reg=0;reg<4;reg++){ float v=acc[ot][reg]; s1+=v; s2+=v*v; }
  s1 += __shfl_xor(s1,16); s1 += __shfl_xor(s1,32);
  s2 += __shfl_xor(s2,16); s2 += __shfl_xor(s2,32);
  float u = s1*(1.f/C1);
  float inv = rsqrtf(s2*(1.f/C1)-u*u+1e-6f);
  int tok = (y>>1)*(S2*S2) + (xv>>1)*S2 + (zv>>1);
  int p8 = (y&1)*4 + (xv&1)*2 + (zv&1);
  unsigned short* hb = h1p + (size_t)(b*LL+tok)*KDIM + p8*C1;
#pragma unroll
  for (int ot=0; ot<12; ot++){
    int oc0 = ot*16 + g*4;
    float4 gg = *(const float4*)&Gl[oc0];
    float4 bb = *(const float4*)&Bl2[oc0];
    float x0 = gelu_exact((acc[ot][0]-u)*inv*gg.x+bb.x);
    float x1 = gelu_exact((acc[ot][1]-u)*inv*gg.y+bb.y);
    float x2e= gelu_exact((acc[ot][2]-u)*inv*gg.z+bb.z);
    float x3 = gelu_exact((acc[ot][3]-u)*inv*gg.w+bb.w);
    uint2 pk; pk.x = pk_bf16(x0,x1); pk.y = pk_bf16(x2e,x3);
    *(uint2*)&hb[oc0] = pk;
  }
}

// ---------------- fused stem GEMM, 128x128 tiles, XCD-swizzled 1D grid ----------------
// 486 tiles (3 stems x 27 m x 6 n), grid 488; each XCD owns a contiguous slice of 61.
__global__ __launch_bounds__(256) void gemm_stem_kernel(
    const unsigned short* __restrict__ A0, const unsigned short* __restrict__ A1,
    const unsigned short* __restrict__ A2,
    const unsigned short* __restrict__ B0, const unsigned short* __restrict__ B1,
    const unsigned short* __restrict__ B2,
    unsigned short* __restrict__ Cq, unsigned short* __restrict__ Ck,
    unsigned short* __restrict__ Cv){
  int flat = blockIdx.x;
  int xcd = flat & 7, slot = flat >> 3;
  int tile = xcd*61 + slot;
  if (tile >= 486) return;
  int z = tile/162; int rr = tile - z*162;
  int m0 = (rr/6)*128, n0 = (rr - (rr/6)*6)*128;
  const unsigned short* A = (z==0)?A0:((z==1)?A1:A2);
  const unsigned short* Bt = (z==0)?B0:((z==1)?B1:B2);
  unsigned short* Cp = (z==0)?Cq:((z==1)?Ck:Cv);
  __shared__ __align__(16) unsigned short Al[128*32];
  __shared__ __align__(16) unsigned short Bl[128*32];
  int t=threadIdx.x, w=t>>6, lane=t&63;
  int g=lane>>4, l16=lane&15, r16=lane>>2, c16=lane&3;
  int wm=w>>1, wn=w&1;
  float4v acc[4][4] = {};
  for (int kb=0;kb<KDIM;kb+=32){
    __syncthreads();
#pragma unroll
    for (int cc=0;cc<4;cc++){
      int ch = w*4+cc;
      if (ch<8){
        const unsigned short* gp = A + (size_t)(m0+ch*16+r16)*KDIM + kb + c16*8;
        load_lds16(gp, &Al[ch*512]);
      } else {
        const unsigned short* gp = Bt + (size_t)(n0+(ch-8)*16+r16)*KDIM + kb + c16*8;
        load_lds16(gp, &Bl[(ch-8)*512]);
      }
    }
    __syncthreads();
    short8 af[4], bf[4];
#pragma unroll
    for (int mt=0;mt<4;mt++) af[mt] = *(const short8*)&Al[(wm*64+mt*16+l16)*32 + g*8];
#pragma unroll
    for (int nt=0;nt<4;nt++) bf[nt] = *(const short8*)&Bl[(wn*64+nt*16+l16)*32 + g*8];
#pragma unroll
    for (int mt=0;mt<4;mt++)
#pragma unroll
      for (int nt=0;nt<4;nt++)
        acc[mt][nt] = mfma32(af[mt], bf[nt], acc[mt][nt]);
  }
#pragma unroll
  for (int mt=0;mt<4;mt++){
    int mb = m0 + wm*64 + mt*16 + g*4;
#pragma unroll
    for (int nt=0;nt<4;nt++){
      int col = n0 + wn*64 + nt*16 + l16;
#pragma unroll
      for (int reg=0;reg<4;reg++)
        Cp[(size_t)(mb+reg)*C2 + col] = f2bf(acc[mt][nt][reg]);
    }
  }
}

// ---------------- debed GEMM: 128x128 tiles, XCD-swizzled; scatter -> dh bf16 ----------------
// 324 tiles (27 m x 12 n), grid 328; each XCD owns 41 consecutive.
__global__ __launch_bounds__(256) void gemm_debed_kernel(const unsigned short* __restrict__ A,
    const unsigned short* __restrict__ Bt, unsigned short* __restrict__ C){
  int flat = blockIdx.x;
  int xcd = flat & 7, slot = flat >> 3;
  int tile = xcd*41 + slot;
  if (tile >= 324) return;
  int m0 = (tile/12)*128, n0 = (tile - (tile/12)*12)*128;
  __shared__ __align__(16) unsigned short Al[128*32];
  __shared__ __align__(16) unsigned short Bl[128*32];
  int t=threadIdx.x, w=t>>6, lane=t&63;
  int g=lane>>4, l16=lane&15, r16=lane>>2, c16=lane&3;
  int wm=w>>1, wn=w&1;
  float4v acc[4][4] = {};
  for (int kb=0;kb<C2;kb+=32){
    __syncthreads();
#pragma unroll
    for (int cc=0;cc<4;cc++){
      int ch = w*4+cc;
      if (ch<8){
        const unsigned short* gp = A + (size_t)(m0+ch*16+r16)*C2 + kb + c16*8;
        load_lds16(gp, &Al[ch*512]);
      } else {
        const unsigned short* gp = Bt + (size_t)(n0+(ch-8)*16+r16)*C2 + kb + c16*8;
        load_lds16(gp, &Bl[(ch-8)*512]);
      }
    }
    __syncthreads();
    short8 af[4], bf[4];
#pragma unroll
    for (int mt=0;mt<4;mt++) af[mt] = *(const short8*)&Al[(wm*64+mt*16+l16)*32 + g*8];
#pragma unroll
    for (int nt=0;nt<4;nt++) bf[nt] = *(const short8*)&Bl[(wn*64+nt*16+l16)*32 + g*8];
#pragma unroll
    for (int mt=0;mt<4;mt++)
#pragma unroll
      for (int nt=0;nt<4;nt++)
        acc[mt][nt] = mfma32(af[mt], bf[nt], acc[mt][nt]);
  }
#pragma unroll
  for (int nt=0;nt<4;nt++){
    int n = n0 + wn*64 + nt*16 + l16;
    int kpq = n / C1;
    int o = n - kpq*C1;
#pragma unroll
    for (int mt=0;mt<4;mt++){
      int mb = m0 + wm*64 + mt*16 + g*4;
#pragma unroll
      for (int reg=0;reg<4;reg++){
        int m = mb + reg;
        int b = m / LL; int tok = m - b*LL;
        int h = tok/(S2*S2), ww=(tok/S2)%S2, d=tok%S2;
        int v24 = (2*h+((kpq>>2)&1))*(S1*S1) + (2*ww+((kpq>>1)&1))*S1 + (2*d+(kpq&1));
        C[(size_t)(b*V1+v24)*C1 + o] = f2bf(acc[mt][nt][reg]);
      }
    }
  }
}

// ---------------- final: LN(192)+GELU fused into convT2 GEMM + bias + residual ----------------
__global__ __launch_bounds__(256) void final_kernel(const unsigned short* __restrict__ dh,
    const unsigned short* __restrict__ Bt48, const float* __restrict__ og,
    const float* __restrict__ ob, const float* __restrict__ tb2s,
    const float* __restrict__ skipp, float* __restrict__ out){
  __shared__ __align__(16) unsigned short As[64*200];
  __shared__ __align__(16) unsigned short Bs[64*200];
  int t=threadIdx.x, w=t>>6, lane=t&63;
  int g=lane>>4, l16=lane&15;
  int m0 = blockIdx.x*64;
  for (int n8 = t; n8 < 1536; n8 += 256){
    int n64 = n8/24, kk = (n8 - n64*24)*8;
    uint4 d4 = *(const uint4*)&Bt48[n64*192 + kk];
    *(uint4*)&Bs[n64*200 + kk] = d4;
  }
  float g0=og[lane], g1v=og[lane+64], g2v=og[lane+128];
  float b0=ob[lane], b1v=ob[lane+64], b2v=ob[lane+128];
  for (int rr=0; rr<16; rr++){
    int rl = w*16 + rr;
    const unsigned short* row = dh + (size_t)(m0+rl)*C1;
    float v0=bf2f(row[lane]), v1=bf2f(row[lane+64]), v2=bf2f(row[lane+128]);
    float s1=v0+v1+v2, s2=v0*v0+v1*v1+v2*v2;
#pragma unroll
    for (int off=32;off>0;off>>=1){ s1+=__shfl_xor(s1,off); s2+=__shfl_xor(s2,off); }
    float u=s1*(1.f/C1), inv=rsqrtf(s2*(1.f/C1)-u*u+1e-6f);
    As[rl*200+lane]     = f2bf(gelu_exact((v0-u)*inv*g0+b0));
    As[rl*200+lane+64]  = f2bf(gelu_exact((v1-u)*inv*g1v+b1v));
    As[rl*200+lane+128] = f2bf(gelu_exact((v2-u)*inv*g2v+b2v));
  }
  __syncthreads();
  int wm=w>>1, wn=w&1;
  float4v acc[2][2] = {};
#pragma unroll
  for (int kb=0;kb<192;kb+=32){
    short8 af[2], bf[2];
#pragma unroll
    for (int mt=0;mt<2;mt++) af[mt] = *(const short8*)&As[(wm*32+mt*16+l16)*200 + kb + g*8];
#pragma unroll
    for (int nt=0;nt<2;nt++) bf[nt] = *(const short8*)&Bs[(wn*32+nt*16+l16)*200 + kb + g*8];
#pragma unroll
    for (int mt=0;mt<2;mt++)
#pragma unroll
      for (int nt=0;nt<2;nt++)
        acc[mt][nt] = mfma32(af[mt], bf[nt], acc[mt][nt]);
  }
#pragma unroll
  for (int nt=0;nt<2;nt++){
    int n = wn*32 + nt*16 + l16;
    if (n < 48){
      int c = n>>3, kpq = n&7;
      float bias = tb2s[c];
#pragma unroll
      for (int mt=0;mt<2;mt++){
        int mb = m0 + wm*32 + mt*16 + g*4;
#pragma unroll
        for (int reg=0;reg<4;reg++){
          int m = mb + reg;
          int b = m / V1; int v24 = m - b*V1;
          int y24 = v24/(S1*S1), x24=(v24/S1)%S1, z24=v24%S1;
          int vox = (2*y24+((kpq>>2)&1))*(S0*S0) + (2*x24+((kpq>>1)&1))*S0 + 2*z24+(kpq&1);
          size_t oi = (size_t)(b*C0+c)*V0 + vox;
          out[oi] = acc[mt][nt][reg] + bias + skipp[oi];
        }
      }
    }
  }
}

// ------------- fused stem LN over 768 (in-place bf16): z=0 q(rope,scale) z=1 k(rope) z=2 v -------------
__global__ __launch_bounds__(64) void ln768_stem_kernel(
    unsigned short* __restrict__ qb, unsigned short* __restrict__ kb2,
    unsigned short* __restrict__ vb,
    const float* __restrict__ qg, const float* __restrict__ qbi,
    const float* __restrict__ kg, const float* __restrict__ kbi,
    const float* __restrict__ vg, const float* __restrict__ vbi, float qscale){
  int z = blockIdx.y;
  unsigned short* buf = (z==0)?qb:((z==1)?kb2:vb);
  const float* g  = (z==0)?qg:((z==1)?kg:vg);
  const float* bia= (z==0)?qbi:((z==1)?kbi:vbi);
  float scale = (z==0)? qscale : 1.0f;
  int tok = blockIdx.x, lane = threadIdx.x;
  unsigned short* row = buf + (size_t)tok*C2;
  float v[12]; float s1=0.f,s2=0.f;
#pragma unroll
  for (int i=0;i<12;i++){ float t=bf2f(row[i*64+lane]); v[i]=t; s1+=t; s2+=t*t; }
#pragma unroll
  for (int off=32;off>0;off>>=1){ s1+=__shfl_xor(s1,off); s2+=__shfl_xor(s2,off); }
  float u=s1*(1.f/C2);
  float inv=rsqrtf(s2*(1.f/C2)-u*u+1e-6f);
  if (z==2){
#pragma unroll
    for (int i=0;i<12;i++){ int j=i*64+lane; row[j]=f2bf((v[i]-u)*inv*g[j]+bia[j]); }
  } else {
    int pos = tok % LL;
#pragma unroll
    for (int i=0;i<6;i++){
      int j=i*64+lane;
      float xn1=(v[i]-u)*inv*g[j]+bia[j];
      float xn2=(v[i+6]-u)*inv*g[j+384]+bia[j+384];
      float fr=(float)pos*__expf(-0.02398526139f*(float)j);  // 10000^{-j/384}
      float cs=cosf(fr), sn=sinf(fr);
      row[j]     = f2bf((xn1*cs - xn2*sn)*scale);
      row[j+384] = f2bf((xn2*cs + xn1*sn)*scale);
    }
  }
}

// ------------- V transpose: vbf [m][768] bf16 -> vT [(b*12+h)*64+d][1728] bf16 -------------
__global__ __launch_bounds__(256) void vtrans_kernel(const unsigned short* __restrict__ vbf,
    unsigned short* __restrict__ vT){
  int idx = blockIdx.x*256 + threadIdx.x;
  int token = idx % LL;
  int rest = idx / LL;
  int dc = rest & 7;
  int hb = rest >> 3;
  int h = hb % NH, b = hb / NH;
  const unsigned short* src = vbf + (size_t)(b*LL+token)*C2 + h*64 + dc*8;
  uint4 d4 = *(const uint4*)src;
  const unsigned short* s = (const unsigned short*)&d4;
#pragma unroll
  for (int i=0;i<8;i++)
    vT[(size_t)((b*NH+h)*HD + dc*8 + i)*LL + token] = s[i];
}

// ---------------- transposed MFMA flash attention, split-K x4, raw exp2 (no max) ----------------
__global__ __launch_bounds__(256) void attn_kernel(const unsigned short* __restrict__ q,
    const unsigned short* __restrict__ k, const unsigned short* __restrict__ vt,
    unsigned short* __restrict__ opart, float* __restrict__ lbuf){
  __shared__ __align__(16) unsigned char smem[18432];
  unsigned short* Ks = (unsigned short*)smem;       // [64 keys][64 d] chunk-swizzled
  unsigned short* Vs = Ks + 4096;                   // [64 d][64 keys]
  int qt=blockIdx.x, h=blockIdx.y;
  int b = blockIdx.z>>2, split = blockIdx.z&3;
  int t=threadIdx.x, w=t>>6, lane=t&63;
  int g=lane>>4, l16=lane&15;
  const unsigned short* qrow = q + (size_t)(b*LL + qt*64 + w*16 + l16)*C2 + h*64;
  short8 qA = *(const short8*)(qrow + g*8);
  short8 qB = *(const short8*)(qrow + 32 + g*8);
  const unsigned short* kbase = k + (size_t)(b*LL)*C2 + h*64;
  const unsigned short* vbase = vt + (size_t)((b*NH+h)*HD)*LL;
  int sub = lane>>3;
  int chs = (lane&7) ^ sub;
  float lrow = 0.f;
  float4v O4[4] = {};
  int ktb = split*7, kte = (split==3)? 27 : (split*7+7);
  for (int kt=ktb; kt<kte; kt++){
    __syncthreads();
#pragma unroll
    for (int cc=0;cc<4;cc++){
      int ii = w*4+cc;
      if (ii<8){
        int key = kt*64 + ii*8 + sub;
        load_lds16(kbase + (size_t)key*C2 + chs*8, &Ks[ii*512]);
      } else {
        int d = (ii-8)*8 + sub;
        load_lds16(vbase + (size_t)d*LL + kt*64 + chs*8, &Vs[(ii-8)*512]);
      }
    }
    __syncthreads();
    float4v sc[4];
#pragma unroll
    for (int nt=0;nt<4;nt++){
      int row = nt*16 + l16;
      int sw = row & 7;
      short8 k1 = *(const short8*)&Ks[row*64 + ((g^sw))*8];
      short8 k2 = *(const short8*)&Ks[row*64 + (((4+g)^sw))*8];
      float4v z = {};
      z = mfma32(k1, qA, z);
      z = mfma32(k2, qB, z);
      sc[nt] = z;
    }
#pragma unroll
    for (int nt=0;nt<4;nt++)
#pragma unroll
      for (int reg=0;reg<4;reg++){
        float e = exp2f(sc[nt][reg]); sc[nt][reg]=e; lrow+=e;
      }
#pragma unroll
    for (int kc=0;kc<4;kc++){
      union { short4v v; unsigned int u[2]; } pb;
      pb.u[0] = pk_bf16(sc[kc][0], sc[kc][1]);
      pb.u[1] = pk_bf16(sc[kc][2], sc[kc][3]);
#pragma unroll
      for (int dt=0;dt<4;dt++){
        int row = dt*16 + l16;
        int ch = (kc*2 + (g>>1)) ^ (row&7);
        short4v va = *(const short4v*)&Vs[row*64 + ch*8 + (g&1)*4];
        O4[dt] = mfma16(va, pb.v, O4[dt]);
      }
    }
  }
  lrow += __shfl_xor(lrow,16);
  lrow += __shfl_xor(lrow,32);
  __syncthreads();                       // reuse smem for transpose
  float* Ot = (float*)smem;
  float* ot = Ot + w*1152;
#pragma unroll
  for (int dt=0;dt<4;dt++)
    *(float4*)&ot[l16*72 + dt*16 + g*4] =
        make_float4(O4[dt][0],O4[dt][1],O4[dt][2],O4[dt][3]);
  if (g==0){
    int qi = qt*64 + w*16 + l16;
    lbuf[((size_t)(b*4+split)*NH+h)*LL + qi] = lrow;
  }
  int qq = lane>>2, c4 = lane&3;
  unsigned short* orow = opart + (size_t)split*MDIM*C2
              + (size_t)(b*LL + qt*64 + w*16 + qq)*C2 + h*64;
#pragma unroll
  for (int p=0;p<4;p++){
    float4 vv = *(float4*)&ot[qq*72 + p*16 + c4*4];
    uint2 pk; pk.x = pk_bf16(vv.x,vv.y); pk.y = pk_bf16(vv.z,vv.w);
    *(uint2*)&orow[p*16 + c4*4] = pk;
  }
}

// ---------------- combine 4 splits + post-attn LN (permuted gamma) -> bf16 aob ----------------
__global__ __launch_bounds__(256) void attn_post_kernel(const unsigned short* __restrict__ opart,
    const float* __restrict__ lbuf,
    const float* __restrict__ g, const float* __restrict__ bia,
    unsigned short* __restrict__ aob){
  int t=threadIdx.x, w=t>>6, lane=t&63;
  int m = blockIdx.x*4 + w;               // grid 864
  int b = m / LL, l = m - b*LL;
  const unsigned short* o0 = opart + (size_t)m*C2;
  unsigned short* orow = aob + (size_t)m*C2;
  float vv[12]; float s1=0.f, s2=0.f;
#pragma unroll
  for (int i=0;i<12;i++){
    float ls = 0.f;
#pragma unroll
    for (int s=0;s<4;s++) ls += lbuf[((size_t)(b*4+s)*NH+i)*LL + l];
    float inv = 1.f/ls;
    int j = i*64+lane;
    float val = 0.f;
#pragma unroll
    for (int s=0;s<4;s++) val += bf2f(o0[(size_t)s*MDIM*C2 + j]);
    val *= inv;
    vv[i]=val; s1+=val; s2+=val*val;
  }
#pragma unroll
  for (int off=32;off>0;off>>=1){ s1+=__shfl_xor(s1,off); s2+=__shfl_xor(s2,off); }
  float u=s1*(1.f/C2);
  float invs=rsqrtf(s2*(1.f/C2)-u*u+1e-6f);
#pragma unroll
  for (int i=0;i<12;i++){
    int cj = lane*NH + i;                 // permuted gamma: channel p=h*64+d -> c=d*12+h
    orow[i*64+lane] = f2bf((vv[i]-u)*invs*g[cj]+bia[cj]);
  }
}

extern "C" void kernel_launch(void* const* d_in, const int* in_sizes, int n_in,
                              void* d_out, int out_size, void* d_ws, size_t ws_size,
                              hipStream_t stream){
  (void)in_sizes; (void)n_in; (void)out_size; (void)ws_size;
  const float* x    =(const float*)d_in[0];
  const float* skip =(const float*)d_in[1];
  const float* q_w1 =(const float*)d_in[2];
  const float* q_g1 =(const float*)d_in[3];
  const float* q_b1 =(const float*)d_in[4];
  const float* q_w2 =(const float*)d_in[5];
  const float* q_g2 =(const float*)d_in[6];
  const float* q_b2 =(const float*)d_in[7];
  const float* k_w1 =(const float*)d_in[8];
  const float* k_g1 =(const float*)d_in[9];
  const float* k_b1 =(const float*)d_in[10];
  const float* k_w2 =(const float*)d_in[11];
  const float* k_g2 =(const float*)d_in[12];
  const float* k_b2 =(const float*)d_in[13];
  const float* v_w1 =(const float*)d_in[14];
  const float* v_g1 =(const float*)d_in[15];
  const float* v_b1 =(const float*)d_in[16];
  const float* v_w2 =(const float*)d_in[17];
  const float* v_g2 =(const float*)d_in[18];
  const float* v_b2 =(const float*)d_in[19];
  const float* o_tw1=(const float*)d_in[20];
  const float* o_g  =(const float*)d_in[21];
  const float* o_b  =(const float*)d_in[22];
  const float* o_tw2=(const float*)d_in[23];
  const float* o_tb2=(const float*)d_in[24];
  const float* ns_w =(const float*)d_in[25];
  const float* ns_b =(const float*)d_in[26];
  const float* nx_w =(const float*)d_in[27];
  const float* nx_b =(const float*)d_in[28];
  const float* no_w =(const float*)d_in[29];
  const float* no_b =(const float*)d_in[30];
  float* out=(float*)d_out;

  char* W = (char*)d_ws;
  unsigned short* lnSb = (unsigned short*)(W + 0);          //  2,654,208
  unsigned short* lnXb = (unsigned short*)(W + 2654208);    //  2,654,208
  unsigned short* h1q  = (unsigned short*)(W + 5308416);    // 10,616,832
  unsigned short* h1k  = (unsigned short*)(W + 15925248);   // 10,616,832
  unsigned short* h1v  = (unsigned short*)(W + 26542080);   // 10,616,832
  unsigned short* w2tq = (unsigned short*)(W + 37158912);   //  2,359,296
  unsigned short* w2tk = (unsigned short*)(W + 39518208);   //  2,359,296
  unsigned short* w2tv = (unsigned short*)(W + 41877504);   //  2,359,296
  unsigned short* qbf  = (unsigned short*)(W + 44236800);   //  5,308,416
  unsigned short* kbf  = (unsigned short*)(W + 49545216);   //  5,308,416
  unsigned short* vbf  = (unsigned short*)(W + 54853632);   //  5,308,416
  unsigned short* vT   = (unsigned short*)(W + 60162048);   //  5,308,416
  unsigned short* aob  = (unsigned short*)(W + 65470464);   //  5,308,416
  unsigned short* Btd  = (unsigned short*)(W + 70778880);   //  2,359,296
  unsigned short* Bt48 = (unsigned short*)(W + 73138176);   //     24,576
  // overlays:
  float* lbuf  = (float*)(W + 0);                     // 663,552 (lnSb dead after conv1)
  unsigned short* opart = (unsigned short*)(W + 5308416);  // 4x5,308,416 bf16 (h1q+h1k dead)
  unsigned short* dh   = (unsigned short*)(W + 5308416);   // 10,616,832 bf16 (opart dead after attn_post)

  const float QSCALE = 0.125f*1.44269504089f;  // 1/sqrt(64) * log2(e)

  prep_kernel<<<20208,256,0,stream>>>(skip, x, ns_w, ns_b, nx_w, nx_b, lnSb, lnXb,
      q_w2,k_w2,v_w2,o_tw1,o_tw2, w2tq,w2tk,w2tv,Btd,Bt48);
  conv1_kernel<<<dim3(432,1,3),256,0,stream>>>(lnSb,lnXb,
      q_w1,q_g1,q_b1, k_w1,k_g1,k_b1, v_w1,v_g1,v_b1, h1q,h1k,h1v);
  gemm_stem_kernel<<<488,256,0,stream>>>(h1q,h1k,h1v,
      w2tq,w2tk,w2tv, qbf,kbf,vbf);
  ln768_stem_kernel<<<dim3(MDIM,3),64,0,stream>>>(qbf,kbf,vbf,
      q_g2,q_b2, k_g2,k_b2, v_g2,v_b2, QSCALE);
  vtrans_kernel<<<1296,256,0,stream>>>(vbf, vT);
  attn_kernel<<<dim3(27,12,8),256,0,stream>>>(qbf, kbf, vT, opart, lbuf);
  attn_post_kernel<<<864,256,0,stream>>>(opart, lbuf, no_w, no_b, aob);
  gemm_debed_kernel<<<328,256,0,stream>>>(aob, Btd, dh);
  final_kernel<<<432,256,0,stream>>>(dh, Bt48, o_g, o_b, o_tb2, skip, out);
}

// Round 11
// 329.043 us; speedup vs baseline: 4.5672x; 1.0175x over previous
//
#include <hip/hip_runtime.h>
#include <math.h>

#define BB_ 2
#define C0 6
#define S0 48
#define V0 (S0*S0*S0)      // 110592
#define C1 192
#define S1 24
#define V1 (S1*S1*S1)      // 13824
#define C2 768
#define S2 12
#define LL (S2*S2*S2)      // 1728
#define NH 12
#define HD 64
#define KDIM (C1*8)        // 1536
#define MDIM (BB_*LL)      // 3456

typedef __attribute__((ext_vector_type(8))) short short8;
typedef __attribute__((ext_vector_type(4))) short short4v;
typedef __attribute__((ext_vector_type(4))) float float4v;

static __device__ __forceinline__ float gelu_exact(float x){
  return 0.5f*x*(1.0f+erff(x*0.70710678118654752440f));
}
static __device__ __forceinline__ unsigned short f2bf(float f){
  unsigned int u = __float_as_uint(f);
  unsigned int r = (u + 0x7fffu + ((u>>16)&1u)) >> 16;
  return (unsigned short)r;
}
static __device__ __forceinline__ unsigned int pk_bf16(float a, float b){
#if __has_builtin(__builtin_amdgcn_cvt_pk_bf16_f32)
  typedef __attribute__((ext_vector_type(2))) __bf16 bf2;
  bf2 r = __builtin_amdgcn_cvt_pk_bf16_f32(a,b);
  union { bf2 v; unsigned int u; } cv; cv.v = r;
  return cv.u;
#else
  return (unsigned int)f2bf(a) | ((unsigned int)f2bf(b)<<16);
#endif
}
static __device__ __forceinline__ float bf2f(unsigned short u){
  return __uint_as_float(((unsigned int)u)<<16);
}
static __device__ __forceinline__ void load_lds16(const void* g, void* l){
  __builtin_amdgcn_global_load_lds((const __attribute__((address_space(1))) unsigned int*)g,
      (__attribute__((address_space(3))) unsigned int*)l, 16, 0, 0);
}
static __device__ __forceinline__ float4v mfma32(short8 a, short8 b, float4v c){
  return __builtin_amdgcn_mfma_f32_16x16x32_bf16(a,b,c,0,0,0);
}
static __device__ __forceinline__ float4v mfma16(short4v a, short4v b, float4v c){
#if __has_builtin(__builtin_amdgcn_mfma_f32_16x16x16bf16_1k)
  return __builtin_amdgcn_mfma_f32_16x16x16bf16_1k(a,b,c,0,0,0);
#else
  asm volatile("v_mfma_f32_16x16x16_bf16 %0, %1, %2, %0" : "+v"(c) : "v"(a), "v"(b));
  return c;
#endif
}

// ---------------- prep: LN6 (skip,x) + all weight repacks, one launch ----------------
__global__ __launch_bounds__(256) void prep_kernel(
    const float* __restrict__ skin, const float* __restrict__ xin,
    const float* __restrict__ nsw, const float* __restrict__ nsb,
    const float* __restrict__ nxw, const float* __restrict__ nxb,
    unsigned short* __restrict__ outS, unsigned short* __restrict__ outX,
    const float* __restrict__ qw2, const float* __restrict__ kw2, const float* __restrict__ vw2,
    const float* __restrict__ tw1, const float* __restrict__ tw2,
    const float* __restrict__ qw1, const float* __restrict__ kw1, const float* __restrict__ vw1,
    unsigned short* __restrict__ w2tq, unsigned short* __restrict__ w2tk,
    unsigned short* __restrict__ w2tv, unsigned short* __restrict__ Btd,
    unsigned short* __restrict__ Bt48,
    unsigned short* __restrict__ w1q, unsigned short* __restrict__ w1k,
    unsigned short* __restrict__ w1v){
  int bx = blockIdx.x;
  if (bx < 1728){                         // LN over 6 channels (channels_first)
    int z = bx >= 864;
    const float* in = z ? xin : skin;
    const float* w  = z ? nxw : nsw;
    const float* bi = z ? nxb : nsb;
    unsigned short* out = z ? outX : outS;
    int idx = (bx - z*864)*256 + threadIdx.x;
    int b = idx / V0, vox = idx - b*V0;
    const float* p = in + (size_t)b*(C0*V0) + vox;
    float v[C0]; float s=0.f;
#pragma unroll
    for (int c=0;c<C0;c++){ v[c]=p[(size_t)c*V0]; s+=v[c]; }
    float u = s*(1.f/C0);
    float ss=0.f;
#pragma unroll
    for (int c=0;c<C0;c++){ float d=v[c]-u; ss+=d*d; }
    float inv = rsqrtf(ss*(1.f/C0)+1e-6f);
    unsigned short* o = out + (size_t)b*(C0*V0) + vox;
#pragma unroll
    for (int c=0;c<C0;c++) o[(size_t)c*V0] = f2bf((v[c]-u)*inv*w[c]+bi[c]);
    return;
  }
  bx -= 1728;
  if (bx < 13824){                       // 3 x 4608 : w2 repacks -> [oc][p*192+ic]
    int z = bx/4608;
    int idx = (bx - z*4608)*256 + threadIdx.x;
    const float* w2 = (z==0)?qw2:((z==1)?kw2:vw2);
    unsigned short* o = (z==0)?w2tq:((z==1)?w2tk:w2tv);
    int oc = idx/KDIM; int r = idx-oc*KDIM; int p = r/C1; int ic = r-p*C1;
    o[idx] = f2bf(w2[(size_t)oc*KDIM + ic*8 + p]);
  } else if (bx < 18432){                // tw1 -> [kpq*192+o][p head-major]
    int idx = (bx-13824)*256 + threadIdx.x;
    int n = idx/C2; int p = idx-n*C2;
    int i = ((p&63)*NH) + (p>>6);
    int kpq = n/C1, o2 = n-kpq*C1;
    Btd[idx] = f2bf(tw1[(size_t)i*KDIM + o2*8 + kpq]);
  } else if (bx < 18480){                // 48 blocks: tw2 -> [n=c*8+kpq pad64][i]
    int idx = (bx-18432)*256 + threadIdx.x;
    int n = idx/C1; int i = idx-n*C1;
    Bt48[idx] = (n<48) ? f2bf(tw2[(size_t)i*48 + n]) : (unsigned short)0;
  } else {                               // 108 blocks: w1 -> bf16 passthrough
    int idx = (bx-18480)*256 + threadIdx.x;  // 27648 = 3*9216
    int z = idx / 9216; int r = idx - z*9216;
    const float* w1 = (z==0)?qw1:((z==1)?kw1:vw1);
    unsigned short* o = (z==0)?w1q:((z==1)?w1k:w1v);
    o[r] = f2bf(w1[r]);
  }
}

// ------------- conv1 via MFMA, one tile-job per wave, NO LDS (W bf16 in L1/L2) -------------
__global__ __launch_bounds__(256) void conv1_kernel(
    const unsigned short* __restrict__ lnSb, const unsigned short* __restrict__ lnXb,
    const unsigned short* __restrict__ w1bq, const unsigned short* __restrict__ w1bk,
    const unsigned short* __restrict__ w1bv,
    const float* __restrict__ qg1, const float* __restrict__ qb1,
    const float* __restrict__ kg1, const float* __restrict__ kb1,
    const float* __restrict__ vg1, const float* __restrict__ vb1,
    unsigned short* __restrict__ h1q, unsigned short* __restrict__ h1k,
    unsigned short* __restrict__ h1v){
  int z = blockIdx.z;
  const unsigned short* in = (z==0)? lnSb : lnXb;
  const unsigned short* Wb = (z==0)?w1bq:((z==1)?w1bk:w1bv);
  const float* g1 = (z==0)?qg1:((z==1)?kg1:vg1);
  const float* b1 = (z==0)?qb1:((z==1)?kb1:vb1);
  unsigned short* h1p = (z==0)?h1q:((z==1)?h1k:h1v);
  int t = threadIdx.x, w = t>>6, lane = t&63;
  int g = lane>>4, l16 = lane&15;
  int j = blockIdx.x*4 + w;
  int bxh = j/18, mt = j - bxh*18;
  int b = bxh/48; int rem = bxh - b*48; int y = rem>>1, xh = rem&1;
  int xo = mt/3, zo = mt - xo*3;
  int xv = xh*12 + xo*2 + (l16>>3);
  int zv = zo*8 + (l16&7);
  int x2 = 2*xv, z2 = 2*zv, y2 = 2*y;
  const unsigned short* base = in + (size_t)b*C0*V0;
  union { short8 v; unsigned int u[4]; } aA;     // k=g*8+jj  -> ic=g, p=jj
  {
    size_t rb = (size_t)g*V0;
    aA.u[0] = *(const unsigned int*)&base[rb + (y2+0)*(S0*S0) + (x2+0)*S0 + z2];
    aA.u[1] = *(const unsigned int*)&base[rb + (y2+0)*(S0*S0) + (x2+1)*S0 + z2];
    aA.u[2] = *(const unsigned int*)&base[rb + (y2+1)*(S0*S0) + (x2+0)*S0 + z2];
    aA.u[3] = *(const unsigned int*)&base[rb + (y2+1)*(S0*S0) + (x2+1)*S0 + z2];
  }
  union { short4v v; unsigned int u[2]; } aB;    // k=32+g*4+jj -> ic=4+(g>>1), p=(g&1)*4+jj
  {
    size_t rb = (size_t)(4+(g>>1))*V0 + (y2+(g&1))*(S0*S0);
    aB.u[0] = *(const unsigned int*)&base[rb + (x2+0)*S0 + z2];
    aB.u[1] = *(const unsigned int*)&base[rb + (x2+1)*S0 + z2];
  }
  float4v acc[12];
#pragma unroll
  for (int ot=0; ot<12; ot++){
    short8  wA = *(const short8*)&Wb[(ot*16+l16)*48 + g*8];
    short4v wB = *(const short4v*)&Wb[(ot*16+l16)*48 + 32 + g*4];
    float4v a = {};
    a = mfma32(wA, aA.v, a);
    a = mfma16(wB, aB.v, a);
    acc[ot] = a;
  }
  float s1=0.f, s2=0.f;
#pragma unroll
  for (int ot=0;ot<12;ot++)
#pragma unroll
    for (int reg=0;reg<4;reg++){ float v=acc[ot][reg]; s1+=v; s2+=v*v; }
  s1 += __shfl_xor(s1,16); s1 += __shfl_xor(s1,32);
  s2 += __shfl_xor(s2,16); s2 += __shfl_xor(s2,32);
  float u = s1*(1.f/C1);
  float inv = rsqrtf(s2*(1.f/C1)-u*u+1e-6f);
  int tok = (y>>1)*(S2*S2) + (xv>>1)*S2 + (zv>>1);
  int p8 = (y&1)*4 + (xv&1)*2 + (zv&1);
  unsigned short* hb = h1p + (size_t)(b*LL+tok)*KDIM + p8*C1;
#pragma unroll
  for (int ot=0; ot<12; ot++){
    int oc0 = ot*16 + g*4;
    float4 gg = *(const float4*)&g1[oc0];
    float4 bb = *(const float4*)&b1[oc0];
    float x0 = gelu_exact((acc[ot][0]-u)*inv*gg.x+bb.x);
    float x1 = gelu_exact((acc[ot][1]-u)*inv*gg.y+bb.y);
    float x2e= gelu_exact((acc[ot][2]-u)*inv*gg.z+bb.z);
    float x3 = gelu_exact((acc[ot][3]-u)*inv*gg.w+bb.w);
    uint2 pk; pk.x = pk_bf16(x0,x1); pk.y = pk_bf16(x2e,x3);
    *(uint2*)&hb[oc0] = pk;
  }
}

// ---------------- fused stem GEMM, 128x128 tiles, XCD-swizzled 1D grid ----------------
__global__ __launch_bounds__(256) void gemm_stem_kernel(
    const unsigned short* __restrict__ A0, const unsigned short* __restrict__ A1,
    const unsigned short* __restrict__ A2,
    const unsigned short* __restrict__ B0, const unsigned short* __restrict__ B1,
    const unsigned short* __restrict__ B2,
    unsigned short* __restrict__ Cq, unsigned short* __restrict__ Ck,
    unsigned short* __restrict__ Cv){
  int flat = blockIdx.x;
  int xcd = flat & 7, slot = flat >> 3;
  int tile = xcd*61 + slot;
  if (tile >= 486) return;
  int z = tile/162; int rr = tile - z*162;
  int m0 = (rr/6)*128, n0 = (rr - (rr/6)*6)*128;
  const unsigned short* A = (z==0)?A0:((z==1)?A1:A2);
  const unsigned short* Bt = (z==0)?B0:((z==1)?B1:B2);
  unsigned short* Cp = (z==0)?Cq:((z==1)?Ck:Cv);
  __shared__ __align__(16) unsigned short Al[128*32];
  __shared__ __align__(16) unsigned short Bl[128*32];
  int t=threadIdx.x, w=t>>6, lane=t&63;
  int g=lane>>4, l16=lane&15, r16=lane>>2, c16=lane&3;
  int wm=w>>1, wn=w&1;
  float4v acc[4][4] = {};
  for (int kb=0;kb<KDIM;kb+=32){
    __syncthreads();
#pragma unroll
    for (int cc=0;cc<4;cc++){
      int ch = w*4+cc;
      if (ch<8){
        const unsigned short* gp = A + (size_t)(m0+ch*16+r16)*KDIM + kb + c16*8;
        load_lds16(gp, &Al[ch*512]);
      } else {
        const unsigned short* gp = Bt + (size_t)(n0+(ch-8)*16+r16)*KDIM + kb + c16*8;
        load_lds16(gp, &Bl[(ch-8)*512]);
      }
    }
    __syncthreads();
    short8 af[4], bf[4];
#pragma unroll
    for (int mt=0;mt<4;mt++) af[mt] = *(const short8*)&Al[(wm*64+mt*16+l16)*32 + g*8];
#pragma unroll
    for (int nt=0;nt<4;nt++) bf[nt] = *(const short8*)&Bl[(wn*64+nt*16+l16)*32 + g*8];
#pragma unroll
    for (int mt=0;mt<4;mt++)
#pragma unroll
      for (int nt=0;nt<4;nt++)
        acc[mt][nt] = mfma32(af[mt], bf[nt], acc[mt][nt]);
  }
#pragma unroll
  for (int mt=0;mt<4;mt++){
    int mb = m0 + wm*64 + mt*16 + g*4;
#pragma unroll
    for (int nt=0;nt<4;nt++){
      int col = n0 + wn*64 + nt*16 + l16;
#pragma unroll
      for (int reg=0;reg<4;reg++)
        Cp[(size_t)(mb+reg)*C2 + col] = f2bf(acc[mt][nt][reg]);
    }
  }
}

// ---------------- debed GEMM: 128x128 tiles, XCD-swizzled; scatter -> dh bf16 ----------------
__global__ __launch_bounds__(256) void gemm_debed_kernel(const unsigned short* __restrict__ A,
    const unsigned short* __restrict__ Bt, unsigned short* __restrict__ C){
  int flat = blockIdx.x;
  int xcd = flat & 7, slot = flat >> 3;
  int tile = xcd*41 + slot;
  if (tile >= 324) return;
  int m0 = (tile/12)*128, n0 = (tile - (tile/12)*12)*128;
  __shared__ __align__(16) unsigned short Al[128*32];
  __shared__ __align__(16) unsigned short Bl[128*32];
  int t=threadIdx.x, w=t>>6, lane=t&63;
  int g=lane>>4, l16=lane&15, r16=lane>>2, c16=lane&3;
  int wm=w>>1, wn=w&1;
  float4v acc[4][4] = {};
  for (int kb=0;kb<C2;kb+=32){
    __syncthreads();
#pragma unroll
    for (int cc=0;cc<4;cc++){
      int ch = w*4+cc;
      if (ch<8){
        const unsigned short* gp = A + (size_t)(m0+ch*16+r16)*C2 + kb + c16*8;
        load_lds16(gp, &Al[ch*512]);
      } else {
        const unsigned short* gp = Bt + (size_t)(n0+(ch-8)*16+r16)*C2 + kb + c16*8;
        load_lds16(gp, &Bl[(ch-8)*512]);
      }
    }
    __syncthreads();
    short8 af[4], bf[4];
#pragma unroll
    for (int mt=0;mt<4;mt++) af[mt] = *(const short8*)&Al[(wm*64+mt*16+l16)*32 + g*8];
#pragma unroll
    for (int nt=0;nt<4;nt++) bf[nt] = *(const short8*)&Bl[(wn*64+nt*16+l16)*32 + g*8];
#pragma unroll
    for (int mt=0;mt<4;mt++)
#pragma unroll
      for (int nt=0;nt<4;nt++)
        acc[mt][nt] = mfma32(af[mt], bf[nt], acc[mt][nt]);
  }
#pragma unroll
  for (int nt=0;nt<4;nt++){
    int n = n0 + wn*64 + nt*16 + l16;
    int kpq = n / C1;
    int o = n - kpq*C1;
#pragma unroll
    for (int mt=0;mt<4;mt++){
      int mb = m0 + wm*64 + mt*16 + g*4;
#pragma unroll
      for (int reg=0;reg<4;reg++){
        int m = mb + reg;
        int b = m / LL; int tok = m - b*LL;
        int h = tok/(S2*S2), ww=(tok/S2)%S2, d=tok%S2;
        int v24 = (2*h+((kpq>>2)&1))*(S1*S1) + (2*ww+((kpq>>1)&1))*S1 + (2*d+(kpq&1));
        C[(size_t)(b*V1+v24)*C1 + o] = f2bf(acc[mt][nt][reg]);
      }
    }
  }
}

// ---------------- final: LN(192)+GELU fused into convT2 GEMM + bias + residual ----------------
__global__ __launch_bounds__(256) void final_kernel(const unsigned short* __restrict__ dh,
    const unsigned short* __restrict__ Bt48, const float* __restrict__ og,
    const float* __restrict__ ob, const float* __restrict__ tb2s,
    const float* __restrict__ skipp, float* __restrict__ out){
  __shared__ __align__(16) unsigned short As[64*200];
  __shared__ __align__(16) unsigned short Bs[64*200];
  int t=threadIdx.x, w=t>>6, lane=t&63;
  int g=lane>>4, l16=lane&15;
  int m0 = blockIdx.x*64;
  for (int n8 = t; n8 < 1536; n8 += 256){
    int n64 = n8/24, kk = (n8 - n64*24)*8;
    uint4 d4 = *(const uint4*)&Bt48[n64*192 + kk];
    *(uint4*)&Bs[n64*200 + kk] = d4;
  }
  float g0=og[lane], g1v=og[lane+64], g2v=og[lane+128];
  float b0=ob[lane], b1v=ob[lane+64], b2v=ob[lane+128];
  for (int rr=0; rr<16; rr++){
    int rl = w*16 + rr;
    const unsigned short* row = dh + (size_t)(m0+rl)*C1;
    float v0=bf2f(row[lane]), v1=bf2f(row[lane+64]), v2=bf2f(row[lane+128]);
    float s1=v0+v1+v2, s2=v0*v0+v1*v1+v2*v2;
#pragma unroll
    for (int off=32;off>0;off>>=1){ s1+=__shfl_xor(s1,off); s2+=__shfl_xor(s2,off); }
    float u=s1*(1.f/C1), inv=rsqrtf(s2*(1.f/C1)-u*u+1e-6f);
    As[rl*200+lane]     = f2bf(gelu_exact((v0-u)*inv*g0+b0));
    As[rl*200+lane+64]  = f2bf(gelu_exact((v1-u)*inv*g1v+b1v));
    As[rl*200+lane+128] = f2bf(gelu_exact((v2-u)*inv*g2v+b2v));
  }
  __syncthreads();
  int wm=w>>1, wn=w&1;
  float4v acc[2][2] = {};
#pragma unroll
  for (int kb=0;kb<192;kb+=32){
    short8 af[2], bf[2];
#pragma unroll
    for (int mt=0;mt<2;mt++) af[mt] = *(const short8*)&As[(wm*32+mt*16+l16)*200 + kb + g*8];
#pragma unroll
    for (int nt=0;nt<2;nt++) bf[nt] = *(const short8*)&Bs[(wn*32+nt*16+l16)*200 + kb + g*8];
#pragma unroll
    for (int mt=0;mt<2;mt++)
#pragma unroll
      for (int nt=0;nt<2;nt++)
        acc[mt][nt] = mfma32(af[mt], bf[nt], acc[mt][nt]);
  }
#pragma unroll
  for (int nt=0;nt<2;nt++){
    int n = wn*32 + nt*16 + l16;
    if (n < 48){
      int c = n>>3, kpq = n&7;
      float bias = tb2s[c];
#pragma unroll
      for (int mt=0;mt<2;mt++){
        int mb = m0 + wm*32 + mt*16 + g*4;
#pragma unroll
        for (int reg=0;reg<4;reg++){
          int m = mb + reg;
          int b = m / V1; int v24 = m - b*V1;
          int y24 = v24/(S1*S1), x24=(v24/S1)%S1, z24=v24%S1;
          int vox = (2*y24+((kpq>>2)&1))*(S0*S0) + (2*x24+((kpq>>1)&1))*S0 + 2*z24+(kpq&1);
          size_t oi = (size_t)(b*C0+c)*V0 + vox;
          out[oi] = acc[mt][nt][reg] + bias + skipp[oi];
        }
      }
    }
  }
}

// ------------- fused stem LN over 768 (in-place bf16): z=0 q(rope,scale) z=1 k(rope) z=2 v -------------
__global__ __launch_bounds__(64) void ln768_stem_kernel(
    unsigned short* __restrict__ qb, unsigned short* __restrict__ kb2,
    unsigned short* __restrict__ vb,
    const float* __restrict__ qg, const float* __restrict__ qbi,
    const float* __restrict__ kg, const float* __restrict__ kbi,
    const float* __restrict__ vg, const float* __restrict__ vbi, float qscale){
  int z = blockIdx.y;
  unsigned short* buf = (z==0)?qb:((z==1)?kb2:vb);
  const float* g  = (z==0)?qg:((z==1)?kg:vg);
  const float* bia= (z==0)?qbi:((z==1)?kbi:vbi);
  float scale = (z==0)? qscale : 1.0f;
  int tok = blockIdx.x, lane = threadIdx.x;
  unsigned short* row = buf + (size_t)tok*C2;
  float v[12]; float s1=0.f,s2=0.f;
#pragma unroll
  for (int i=0;i<12;i++){ float t=bf2f(row[i*64+lane]); v[i]=t; s1+=t; s2+=t*t; }
#pragma unroll
  for (int off=32;off>0;off>>=1){ s1+=__shfl_xor(s1,off); s2+=__shfl_xor(s2,off); }
  float u=s1*(1.f/C2);
  float inv=rsqrtf(s2*(1.f/C2)-u*u+1e-6f);
  if (z==2){
#pragma unroll
    for (int i=0;i<12;i++){ int j=i*64+lane; row[j]=f2bf((v[i]-u)*inv*g[j]+bia[j]); }
  } else {
    int pos = tok % LL;
#pragma unroll
    for (int i=0;i<6;i++){
      int j=i*64+lane;
      float xn1=(v[i]-u)*inv*g[j]+bia[j];
      float xn2=(v[i+6]-u)*inv*g[j+384]+bia[j+384];
      float fr=(float)pos*__expf(-0.02398526139f*(float)j);  // 10000^{-j/384}
      float cs=cosf(fr), sn=sinf(fr);
      row[j]     = f2bf((xn1*cs - xn2*sn)*scale);
      row[j+384] = f2bf((xn2*cs + xn1*sn)*scale);
    }
  }
}

// ------------- V transpose: vbf [m][768] bf16 -> vT [(b*12+h)*64+d][1728] bf16 -------------
__global__ __launch_bounds__(256) void vtrans_kernel(const unsigned short* __restrict__ vbf,
    unsigned short* __restrict__ vT){
  int idx = blockIdx.x*256 + threadIdx.x;
  int token = idx % LL;
  int rest = idx / LL;
  int dc = rest & 7;
  int hb = rest >> 3;
  int h = hb % NH, b = hb / NH;
  const unsigned short* src = vbf + (size_t)(b*LL+token)*C2 + h*64 + dc*8;
  uint4 d4 = *(const uint4*)src;
  const unsigned short* s = (const unsigned short*)&d4;
#pragma unroll
  for (int i=0;i<8;i++)
    vT[(size_t)((b*NH+h)*HD + dc*8 + i)*LL + token] = s[i];
}

// ---------------- transposed MFMA flash attention, split-K x4, raw exp2, XCD-swizzled ----------------
// l computed via ones-column MFMA (sums the same bf16 P used in PV).
__global__ __launch_bounds__(256) void attn_kernel(const unsigned short* __restrict__ q,
    const unsigned short* __restrict__ k, const unsigned short* __restrict__ vt,
    unsigned short* __restrict__ opart, float* __restrict__ lbuf){
  __shared__ __align__(16) unsigned char smem[18432];
  unsigned short* Ks = (unsigned short*)smem;       // [64 keys][64 d] chunk-swizzled
  unsigned short* Vs = Ks + 4096;                   // [64 d][64 keys]
  // decode: each XCD owns an h-contiguous slice (K/V head-slabs L2-local)
  int flat = blockIdx.x;                  // grid 2592 = 8*324 exact
  int xcd = flat & 7, slot = flat >> 3;
  int tile = xcd*324 + slot;
  int h = tile / 216; int rem = tile - h*216;
  int zb = rem / 27, qt = rem - zb*27;
  int b = zb >> 2, split = zb & 3;
  int t=threadIdx.x, w=t>>6, lane=t&63;
  int g=lane>>4, l16=lane&15;
  const unsigned short* qrow = q + (size_t)(b*LL + qt*64 + w*16 + l16)*C2 + h*64;
  short8 qA = *(const short8*)(qrow + g*8);
  short8 qB = *(const short8*)(qrow + 32 + g*8);
  const unsigned short* kbase = k + (size_t)(b*LL)*C2 + h*64;
  const unsigned short* vbase = vt + (size_t)((b*NH+h)*HD)*LL;
  int sub = lane>>3;
  int chs = (lane&7) ^ sub;
  short4v vones;
  vones[0]=vones[1]=vones[2]=vones[3]=(short)0x3F80;  // bf16 1.0 x4
  float4v O4[4] = {};
  float4v Ol = {};
  int ktb = split*7, kte = (split==3)? 27 : (split*7+7);
  for (int kt=ktb; kt<kte; kt++){
    __syncthreads();
#pragma unroll
    for (int cc=0;cc<4;cc++){
      int ii = w*4+cc;
      if (ii<8){
        int key = kt*64 + ii*8 + sub;
        load_lds16(kbase + (size_t)key*C2 + chs*8, &Ks[ii*512]);
      } else {
        int d = (ii-8)*8 + sub;
        load_lds16(vbase + (size_t)d*LL + kt*64 + chs*8, &Vs[(ii-8)*512]);
      }
    }
    __syncthreads();
    float4v sc[4];
#pragma unroll
    for (int nt=0;nt<4;nt++){
      int row = nt*16 + l16;
      int sw = row & 7;
      short8 k1 = *(const short8*)&Ks[row*64 + ((g^sw))*8];
      short8 k2 = *(const short8*)&Ks[row*64 + (((4+g)^sw))*8];
      float4v z = {};
      z = mfma32(k1, qA, z);
      z = mfma32(k2, qB, z);
      sc[nt] = z;
    }
#pragma unroll
    for (int nt=0;nt<4;nt++)
#pragma unroll
      for (int reg=0;reg<4;reg++)
        sc[nt][reg] = exp2f(sc[nt][reg]);
#pragma unroll
    for (int kc=0;kc<4;kc++){
      union { short4v v; unsigned int u[2]; } pb;
      pb.u[0] = pk_bf16(sc[kc][0], sc[kc][1]);
      pb.u[1] = pk_bf16(sc[kc][2], sc[kc][3]);
      Ol = mfma16(vones, pb.v, Ol);
#pragma unroll
      for (int dt=0;dt<4;dt++){
        int row = dt*16 + l16;
        int ch = (kc*2 + (g>>1)) ^ (row&7);
        short4v va = *(const short4v*)&Vs[row*64 + ch*8 + (g&1)*4];
        O4[dt] = mfma16(va, pb.v, O4[dt]);
      }
    }
  }
  __syncthreads();                       // reuse smem for transpose
  float* Ot = (float*)smem;
  float* ot = Ot + w*1152;
#pragma unroll
  for (int dt=0;dt<4;dt++)
    *(float4*)&ot[l16*72 + dt*16 + g*4] =
        make_float4(O4[dt][0],O4[dt][1],O4[dt][2],O4[dt][3]);
  if (g==0){
    int qi = qt*64 + w*16 + l16;
    lbuf[((size_t)(b*4+split)*NH+h)*LL + qi] = Ol[0];
  }
  int qq = lane>>2, c4 = lane&3;
  unsigned short* orow = opart + (size_t)split*MDIM*C2
              + (size_t)(b*LL + qt*64 + w*16 + qq)*C2 + h*64;
#pragma unroll
  for (int p=0;p<4;p++){
    float4 vv = *(float4*)&ot[qq*72 + p*16 + c4*4];
    uint2 pk; pk.x = pk_bf16(vv.x,vv.y); pk.y = pk_bf16(vv.z,vv.w);
    *(uint2*)&orow[p*16 + c4*4] = pk;
  }
}

// ---------------- combine 4 splits + post-attn LN (permuted gamma) -> bf16 aob ----------------
__global__ __launch_bounds__(256) void attn_post_kernel(const unsigned short* __restrict__ opart,
    const float* __restrict__ lbuf,
    const float* __restrict__ g, const float* __restrict__ bia,
    unsigned short* __restrict__ aob){
  int t=threadIdx.x, w=t>>6, lane=t&63;
  int m = blockIdx.x*4 + w;               // grid 864
  int b = m / LL, l = m - b*LL;
  const unsigned short* o0 = opart + (size_t)m*C2;
  unsigned short* orow = aob + (size_t)m*C2;
  float vv[12]; float s1=0.f, s2=0.f;
#pragma unroll
  for (int i=0;i<12;i++){
    float ls = 0.f;
#pragma unroll
    for (int s=0;s<4;s++) ls += lbuf[((size_t)(b*4+s)*NH+i)*LL + l];
    float inv = 1.f/ls;
    int j = i*64+lane;
    float val = 0.f;
#pragma unroll
    for (int s=0;s<4;s++) val += bf2f(o0[(size_t)s*MDIM*C2 + j]);
    val *= inv;
    vv[i]=val; s1+=val; s2+=val*val;
  }
#pragma unroll
  for (int off=32;off>0;off>>=1){ s1+=__shfl_xor(s1,off); s2+=__shfl_xor(s2,off); }
  float u=s1*(1.f/C2);
  float invs=rsqrtf(s2*(1.f/C2)-u*u+1e-6f);
#pragma unroll
  for (int i=0;i<12;i++){
    int cj = lane*NH + i;                 // permuted gamma: channel p=h*64+d -> c=d*12+h
    orow[i*64+lane] = f2bf((vv[i]-u)*invs*g[cj]+bia[cj]);
  }
}

extern "C" void kernel_launch(void* const* d_in, const int* in_sizes, int n_in,
                              void* d_out, int out_size, void* d_ws, size_t ws_size,
                              hipStream_t stream){
  (void)in_sizes; (void)n_in; (void)out_size; (void)ws_size;
  const float* x    =(const float*)d_in[0];
  const float* skip =(const float*)d_in[1];
  const float* q_w1 =(const float*)d_in[2];
  const float* q_g1 =(const float*)d_in[3];
  const float* q_b1 =(const float*)d_in[4];
  const float* q_w2 =(const float*)d_in[5];
  const float* q_g2 =(const float*)d_in[6];
  const float* q_b2 =(const float*)d_in[7];
  const float* k_w1 =(const float*)d_in[8];
  const float* k_g1 =(const float*)d_in[9];
  const float* k_b1 =(const float*)d_in[10];
  const float* k_w2 =(const float*)d_in[11];
  const float* k_g2 =(const float*)d_in[12];
  const float* k_b2 =(const float*)d_in[13];
  const float* v_w1 =(const float*)d_in[14];
  const float* v_g1 =(const float*)d_in[15];
  const float* v_b1 =(const float*)d_in[16];
  const float* v_w2 =(const float*)d_in[17];
  const float* v_g2 =(const float*)d_in[18];
  const float* v_b2 =(const float*)d_in[19];
  const float* o_tw1=(const float*)d_in[20];
  const float* o_g  =(const float*)d_in[21];
  const float* o_b  =(const float*)d_in[22];
  const float* o_tw2=(const float*)d_in[23];
  const float* o_tb2=(const float*)d_in[24];
  const float* ns_w =(const float*)d_in[25];
  const float* ns_b =(const float*)d_in[26];
  const float* nx_w =(const float*)d_in[27];
  const float* nx_b =(const float*)d_in[28];
  const float* no_w =(const float*)d_in[29];
  const float* no_b =(const float*)d_in[30];
  float* out=(float*)d_out;

  char* W = (char*)d_ws;
  unsigned short* lnSb = (unsigned short*)(W + 0);          //  2,654,208
  unsigned short* lnXb = (unsigned short*)(W + 2654208);    //  2,654,208
  unsigned short* h1q  = (unsigned short*)(W + 5308416);    // 10,616,832
  unsigned short* h1k  = (unsigned short*)(W + 15925248);   // 10,616,832
  unsigned short* h1v  = (unsigned short*)(W + 26542080);   // 10,616,832
  unsigned short* w2tq = (unsigned short*)(W + 37158912);   //  2,359,296
  unsigned short* w2tk = (unsigned short*)(W + 39518208);   //  2,359,296
  unsigned short* w2tv = (unsigned short*)(W + 41877504);   //  2,359,296
  unsigned short* qbf  = (unsigned short*)(W + 44236800);   //  5,308,416
  unsigned short* kbf  = (unsigned short*)(W + 49545216);   //  5,308,416
  unsigned short* vbf  = (unsigned short*)(W + 54853632);   //  5,308,416
  unsigned short* vT   = (unsigned short*)(W + 60162048);   //  5,308,416
  unsigned short* aob  = (unsigned short*)(W + 65470464);   //  5,308,416
  unsigned short* Btd  = (unsigned short*)(W + 70778880);   //  2,359,296
  unsigned short* Bt48 = (unsigned short*)(W + 73138176);   //     24,576
  unsigned short* w1q  = (unsigned short*)(W + 73162752);   //     18,432
  unsigned short* w1k  = (unsigned short*)(W + 73181184);   //     18,432
  unsigned short* w1v  = (unsigned short*)(W + 73199616);   //     18,432 -> end 73,218,048
  // overlays:
  float* lbuf  = (float*)(W + 0);                     // 663,552 (lnSb dead after conv1)
  unsigned short* opart = (unsigned short*)(W + 5308416);  // 4x5,308,416 bf16 (h1q+h1k dead)
  unsigned short* dh   = (unsigned short*)(W + 5308416);   // 10,616,832 bf16 (opart dead after attn_post)

  const float QSCALE = 0.125f*1.44269504089f;  // 1/sqrt(64) * log2(e)

  prep_kernel<<<20316,256,0,stream>>>(skip, x, ns_w, ns_b, nx_w, nx_b, lnSb, lnXb,
      q_w2,k_w2,v_w2,o_tw1,o_tw2, q_w1,k_w1,v_w1,
      w2tq,w2tk,w2tv,Btd,Bt48, w1q,w1k,w1v);
  conv1_kernel<<<dim3(432,1,3),256,0,stream>>>(lnSb,lnXb, w1q,w1k,w1v,
      q_g1,q_b1, k_g1,k_b1, v_g1,v_b1, h1q,h1k,h1v);
  gemm_stem_kernel<<<488,256,0,stream>>>(h1q,h1k,h1v,
      w2tq,w2tk,w2tv, qbf,kbf,vbf);
  ln768_stem_kernel<<<dim3(MDIM,3),64,0,stream>>>(qbf,kbf,vbf,
      q_g2,q_b2, k_g2,k_b2, v_g2,v_b2, QSCALE);
  vtrans_kernel<<<1296,256,0,stream>>>(vbf, vT);
  attn_kernel<<<2592,256,0,stream>>>(qbf, kbf, vT, opart, lbuf);
  attn_post_kernel<<<864,256,0,stream>>>(opart, lbuf, no_w, no_b, aob);
  gemm_debed_kernel<<<328,256,0,stream>>>(aob, Btd, dh);
  final_kernel<<<432,256,0,stream>>>(dh, Bt48, o_g, o_b, o_tb2, skip, out);
}

// Round 12
// 327.149 us; speedup vs baseline: 4.5936x; 1.0058x over previous
//
#include <hip/hip_runtime.h>
#include <math.h>

#define BB_ 2
#define C0 6
#define S0 48
#define V0 (S0*S0*S0)      // 110592
#define C1 192
#define S1 24
#define V1 (S1*S1*S1)      // 13824
#define C2 768
#define S2 12
#define LL (S2*S2*S2)      // 1728
#define NH 12
#define HD 64
#define KDIM (C1*8)        // 1536
#define MDIM (BB_*LL)      // 3456

typedef __attribute__((ext_vector_type(8))) short short8;
typedef __attribute__((ext_vector_type(4))) short short4v;
typedef __attribute__((ext_vector_type(4))) float float4v;

static __device__ __forceinline__ float gelu_exact(float x){
  return 0.5f*x*(1.0f+erff(x*0.70710678118654752440f));
}
static __device__ __forceinline__ unsigned short f2bf(float f){
  unsigned int u = __float_as_uint(f);
  unsigned int r = (u + 0x7fffu + ((u>>16)&1u)) >> 16;
  return (unsigned short)r;
}
static __device__ __forceinline__ unsigned int pk_bf16(float a, float b){
#if __has_builtin(__builtin_amdgcn_cvt_pk_bf16_f32)
  typedef __attribute__((ext_vector_type(2))) __bf16 bf2;
  bf2 r = __builtin_amdgcn_cvt_pk_bf16_f32(a,b);
  union { bf2 v; unsigned int u; } cv; cv.v = r;
  return cv.u;
#else
  return (unsigned int)f2bf(a) | ((unsigned int)f2bf(b)<<16);
#endif
}
static __device__ __forceinline__ float bf2f(unsigned short u){
  return __uint_as_float(((unsigned int)u)<<16);
}
static __device__ __forceinline__ void load_lds16(const void* g, void* l){
  __builtin_amdgcn_global_load_lds((const __attribute__((address_space(1))) unsigned int*)g,
      (__attribute__((address_space(3))) unsigned int*)l, 16, 0, 0);
}
static __device__ __forceinline__ float4v mfma32(short8 a, short8 b, float4v c){
  return __builtin_amdgcn_mfma_f32_16x16x32_bf16(a,b,c,0,0,0);
}
static __device__ __forceinline__ float4v mfma16(short4v a, short4v b, float4v c){
#if __has_builtin(__builtin_amdgcn_mfma_f32_16x16x16bf16_1k)
  return __builtin_amdgcn_mfma_f32_16x16x16bf16_1k(a,b,c,0,0,0);
#else
  asm volatile("v_mfma_f32_16x16x16_bf16 %0, %1, %2, %0" : "+v"(c) : "v"(a), "v"(b));
  return c;
#endif
}

// ---------------- prep: LN6 (skip,x) + all weight repacks, one launch ----------------
__global__ __launch_bounds__(256) void prep_kernel(
    const float* __restrict__ skin, const float* __restrict__ xin,
    const float* __restrict__ nsw, const float* __restrict__ nsb,
    const float* __restrict__ nxw, const float* __restrict__ nxb,
    unsigned short* __restrict__ outS, unsigned short* __restrict__ outX,
    const float* __restrict__ qw2, const float* __restrict__ kw2, const float* __restrict__ vw2,
    const float* __restrict__ tw1, const float* __restrict__ tw2,
    const float* __restrict__ qw1, const float* __restrict__ kw1, const float* __restrict__ vw1,
    unsigned short* __restrict__ w2tq, unsigned short* __restrict__ w2tk,
    unsigned short* __restrict__ w2tv, unsigned short* __restrict__ Btd,
    unsigned short* __restrict__ Bt48,
    unsigned short* __restrict__ w1q, unsigned short* __restrict__ w1k,
    unsigned short* __restrict__ w1v){
  int bx = blockIdx.x;
  if (bx < 1728){                         // LN over 6 channels (channels_first)
    int z = bx >= 864;
    const float* in = z ? xin : skin;
    const float* w  = z ? nxw : nsw;
    const float* bi = z ? nxb : nsb;
    unsigned short* out = z ? outX : outS;
    int idx = (bx - z*864)*256 + threadIdx.x;
    int b = idx / V0, vox = idx - b*V0;
    const float* p = in + (size_t)b*(C0*V0) + vox;
    float v[C0]; float s=0.f;
#pragma unroll
    for (int c=0;c<C0;c++){ v[c]=p[(size_t)c*V0]; s+=v[c]; }
    float u = s*(1.f/C0);
    float ss=0.f;
#pragma unroll
    for (int c=0;c<C0;c++){ float d=v[c]-u; ss+=d*d; }
    float inv = rsqrtf(ss*(1.f/C0)+1e-6f);
    unsigned short* o = out + (size_t)b*(C0*V0) + vox;
#pragma unroll
    for (int c=0;c<C0;c++) o[(size_t)c*V0] = f2bf((v[c]-u)*inv*w[c]+bi[c]);
    return;
  }
  bx -= 1728;
  if (bx < 13824){                       // 3 x 4608 : w2 repacks -> [oc][p*192+ic]
    int z = bx/4608;
    int idx = (bx - z*4608)*256 + threadIdx.x;
    const float* w2 = (z==0)?qw2:((z==1)?kw2:vw2);
    unsigned short* o = (z==0)?w2tq:((z==1)?w2tk:w2tv);
    int oc = idx/KDIM; int r = idx-oc*KDIM; int p = r/C1; int ic = r-p*C1;
    o[idx] = f2bf(w2[(size_t)oc*KDIM + ic*8 + p]);
  } else if (bx < 18432){                // tw1 -> [kpq*192+o][p head-major]
    int idx = (bx-13824)*256 + threadIdx.x;
    int n = idx/C2; int p = idx-n*C2;
    int i = ((p&63)*NH) + (p>>6);
    int kpq = n/C1, o2 = n-kpq*C1;
    Btd[idx] = f2bf(tw1[(size_t)i*KDIM + o2*8 + kpq]);
  } else if (bx < 18480){                // 48 blocks: tw2 -> [n=c*8+kpq pad64][i]
    int idx = (bx-18432)*256 + threadIdx.x;
    int n = idx/C1; int i = idx-n*C1;
    Bt48[idx] = (n<48) ? f2bf(tw2[(size_t)i*48 + n]) : (unsigned short)0;
  } else {                               // 108 blocks: w1 -> bf16 passthrough
    int idx = (bx-18480)*256 + threadIdx.x;  // 27648 = 3*9216
    int z = idx / 9216; int r = idx - z*9216;
    const float* w1 = (z==0)?qw1:((z==1)?kw1:vw1);
    unsigned short* o = (z==0)?w1q:((z==1)?w1k:w1v);
    o[r] = f2bf(w1[r]);
  }
}

// ------------- conv1 via MFMA, one tile-job per wave, NO LDS (W bf16 in L1/L2) -------------
__global__ __launch_bounds__(256) void conv1_kernel(
    const unsigned short* __restrict__ lnSb, const unsigned short* __restrict__ lnXb,
    const unsigned short* __restrict__ w1bq, const unsigned short* __restrict__ w1bk,
    const unsigned short* __restrict__ w1bv,
    const float* __restrict__ qg1, const float* __restrict__ qb1,
    const float* __restrict__ kg1, const float* __restrict__ kb1,
    const float* __restrict__ vg1, const float* __restrict__ vb1,
    unsigned short* __restrict__ h1q, unsigned short* __restrict__ h1k,
    unsigned short* __restrict__ h1v){
  int z = blockIdx.z;
  const unsigned short* in = (z==0)? lnSb : lnXb;
  const unsigned short* Wb = (z==0)?w1bq:((z==1)?w1bk:w1bv);
  const float* g1 = (z==0)?qg1:((z==1)?kg1:vg1);
  const float* b1 = (z==0)?qb1:((z==1)?kb1:vb1);
  unsigned short* h1p = (z==0)?h1q:((z==1)?h1k:h1v);
  int t = threadIdx.x, w = t>>6, lane = t&63;
  int g = lane>>4, l16 = lane&15;
  int j = blockIdx.x*4 + w;
  int bxh = j/18, mt = j - bxh*18;
  int b = bxh/48; int rem = bxh - b*48; int y = rem>>1, xh = rem&1;
  int xo = mt/3, zo = mt - xo*3;
  int xv = xh*12 + xo*2 + (l16>>3);
  int zv = zo*8 + (l16&7);
  int x2 = 2*xv, z2 = 2*zv, y2 = 2*y;
  const unsigned short* base = in + (size_t)b*C0*V0;
  union { short8 v; unsigned int u[4]; } aA;     // k=g*8+jj  -> ic=g, p=jj
  {
    size_t rb = (size_t)g*V0;
    aA.u[0] = *(const unsigned int*)&base[rb + (y2+0)*(S0*S0) + (x2+0)*S0 + z2];
    aA.u[1] = *(const unsigned int*)&base[rb + (y2+0)*(S0*S0) + (x2+1)*S0 + z2];
    aA.u[2] = *(const unsigned int*)&base[rb + (y2+1)*(S0*S0) + (x2+0)*S0 + z2];
    aA.u[3] = *(const unsigned int*)&base[rb + (y2+1)*(S0*S0) + (x2+1)*S0 + z2];
  }
  union { short4v v; unsigned int u[2]; } aB;    // k=32+g*4+jj -> ic=4+(g>>1), p=(g&1)*4+jj
  {
    size_t rb = (size_t)(4+(g>>1))*V0 + (y2+(g&1))*(S0*S0);
    aB.u[0] = *(const unsigned int*)&base[rb + (x2+0)*S0 + z2];
    aB.u[1] = *(const unsigned int*)&base[rb + (x2+1)*S0 + z2];
  }
  float4v acc[12];
#pragma unroll
  for (int ot=0; ot<12; ot++){
    short8  wA = *(const short8*)&Wb[(ot*16+l16)*48 + g*8];
    short4v wB = *(const short4v*)&Wb[(ot*16+l16)*48 + 32 + g*4];
    float4v a = {};
    a = mfma32(wA, aA.v, a);
    a = mfma16(wB, aB.v, a);
    acc[ot] = a;
  }
  float s1=0.f, s2=0.f;
#pragma unroll
  for (int ot=0;ot<12;ot++)
#pragma unroll
    for (int reg=0;reg<4;reg++){ float v=acc[ot][reg]; s1+=v; s2+=v*v; }
  s1 += __shfl_xor(s1,16); s1 += __shfl_xor(s1,32);
  s2 += __shfl_xor(s2,16); s2 += __shfl_xor(s2,32);
  float u = s1*(1.f/C1);
  float inv = rsqrtf(s2*(1.f/C1)-u*u+1e-6f);
  int tok = (y>>1)*(S2*S2) + (xv>>1)*S2 + (zv>>1);
  int p8 = (y&1)*4 + (xv&1)*2 + (zv&1);
  unsigned short* hb = h1p + (size_t)(b*LL+tok)*KDIM + p8*C1;
#pragma unroll
  for (int ot=0; ot<12; ot++){
    int oc0 = ot*16 + g*4;
    float4 gg = *(const float4*)&g1[oc0];
    float4 bb = *(const float4*)&b1[oc0];
    float x0 = gelu_exact((acc[ot][0]-u)*inv*gg.x+bb.x);
    float x1 = gelu_exact((acc[ot][1]-u)*inv*gg.y+bb.y);
    float x2e= gelu_exact((acc[ot][2]-u)*inv*gg.z+bb.z);
    float x3 = gelu_exact((acc[ot][3]-u)*inv*gg.w+bb.w);
    uint2 pk; pk.x = pk_bf16(x0,x1); pk.y = pk_bf16(x2e,x3);
    *(uint2*)&hb[oc0] = pk;
  }
}

// ---------------- fused stem GEMM, 128x128 tiles, XCD-swizzled 1D grid ----------------
__global__ __launch_bounds__(256) void gemm_stem_kernel(
    const unsigned short* __restrict__ A0, const unsigned short* __restrict__ A1,
    const unsigned short* __restrict__ A2,
    const unsigned short* __restrict__ B0, const unsigned short* __restrict__ B1,
    const unsigned short* __restrict__ B2,
    unsigned short* __restrict__ Cq, unsigned short* __restrict__ Ck,
    unsigned short* __restrict__ Cv){
  int flat = blockIdx.x;
  int xcd = flat & 7, slot = flat >> 3;
  int tile = xcd*61 + slot;
  if (tile >= 486) return;
  int z = tile/162; int rr = tile - z*162;
  int m0 = (rr/6)*128, n0 = (rr - (rr/6)*6)*128;
  const unsigned short* A = (z==0)?A0:((z==1)?A1:A2);
  const unsigned short* Bt = (z==0)?B0:((z==1)?B1:B2);
  unsigned short* Cp = (z==0)?Cq:((z==1)?Ck:Cv);
  __shared__ __align__(16) unsigned short Al[128*32];
  __shared__ __align__(16) unsigned short Bl[128*32];
  int t=threadIdx.x, w=t>>6, lane=t&63;
  int g=lane>>4, l16=lane&15, r16=lane>>2, c16=lane&3;
  int wm=w>>1, wn=w&1;
  float4v acc[4][4] = {};
  for (int kb=0;kb<KDIM;kb+=32){
    __syncthreads();
#pragma unroll
    for (int cc=0;cc<4;cc++){
      int ch = w*4+cc;
      if (ch<8){
        const unsigned short* gp = A + (size_t)(m0+ch*16+r16)*KDIM + kb + c16*8;
        load_lds16(gp, &Al[ch*512]);
      } else {
        const unsigned short* gp = Bt + (size_t)(n0+(ch-8)*16+r16)*KDIM + kb + c16*8;
        load_lds16(gp, &Bl[(ch-8)*512]);
      }
    }
    __syncthreads();
    short8 af[4], bf[4];
#pragma unroll
    for (int mt=0;mt<4;mt++) af[mt] = *(const short8*)&Al[(wm*64+mt*16+l16)*32 + g*8];
#pragma unroll
    for (int nt=0;nt<4;nt++) bf[nt] = *(const short8*)&Bl[(wn*64+nt*16+l16)*32 + g*8];
#pragma unroll
    for (int mt=0;mt<4;mt++)
#pragma unroll
      for (int nt=0;nt<4;nt++)
        acc[mt][nt] = mfma32(af[mt], bf[nt], acc[mt][nt]);
  }
#pragma unroll
  for (int mt=0;mt<4;mt++){
    int mb = m0 + wm*64 + mt*16 + g*4;
#pragma unroll
    for (int nt=0;nt<4;nt++){
      int col = n0 + wn*64 + nt*16 + l16;
#pragma unroll
      for (int reg=0;reg<4;reg++)
        Cp[(size_t)(mb+reg)*C2 + col] = f2bf(acc[mt][nt][reg]);
    }
  }
}

// ---------------- debed GEMM: 128x128 tiles, XCD-swizzled; scatter -> dh bf16 ----------------
__global__ __launch_bounds__(256) void gemm_debed_kernel(const unsigned short* __restrict__ A,
    const unsigned short* __restrict__ Bt, unsigned short* __restrict__ C){
  int flat = blockIdx.x;
  int xcd = flat & 7, slot = flat >> 3;
  int tile = xcd*41 + slot;
  if (tile >= 324) return;
  int m0 = (tile/12)*128, n0 = (tile - (tile/12)*12)*128;
  __shared__ __align__(16) unsigned short Al[128*32];
  __shared__ __align__(16) unsigned short Bl[128*32];
  int t=threadIdx.x, w=t>>6, lane=t&63;
  int g=lane>>4, l16=lane&15, r16=lane>>2, c16=lane&3;
  int wm=w>>1, wn=w&1;
  float4v acc[4][4] = {};
  for (int kb=0;kb<C2;kb+=32){
    __syncthreads();
#pragma unroll
    for (int cc=0;cc<4;cc++){
      int ch = w*4+cc;
      if (ch<8){
        const unsigned short* gp = A + (size_t)(m0+ch*16+r16)*C2 + kb + c16*8;
        load_lds16(gp, &Al[ch*512]);
      } else {
        const unsigned short* gp = Bt + (size_t)(n0+(ch-8)*16+r16)*C2 + kb + c16*8;
        load_lds16(gp, &Bl[(ch-8)*512]);
      }
    }
    __syncthreads();
    short8 af[4], bf[4];
#pragma unroll
    for (int mt=0;mt<4;mt++) af[mt] = *(const short8*)&Al[(wm*64+mt*16+l16)*32 + g*8];
#pragma unroll
    for (int nt=0;nt<4;nt++) bf[nt] = *(const short8*)&Bl[(wn*64+nt*16+l16)*32 + g*8];
#pragma unroll
    for (int mt=0;mt<4;mt++)
#pragma unroll
      for (int nt=0;nt<4;nt++)
        acc[mt][nt] = mfma32(af[mt], bf[nt], acc[mt][nt]);
  }
#pragma unroll
  for (int nt=0;nt<4;nt++){
    int n = n0 + wn*64 + nt*16 + l16;
    int kpq = n / C1;
    int o = n - kpq*C1;
#pragma unroll
    for (int mt=0;mt<4;mt++){
      int mb = m0 + wm*64 + mt*16 + g*4;
#pragma unroll
      for (int reg=0;reg<4;reg++){
        int m = mb + reg;
        int b = m / LL; int tok = m - b*LL;
        int h = tok/(S2*S2), ww=(tok/S2)%S2, d=tok%S2;
        int v24 = (2*h+((kpq>>2)&1))*(S1*S1) + (2*ww+((kpq>>1)&1))*S1 + (2*d+(kpq&1));
        C[(size_t)(b*V1+v24)*C1 + o] = f2bf(acc[mt][nt][reg]);
      }
    }
  }
}

// ---------------- final: LN(192)+GELU fused into convT2 GEMM + bias + residual ----------------
__global__ __launch_bounds__(256) void final_kernel(const unsigned short* __restrict__ dh,
    const unsigned short* __restrict__ Bt48, const float* __restrict__ og,
    const float* __restrict__ ob, const float* __restrict__ tb2s,
    const float* __restrict__ skipp, float* __restrict__ out){
  __shared__ __align__(16) unsigned short As[64*200];
  __shared__ __align__(16) unsigned short Bs[64*200];
  int t=threadIdx.x, w=t>>6, lane=t&63;
  int g=lane>>4, l16=lane&15;
  int m0 = blockIdx.x*64;
  for (int n8 = t; n8 < 1536; n8 += 256){
    int n64 = n8/24, kk = (n8 - n64*24)*8;
    uint4 d4 = *(const uint4*)&Bt48[n64*192 + kk];
    *(uint4*)&Bs[n64*200 + kk] = d4;
  }
  float g0=og[lane], g1v=og[lane+64], g2v=og[lane+128];
  float b0=ob[lane], b1v=ob[lane+64], b2v=ob[lane+128];
  for (int rr=0; rr<16; rr++){
    int rl = w*16 + rr;
    const unsigned short* row = dh + (size_t)(m0+rl)*C1;
    float v0=bf2f(row[lane]), v1=bf2f(row[lane+64]), v2=bf2f(row[lane+128]);
    float s1=v0+v1+v2, s2=v0*v0+v1*v1+v2*v2;
#pragma unroll
    for (int off=32;off>0;off>>=1){ s1+=__shfl_xor(s1,off); s2+=__shfl_xor(s2,off); }
    float u=s1*(1.f/C1), inv=rsqrtf(s2*(1.f/C1)-u*u+1e-6f);
    As[rl*200+lane]     = f2bf(gelu_exact((v0-u)*inv*g0+b0));
    As[rl*200+lane+64]  = f2bf(gelu_exact((v1-u)*inv*g1v+b1v));
    As[rl*200+lane+128] = f2bf(gelu_exact((v2-u)*inv*g2v+b2v));
  }
  __syncthreads();
  int wm=w>>1, wn=w&1;
  float4v acc[2][2] = {};
#pragma unroll
  for (int kb=0;kb<192;kb+=32){
    short8 af[2], bf[2];
#pragma unroll
    for (int mt=0;mt<2;mt++) af[mt] = *(const short8*)&As[(wm*32+mt*16+l16)*200 + kb + g*8];
#pragma unroll
    for (int nt=0;nt<2;nt++) bf[nt] = *(const short8*)&Bs[(wn*32+nt*16+l16)*200 + kb + g*8];
#pragma unroll
    for (int mt=0;mt<2;mt++)
#pragma unroll
      for (int nt=0;nt<2;nt++)
        acc[mt][nt] = mfma32(af[mt], bf[nt], acc[mt][nt]);
  }
#pragma unroll
  for (int nt=0;nt<2;nt++){
    int n = wn*32 + nt*16 + l16;
    if (n < 48){
      int c = n>>3, kpq = n&7;
      float bias = tb2s[c];
#pragma unroll
      for (int mt=0;mt<2;mt++){
        int mb = m0 + wm*32 + mt*16 + g*4;
#pragma unroll
        for (int reg=0;reg<4;reg++){
          int m = mb + reg;
          int b = m / V1; int v24 = m - b*V1;
          int y24 = v24/(S1*S1), x24=(v24/S1)%S1, z24=v24%S1;
          int vox = (2*y24+((kpq>>2)&1))*(S0*S0) + (2*x24+((kpq>>1)&1))*S0 + 2*z24+(kpq&1);
          size_t oi = (size_t)(b*C0+c)*V0 + vox;
          out[oi] = acc[mt][nt][reg] + bias + skipp[oi];
        }
      }
    }
  }
}

// ------------- fused stem LN over 768 (in-place bf16): z=0 q(rope,scale) z=1 k(rope) z=2 v -------------
__global__ __launch_bounds__(64) void ln768_stem_kernel(
    unsigned short* __restrict__ qb, unsigned short* __restrict__ kb2,
    unsigned short* __restrict__ vb,
    const float* __restrict__ qg, const float* __restrict__ qbi,
    const float* __restrict__ kg, const float* __restrict__ kbi,
    const float* __restrict__ vg, const float* __restrict__ vbi, float qscale){
  int z = blockIdx.y;
  unsigned short* buf = (z==0)?qb:((z==1)?kb2:vb);
  const float* g  = (z==0)?qg:((z==1)?kg:vg);
  const float* bia= (z==0)?qbi:((z==1)?kbi:vbi);
  float scale = (z==0)? qscale : 1.0f;
  int tok = blockIdx.x, lane = threadIdx.x;
  unsigned short* row = buf + (size_t)tok*C2;
  float v[12]; float s1=0.f,s2=0.f;
#pragma unroll
  for (int i=0;i<12;i++){ float t=bf2f(row[i*64+lane]); v[i]=t; s1+=t; s2+=t*t; }
#pragma unroll
  for (int off=32;off>0;off>>=1){ s1+=__shfl_xor(s1,off); s2+=__shfl_xor(s2,off); }
  float u=s1*(1.f/C2);
  float inv=rsqrtf(s2*(1.f/C2)-u*u+1e-6f);
  if (z==2){
#pragma unroll
    for (int i=0;i<12;i++){ int j=i*64+lane; row[j]=f2bf((v[i]-u)*inv*g[j]+bia[j]); }
  } else {
    int pos = tok % LL;
#pragma unroll
    for (int i=0;i<6;i++){
      int j=i*64+lane;
      float xn1=(v[i]-u)*inv*g[j]+bia[j];
      float xn2=(v[i+6]-u)*inv*g[j+384]+bia[j+384];
      float fr=(float)pos*__expf(-0.02398526139f*(float)j);  // 10000^{-j/384}
      float cs=cosf(fr), sn=sinf(fr);
      row[j]     = f2bf((xn1*cs - xn2*sn)*scale);
      row[j+384] = f2bf((xn2*cs + xn1*sn)*scale);
    }
  }
}

// ------------- V transpose, LDS-tiled: vbf [m][768] -> vT [(b*12+h)*64+d][1728] -------------
__global__ __launch_bounds__(256) void vtrans_kernel(const unsigned short* __restrict__ vbf,
    unsigned short* __restrict__ vT){
  __shared__ unsigned short T[64*72];
  int tok0 = blockIdx.x*64;
  int h = blockIdx.y, b = blockIdx.z;
  int t = threadIdx.x;
#pragma unroll
  for (int i=0;i<2;i++){
    int idx = t + i*256;
    int token = idx>>3, dc = idx&7;
    uint4 d4 = *(const uint4*)&vbf[(size_t)(b*LL+tok0+token)*C2 + h*64 + dc*8];
    const unsigned short* s = (const unsigned short*)&d4;
#pragma unroll
    for (int j2=0;j2<8;j2++) T[(dc*8+j2)*72 + token] = s[j2];
  }
  __syncthreads();
  int r = t>>2, seg = t&3;
  unsigned short* dst = vT + (size_t)((b*NH+h)*HD + r)*LL + tok0 + seg*16;
  uint4 o[2];
  unsigned short* os = (unsigned short*)o;
#pragma unroll
  for (int j2=0;j2<16;j2++) os[j2] = T[r*72 + seg*16 + j2];
  *(uint4*)dst = o[0];
  *(uint4*)(dst+8) = o[1];
}

// ---------------- transposed MFMA flash attention, split-K x4, raw exp2, XCD-swizzled ----------------
// Hoisted LDS offsets + running global staging pointers.
__global__ __launch_bounds__(256) void attn_kernel(const unsigned short* __restrict__ q,
    const unsigned short* __restrict__ k, const unsigned short* __restrict__ vt,
    unsigned short* __restrict__ opart, float* __restrict__ lbuf){
  __shared__ __align__(16) unsigned char smem[18432];
  unsigned short* Ks = (unsigned short*)smem;       // [64 keys][64 d] chunk-swizzled
  unsigned short* Vs = Ks + 4096;                   // [64 d][64 keys]
  int flat = blockIdx.x;                  // grid 2592 = 8*324 exact
  int xcd = flat & 7, slot = flat >> 3;
  int tile = xcd*324 + slot;
  int h = tile / 216; int rem = tile - h*216;
  int zb = rem / 27, qt = rem - zb*27;
  int b = zb >> 2, split = zb & 3;
  int t=threadIdx.x, w=t>>6, lane=t&63;
  int g=lane>>4, l16=lane&15;
  const unsigned short* qrow = q + (size_t)(b*LL + qt*64 + w*16 + l16)*C2 + h*64;
  short8 qA = *(const short8*)(qrow + g*8);
  short8 qB = *(const short8*)(qrow + 32 + g*8);
  const unsigned short* kbase = k + (size_t)(b*LL)*C2 + h*64;
  const unsigned short* vbase = vt + (size_t)((b*NH+h)*HD)*LL;
  int sub = lane>>3;
  int chs = (lane&7) ^ sub;
  int ktb = split*7, kte = (split==3)? 27 : (split*7+7);
  // running staging pointers (per wave: 4 channels)
  const unsigned short* gptr[4];
  unsigned short* ldst[4];
  int gstep[4];
#pragma unroll
  for (int cc=0;cc<4;cc++){
    int ii = w*4+cc;
    if (ii<8){
      int key = ktb*64 + ii*8 + sub;
      gptr[cc] = kbase + (size_t)key*C2 + chs*8;
      gstep[cc] = 64*C2;
      ldst[cc] = &Ks[ii*512];
    } else {
      int d = (ii-8)*8 + sub;
      gptr[cc] = vbase + (size_t)d*LL + ktb*64 + chs*8;
      gstep[cc] = 64;
      ldst[cc] = &Vs[(ii-8)*512];
    }
  }
  // hoisted LDS read offsets (kt-invariant): note (nt*16+l16)&7 == l16&7
  int sw = l16 & 7;
  const unsigned short* ksrow = &Ks[l16*64 + (g^sw)*8];        // k1 base; k2 = +((4+g)^sw - (g^sw))*8
  int c2d = (((4+g)^sw) - (g^sw))*8;
  const unsigned short* vsrow = &Vs[l16*64 + (g&1)*4];
  int xk[4];
#pragma unroll
  for (int kc=0;kc<4;kc++) xk[kc] = (((kc*2 + (g>>1)) ^ sw))*8;
  short4v vones;
  vones[0]=vones[1]=vones[2]=vones[3]=(short)0x3F80;  // bf16 1.0 x4
  float4v O4[4] = {};
  float4v Ol = {};
  for (int kt=ktb; kt<kte; kt++){
    __syncthreads();
#pragma unroll
    for (int cc=0;cc<4;cc++){
      load_lds16(gptr[cc], ldst[cc]);
      gptr[cc] += gstep[cc];
    }
    __syncthreads();
    float4v sc[4];
#pragma unroll
    for (int nt=0;nt<4;nt++){
      short8 k1 = *(const short8*)(ksrow + nt*1024);
      short8 k2 = *(const short8*)(ksrow + nt*1024 + c2d);
      float4v z = {};
      z = mfma32(k1, qA, z);
      z = mfma32(k2, qB, z);
      sc[nt] = z;
    }
#pragma unroll
    for (int nt=0;nt<4;nt++)
#pragma unroll
      for (int reg=0;reg<4;reg++)
        sc[nt][reg] = exp2f(sc[nt][reg]);
#pragma unroll
    for (int kc=0;kc<4;kc++){
      union { short4v v; unsigned int u[2]; } pb;
      pb.u[0] = pk_bf16(sc[kc][0], sc[kc][1]);
      pb.u[1] = pk_bf16(sc[kc][2], sc[kc][3]);
      Ol = mfma16(vones, pb.v, Ol);
      const unsigned short* vp = vsrow + xk[kc];
#pragma unroll
      for (int dt=0;dt<4;dt++){
        short4v va = *(const short4v*)(vp + dt*1024);
        O4[dt] = mfma16(va, pb.v, O4[dt]);
      }
    }
  }
  __syncthreads();                       // reuse smem for transpose
  float* Ot = (float*)smem;
  float* ot = Ot + w*1152;
#pragma unroll
  for (int dt=0;dt<4;dt++)
    *(float4*)&ot[l16*72 + dt*16 + g*4] =
        make_float4(O4[dt][0],O4[dt][1],O4[dt][2],O4[dt][3]);
  if (g==0){
    int qi = qt*64 + w*16 + l16;
    lbuf[((size_t)(b*4+split)*NH+h)*LL + qi] = Ol[0];
  }
  int qq = lane>>2, c4 = lane&3;
  unsigned short* orow = opart + (size_t)split*MDIM*C2
              + (size_t)(b*LL + qt*64 + w*16 + qq)*C2 + h*64;
#pragma unroll
  for (int p=0;p<4;p++){
    float4 vv = *(float4*)&ot[qq*72 + p*16 + c4*4];
    uint2 pk; pk.x = pk_bf16(vv.x,vv.y); pk.y = pk_bf16(vv.z,vv.w);
    *(uint2*)&orow[p*16 + c4*4] = pk;
  }
}

// ---------------- combine 4 splits + post-attn LN (permuted gamma) -> bf16 aob ----------------
__global__ __launch_bounds__(256) void attn_post_kernel(const unsigned short* __restrict__ opart,
    const float* __restrict__ lbuf,
    const float* __restrict__ g, const float* __restrict__ bia,
    unsigned short* __restrict__ aob){
  int t=threadIdx.x, w=t>>6, lane=t&63;
  int m = blockIdx.x*4 + w;               // grid 864
  int b = m / LL, l = m - b*LL;
  const unsigned short* o0 = opart + (size_t)m*C2;
  unsigned short* orow = aob + (size_t)m*C2;
  float vv[12]; float s1=0.f, s2=0.f;
#pragma unroll
  for (int i=0;i<12;i++){
    float ls = 0.f;
#pragma unroll
    for (int s=0;s<4;s++) ls += lbuf[((size_t)(b*4+s)*NH+i)*LL + l];
    float inv = 1.f/ls;
    int j = i*64+lane;
    float val = 0.f;
#pragma unroll
    for (int s=0;s<4;s++) val += bf2f(o0[(size_t)s*MDIM*C2 + j]);
    val *= inv;
    vv[i]=val; s1+=val; s2+=val*val;
  }
#pragma unroll
  for (int off=32;off>0;off>>=1){ s1+=__shfl_xor(s1,off); s2+=__shfl_xor(s2,off); }
  float u=s1*(1.f/C2);
  float invs=rsqrtf(s2*(1.f/C2)-u*u+1e-6f);
#pragma unroll
  for (int i=0;i<12;i++){
    int cj = lane*NH + i;                 // permuted gamma: channel p=h*64+d -> c=d*12+h
    orow[i*64+lane] = f2bf((vv[i]-u)*invs*g[cj]+bia[cj]);
  }
}

extern "C" void kernel_launch(void* const* d_in, const int* in_sizes, int n_in,
                              void* d_out, int out_size, void* d_ws, size_t ws_size,
                              hipStream_t stream){
  (void)in_sizes; (void)n_in; (void)out_size; (void)ws_size;
  const float* x    =(const float*)d_in[0];
  const float* skip =(const float*)d_in[1];
  const float* q_w1 =(const float*)d_in[2];
  const float* q_g1 =(const float*)d_in[3];
  const float* q_b1 =(const float*)d_in[4];
  const float* q_w2 =(const float*)d_in[5];
  const float* q_g2 =(const float*)d_in[6];
  const float* q_b2 =(const float*)d_in[7];
  const float* k_w1 =(const float*)d_in[8];
  const float* k_g1 =(const float*)d_in[9];
  const float* k_b1 =(const float*)d_in[10];
  const float* k_w2 =(const float*)d_in[11];
  const float* k_g2 =(const float*)d_in[12];
  const float* k_b2 =(const float*)d_in[13];
  const float* v_w1 =(const float*)d_in[14];
  const float* v_g1 =(const float*)d_in[15];
  const float* v_b1 =(const float*)d_in[16];
  const float* v_w2 =(const float*)d_in[17];
  const float* v_g2 =(const float*)d_in[18];
  const float* v_b2 =(const float*)d_in[19];
  const float* o_tw1=(const float*)d_in[20];
  const float* o_g  =(const float*)d_in[21];
  const float* o_b  =(const float*)d_in[22];
  const float* o_tw2=(const float*)d_in[23];
  const float* o_tb2=(const float*)d_in[24];
  const float* ns_w =(const float*)d_in[25];
  const float* ns_b =(const float*)d_in[26];
  const float* nx_w =(const float*)d_in[27];
  const float* nx_b =(const float*)d_in[28];
  const float* no_w =(const float*)d_in[29];
  const float* no_b =(const float*)d_in[30];
  float* out=(float*)d_out;

  char* W = (char*)d_ws;
  unsigned short* lnSb = (unsigned short*)(W + 0);          //  2,654,208
  unsigned short* lnXb = (unsigned short*)(W + 2654208);    //  2,654,208
  unsigned short* h1q  = (unsigned short*)(W + 5308416);    // 10,616,832
  unsigned short* h1k  = (unsigned short*)(W + 15925248);   // 10,616,832
  unsigned short* h1v  = (unsigned short*)(W + 26542080);   // 10,616,832
  unsigned short* w2tq = (unsigned short*)(W + 37158912);   //  2,359,296
  unsigned short* w2tk = (unsigned short*)(W + 39518208);   //  2,359,296
  unsigned short* w2tv = (unsigned short*)(W + 41877504);   //  2,359,296
  unsigned short* qbf  = (unsigned short*)(W + 44236800);   //  5,308,416
  unsigned short* kbf  = (unsigned short*)(W + 49545216);   //  5,308,416
  unsigned short* vbf  = (unsigned short*)(W + 54853632);   //  5,308,416
  unsigned short* vT   = (unsigned short*)(W + 60162048);   //  5,308,416
  unsigned short* aob  = (unsigned short*)(W + 65470464);   //  5,308,416
  unsigned short* Btd  = (unsigned short*)(W + 70778880);   //  2,359,296
  unsigned short* Bt48 = (unsigned short*)(W + 73138176);   //     24,576
  unsigned short* w1q  = (unsigned short*)(W + 73162752);   //     18,432
  unsigned short* w1k  = (unsigned short*)(W + 73181184);   //     18,432
  unsigned short* w1v  = (unsigned short*)(W + 73199616);   //     18,432 -> end 73,218,048
  // overlays:
  float* lbuf  = (float*)(W + 0);                     // 663,552 (lnSb dead after conv1)
  unsigned short* opart = (unsigned short*)(W + 5308416);  // 4x5,308,416 bf16 (h1q+h1k dead)
  unsigned short* dh   = (unsigned short*)(W + 5308416);   // 10,616,832 bf16 (opart dead after attn_post)

  const float QSCALE = 0.125f*1.44269504089f;  // 1/sqrt(64) * log2(e)

  prep_kernel<<<20316,256,0,stream>>>(skip, x, ns_w, ns_b, nx_w, nx_b, lnSb, lnXb,
      q_w2,k_w2,v_w2,o_tw1,o_tw2, q_w1,k_w1,v_w1,
      w2tq,w2tk,w2tv,Btd,Bt48, w1q,w1k,w1v);
  conv1_kernel<<<dim3(432,1,3),256,0,stream>>>(lnSb,lnXb, w1q,w1k,w1v,
      q_g1,q_b1, k_g1,k_b1, v_g1,v_b1, h1q,h1k,h1v);
  gemm_stem_kernel<<<488,256,0,stream>>>(h1q,h1k,h1v,
      w2tq,w2tk,w2tv, qbf,kbf,vbf);
  ln768_stem_kernel<<<dim3(MDIM,3),64,0,stream>>>(qbf,kbf,vbf,
      q_g2,q_b2, k_g2,k_b2, v_g2,v_b2, QSCALE);
  vtrans_kernel<<<dim3(27,12,2),256,0,stream>>>(vbf, vT);
  attn_kernel<<<2592,256,0,stream>>>(qbf, kbf, vT, opart, lbuf);
  attn_post_kernel<<<864,256,0,stream>>>(opart, lbuf, no_w, no_b, aob);
  gemm_debed_kernel<<<328,256,0,stream>>>(aob, Btd, dh);
  final_kernel<<<432,256,0,stream>>>(dh, Bt48, o_g, o_b, o_tb2, skip, out);
}